// Round 1
// baseline (505.074 us; speedup 1.0000x reference)
//
#include <hip/hip_runtime.h>
#include <hip/hip_bf16.h>
#include <math.h>

// B=2 N=1024 M=512 D=1024 H=16 DH=64 MID=1024 DC=768 MULT=4
// All GEMMs: bf16 inputs (pre-converted), fp32 MFMA accumulate.
// Requires ws_size >= ~93 MB.

typedef float f32x4 __attribute__((ext_vector_type(4)));
typedef __bf16 bf16x8 __attribute__((ext_vector_type(8)));
typedef __bf16 bf16x4 __attribute__((ext_vector_type(4)));

#define DEVI __device__ __forceinline__

DEVI void gload16(const void* g, void* l) {
  __builtin_amdgcn_global_load_lds((const __attribute__((address_space(1))) void*)g,
                                   (__attribute__((address_space(3))) void*)l, 16, 0, 0);
}

// ---------------- weight fp32 -> bf16 transposed: WT[n][k] = W[k][n] ----------------
__global__ __launch_bounds__(256) void wt_kernel(const float* __restrict__ W,
                                                 __bf16* __restrict__ WT, int K, int N) {
  __shared__ float tile[32][33];
  int n0 = blockIdx.x * 32, k0 = blockIdx.y * 32;
  int tx = threadIdx.x & 31, ty = threadIdx.x >> 5;
#pragma unroll
  for (int i = 0; i < 4; ++i) {
    int k = ty + i * 8;
    tile[k][tx] = W[(size_t)(k0 + k) * N + n0 + tx];
  }
  __syncthreads();
#pragma unroll
  for (int i = 0; i < 4; ++i) {
    int n = ty + i * 8;
    WT[(size_t)(n0 + n) * K + k0 + tx] = (__bf16)tile[tx][n];
  }
}

// ---------------- cond @ {g1,b1,g2,b2} (B=2, tiny GEMV) ----------------
__global__ __launch_bounds__(256) void mod_gemv_kernel(
    const float* __restrict__ cond,
    const float* __restrict__ g1w, const float* __restrict__ g1b,
    const float* __restrict__ b1w, const float* __restrict__ b1b,
    const float* __restrict__ g2w, const float* __restrict__ g2b,
    const float* __restrict__ b2w, const float* __restrict__ b2b,
    float* __restrict__ mods) {
  __shared__ float sc[1024];
  int b = blockIdx.y, mat = blockIdx.z;
  const float* W  = (mat == 0) ? g1w : (mat == 1) ? b1w : (mat == 2) ? g2w : b2w;
  const float* Bv = (mat == 0) ? g1b : (mat == 1) ? b1b : (mat == 2) ? g2b : b2b;
  for (int i = threadIdx.x; i < 1024; i += 256) sc[i] = cond[b * 1024 + i];
  __syncthreads();
  int d = blockIdx.x * 256 + threadIdx.x;
  float acc = 0.f;
#pragma unroll 8
  for (int k = 0; k < 1024; ++k) acc += sc[k] * W[(size_t)k * 1024 + d];
  mods[(size_t)(mat * 2 + b) * 1024 + d] = acc + Bv[d];
}

// ---------------- adaLN: out_bf16 = LN(x)*(1+g)+bt ----------------
__global__ __launch_bounds__(256) void adaln_kernel(const float* __restrict__ X,
                                                    const float* __restrict__ lnw,
                                                    const float* __restrict__ lnb,
                                                    const float* __restrict__ mods,
                                                    int gi, int bi,
                                                    __bf16* __restrict__ out) {
  __shared__ float red[2][4];
  int row = blockIdx.x;  // 0..2047
  int b = row >> 10;
  int t = threadIdx.x;
  const float4 xv = ((const float4*)(X + (size_t)row * 1024))[t];
  float s  = xv.x + xv.y + xv.z + xv.w;
  float s2 = xv.x * xv.x + xv.y * xv.y + xv.z * xv.z + xv.w * xv.w;
  int lane = t & 63, w = t >> 6;
#pragma unroll
  for (int off = 32; off > 0; off >>= 1) {
    s += __shfl_down(s, off);
    s2 += __shfl_down(s2, off);
  }
  if (lane == 0) { red[0][w] = s; red[1][w] = s2; }
  __syncthreads();
  s  = red[0][0] + red[0][1] + red[0][2] + red[0][3];
  s2 = red[1][0] + red[1][1] + red[1][2] + red[1][3];
  float mu = s * (1.0f / 1024.0f);
  float var = s2 * (1.0f / 1024.0f) - mu * mu;
  float rstd = rsqrtf(var + 1e-5f);
  const float4 wv = ((const float4*)lnw)[t];
  const float4 bv = ((const float4*)lnb)[t];
  const float4 gv = ((const float4*)(mods + (size_t)(gi * 2 + b) * 1024))[t];
  const float4 tv = ((const float4*)(mods + (size_t)(bi * 2 + b) * 1024))[t];
  bf16x4 ov;
  ov[0] = (__bf16)(((xv.x - mu) * rstd * wv.x + bv.x) * (1.0f + gv.x) + tv.x);
  ov[1] = (__bf16)(((xv.y - mu) * rstd * wv.y + bv.y) * (1.0f + gv.y) + tv.y);
  ov[2] = (__bf16)(((xv.z - mu) * rstd * wv.z + bv.z) * (1.0f + gv.z) + tv.z);
  ov[3] = (__bf16)(((xv.w - mu) * rstd * wv.w + bv.w) * (1.0f + gv.w) + tv.w);
  *(bf16x4*)(out + (size_t)row * 1024 + t * 4) = ov;
}

// ---------------- context LN (D=768) ----------------
__global__ __launch_bounds__(256) void ctxln_kernel(const float* __restrict__ X,
                                                    const float* __restrict__ w,
                                                    const float* __restrict__ bias,
                                                    __bf16* __restrict__ out) {
  __shared__ float red[2][4];
  int row = blockIdx.x;  // 0..1023
  int t = threadIdx.x;
  const float* xp = X + (size_t)row * 768;
  float v[3];
  float s = 0.f, s2 = 0.f;
#pragma unroll
  for (int i = 0; i < 3; ++i) {
    v[i] = xp[t + i * 256];
    s += v[i];
    s2 += v[i] * v[i];
  }
  int lane = t & 63, wv_ = t >> 6;
#pragma unroll
  for (int off = 32; off > 0; off >>= 1) {
    s += __shfl_down(s, off);
    s2 += __shfl_down(s2, off);
  }
  if (lane == 0) { red[0][wv_] = s; red[1][wv_] = s2; }
  __syncthreads();
  s  = red[0][0] + red[0][1] + red[0][2] + red[0][3];
  s2 = red[1][0] + red[1][1] + red[1][2] + red[1][3];
  float mu = s * (1.0f / 768.0f);
  float var = s2 * (1.0f / 768.0f) - mu * mu;
  float rstd = rsqrtf(var + 1e-5f);
#pragma unroll
  for (int i = 0; i < 3; ++i) {
    int c = t + i * 256;
    out[(size_t)row * 768 + c] = (__bf16)((v[i] - mu) * rstd * w[c] + bias[c]);
  }
}

// ---------------- rope table: tbl[n*32+i] = (sin, cos)(n * 10000^(-2i/64)) ----------------
__global__ __launch_bounds__(256) void rope_tbl_kernel(float2* __restrict__ tbl) {
  int idx = blockIdx.x * 256 + threadIdx.x;  // 1024*32
  int n = idx >> 5, i = idx & 31;
  float inv = expf(-(float)(2 * i) * (1.0f / 64.0f) * 9.210340371976184f);  // ln(10000)
  float ang = (float)n * inv;
  tbl[idx] = make_float2(sinf(ang), cosf(ang));
}

// ---------------- rope + head-layout: X[b*Ntok+n][col0 + h*64 + 2i(+1)] -> out[bh][n][dh] bf16 ----------------
__global__ __launch_bounds__(256) void rope_kernel(const float* __restrict__ X, int ldx, int col0,
                                                   const float2* __restrict__ tbl,
                                                   __bf16* __restrict__ out, int Ntok) {
  int idx = blockIdx.x * 256 + threadIdx.x;  // B*Ntok*16*32
  int i = idx & 31;
  int h = (idx >> 5) & 15;
  int nn = idx >> 9;
  int n = nn % Ntok;
  int b = nn / Ntok;
  const float* xp = X + (size_t)(b * Ntok + n) * ldx + col0 + h * 64 + 2 * i;
  float xe = xp[0], xo = xp[1];
  float2 sc2 = tbl[n * 32 + i];
  float re = xe * sc2.y - xo * sc2.x;
  float ro = xe * sc2.x + xo * sc2.y;
  __bf16* op = out + ((size_t)(b * 16 + h) * Ntok + n) * 64 + 2 * i;
  op[0] = (__bf16)re;
  op[1] = (__bf16)ro;
}

// ---------------- V transpose: KV[b*Ntok+n][col0 + h*64 + d] -> VT[bh][d][n] bf16 ----------------
__global__ __launch_bounds__(256) void vt_kernel(const float* __restrict__ KV, int ld, int col0,
                                                 __bf16* __restrict__ VT, int Ntok) {
  __shared__ float tile[32][33];
  int bh = blockIdx.x;
  int n0 = blockIdx.y * 32, d0 = blockIdx.z * 32;
  int b = bh >> 4, h = bh & 15;
  int tx = threadIdx.x & 31, ty = threadIdx.x >> 5;
#pragma unroll
  for (int i = 0; i < 4; ++i) {
    int n = ty + i * 8;
    tile[n][tx] = KV[(size_t)(b * Ntok + n0 + n) * ld + col0 + h * 64 + d0 + tx];
  }
  __syncthreads();
#pragma unroll
  for (int i = 0; i < 4; ++i) {
    int d = ty + i * 8;
    VT[((size_t)bh * 64 + d0 + d) * Ntok + n0 + tx] = (__bf16)tile[tx][d];
  }
}

// ---------------- bf16 GEMM: C[M,N] = A[M,K] @ BT[N,K]^T (+epilogue) ----------------
// EPI: 0 = fp32 out; 1 = fp32 out + bias[col] + res[row,col]; 2 = bf16 out = gelu(acc+bias)
template <int EPI>
__global__ __launch_bounds__(256) void gemm_bt(const __bf16* __restrict__ A,
                                               const __bf16* __restrict__ BT,
                                               const float* __restrict__ bias,
                                               const float* __restrict__ res,
                                               void* __restrict__ outv,
                                               int M, int N, int K) {
  __shared__ __bf16 sA[128 * 32];
  __shared__ __bf16 sB[128 * 32];
  const int t = threadIdx.x;
  const int w = t >> 6, lane = t & 63;
  const int lr = lane & 15, lg = lane >> 4;
  const int bm = blockIdx.x, bn = blockIdx.y;
  const int wm = (w >> 1) * 64, wn = (w & 1) * 64;
  f32x4 acc[4][4] = {};
  for (int kt = 0; kt < K; kt += 32) {
#pragma unroll
    for (int i = 0; i < 2; ++i) {
      int e = (i * 256 + t) * 8;
      int row = e >> 5, col = e & 31;
      gload16(A + (size_t)(bm * 128 + row) * K + kt + col, sA + e);
      gload16(BT + (size_t)(bn * 128 + row) * K + kt + col, sB + e);
    }
    __syncthreads();
    bf16x8 af[4], bfr[4];
#pragma unroll
    for (int mi = 0; mi < 4; ++mi)
      af[mi] = *(const bf16x8*)(sA + (wm + mi * 16 + lr) * 32 + lg * 8);
#pragma unroll
    for (int ni = 0; ni < 4; ++ni)
      bfr[ni] = *(const bf16x8*)(sB + (wn + ni * 16 + lr) * 32 + lg * 8);
#pragma unroll
    for (int mi = 0; mi < 4; ++mi)
#pragma unroll
      for (int ni = 0; ni < 4; ++ni)
        acc[mi][ni] = __builtin_amdgcn_mfma_f32_16x16x32_bf16(af[mi], bfr[ni], acc[mi][ni], 0, 0, 0);
    __syncthreads();
  }
#pragma unroll
  for (int mi = 0; mi < 4; ++mi) {
    int row = bm * 128 + wm + mi * 16 + lg * 4;
#pragma unroll
    for (int ni = 0; ni < 4; ++ni) {
      int col = bn * 128 + wn + ni * 16 + lr;
#pragma unroll
      for (int r = 0; r < 4; ++r) {
        float v = acc[mi][ni][r];
        size_t off = (size_t)(row + r) * N + col;
        if (EPI == 0) {
          ((float*)outv)[off] = v;
        } else if (EPI == 1) {
          ((float*)outv)[off] = v + bias[col] + res[off];
        } else {
          float xg = v + bias[col];
          ((__bf16*)outv)[off] = (__bf16)(0.5f * xg * (1.0f + erff(xg * 0.7071067811865475f)));
        }
      }
    }
  }
}

// ---------------- fused attention: per wave 16 q-rows, online softmax, k-tiles of 32 ----------------
// Qr[bh][n][dh], Kr[bh][nk][dh], VT[bh][dh][nk]; O token-major [b*1024+n][h*64+dh] bf16
__global__ __launch_bounds__(256) void attn_kernel(const __bf16* __restrict__ Qr,
                                                   const __bf16* __restrict__ Kr,
                                                   const __bf16* __restrict__ VT,
                                                   __bf16* __restrict__ O,
                                                   int Nq, int Nk) {
  __shared__ __bf16 Pl[4][16 * 32];
  const int t = threadIdx.x, w = t >> 6, lane = t & 63;
  const int lr = lane & 15, lg = lane >> 4;
  const int bh = blockIdx.y, q0 = blockIdx.x * 64 + w * 16;
  const int b = bh >> 4, h = bh & 15;
  bf16x8 qf[2];
#pragma unroll
  for (int kh = 0; kh < 2; ++kh)
    qf[kh] = *(const bf16x8*)(Qr + ((size_t)bh * Nq + q0 + lr) * 64 + kh * 32 + lg * 8);
  f32x4 accO[4] = {};
  float mrow[4], lrow[4];
#pragma unroll
  for (int r = 0; r < 4; ++r) { mrow[r] = -INFINITY; lrow[r] = 0.f; }
  for (int kt = 0; kt < Nk; kt += 32) {
    f32x4 s[2] = {};
#pragma unroll
    for (int nf = 0; nf < 2; ++nf) {
#pragma unroll
      for (int kh = 0; kh < 2; ++kh) {
        bf16x8 kf = *(const bf16x8*)(Kr + ((size_t)bh * Nk + kt + nf * 16 + lr) * 64 + kh * 32 + lg * 8);
        s[nf] = __builtin_amdgcn_mfma_f32_16x16x32_bf16(qf[kh], kf, s[nf], 0, 0, 0);
      }
    }
    float p0s[4], p1s[4];
#pragma unroll
    for (int r = 0; r < 4; ++r) {
      float a0 = s[0][r] * 0.125f, a1 = s[1][r] * 0.125f;
      float tm = fmaxf(a0, a1);
#pragma unroll
      for (int off = 1; off < 16; off <<= 1) tm = fmaxf(tm, __shfl_xor(tm, off));
      float mnew = fmaxf(mrow[r], tm);
      float resc = __expf(mrow[r] - mnew);
      float p0 = __expf(a0 - mnew), p1 = __expf(a1 - mnew);
      float rs = p0 + p1;
#pragma unroll
      for (int off = 1; off < 16; off <<= 1) rs += __shfl_xor(rs, off);
      lrow[r] = lrow[r] * resc + rs;
      mrow[r] = mnew;
#pragma unroll
      for (int df = 0; df < 4; ++df) accO[df][r] *= resc;
      p0s[r] = p0;
      p1s[r] = p1;
    }
    __syncthreads();  // protect previous iteration's P reads (WAR)
#pragma unroll
    for (int r = 0; r < 4; ++r) {
      Pl[w][(lg * 4 + r) * 32 + lr] = (__bf16)p0s[r];
      Pl[w][(lg * 4 + r) * 32 + 16 + lr] = (__bf16)p1s[r];
    }
    __syncthreads();  // P visible before A-frag read
    bf16x8 pa = *(const bf16x8*)(&Pl[w][lr * 32 + lg * 8]);
#pragma unroll
    for (int df = 0; df < 4; ++df) {
      bf16x8 vf = *(const bf16x8*)(VT + ((size_t)bh * 64 + df * 16 + lr) * Nk + kt + lg * 8);
      accO[df] = __builtin_amdgcn_mfma_f32_16x16x32_bf16(pa, vf, accO[df], 0, 0, 0);
    }
  }
#pragma unroll
  for (int r = 0; r < 4; ++r) {
    float inv = 1.0f / lrow[r];
    int n = q0 + lg * 4 + r;
#pragma unroll
    for (int df = 0; df < 4; ++df) {
      O[(size_t)(b * 1024 + n) * 1024 + h * 64 + df * 16 + lr] = (__bf16)(accO[df][r] * inv);
    }
  }
}

extern "C" void kernel_launch(void* const* d_in, const int* in_sizes, int n_in,
                              void* d_out, int out_size, void* d_ws, size_t ws_size,
                              hipStream_t stream) {
  (void)in_sizes; (void)n_in; (void)out_size; (void)ws_size;
  const float* x       = (const float*)d_in[0];
  const float* cond    = (const float*)d_in[1];
  const float* ctx     = (const float*)d_in[2];
  const float* ln1_w   = (const float*)d_in[3];
  const float* ln1_b   = (const float*)d_in[4];
  const float* g1_w    = (const float*)d_in[5];
  const float* g1_b    = (const float*)d_in[6];
  const float* b1_w    = (const float*)d_in[7];
  const float* b1_b    = (const float*)d_in[8];
  const float* ln2_w   = (const float*)d_in[9];
  const float* ln2_b   = (const float*)d_in[10];
  const float* g2_w    = (const float*)d_in[11];
  const float* g2_b    = (const float*)d_in[12];
  const float* b2_w    = (const float*)d_in[13];
  const float* b2_b    = (const float*)d_in[14];
  const float* sa_wq   = (const float*)d_in[15];
  const float* sa_wkv  = (const float*)d_in[16];
  const float* sa_wo   = (const float*)d_in[17];
  const float* sa_bo   = (const float*)d_in[18];
  const float* ca_lnc_w = (const float*)d_in[19];
  const float* ca_lnc_b = (const float*)d_in[20];
  const float* ca_wq   = (const float*)d_in[21];
  const float* ca_wkv  = (const float*)d_in[22];
  const float* ca_wo   = (const float*)d_in[23];
  const float* ca_bo   = (const float*)d_in[24];
  const float* ff_w1   = (const float*)d_in[25];
  const float* ff_b1   = (const float*)d_in[26];
  const float* ff_w2   = (const float*)d_in[27];
  const float* ff_b2   = (const float*)d_in[28];
  float* out = (float*)d_out;

  char* ws = (char*)d_ws;
  size_t o = 0;
  auto alloc = [&](size_t bytes) {
    void* p = ws + o;
    o += (bytes + 255) & ~(size_t)255;
    return p;
  };

  __bf16* wqT   = (__bf16*)alloc(1024ull * 1024 * 2);
  __bf16* wkvT  = (__bf16*)alloc(2048ull * 1024 * 2);
  __bf16* woT   = (__bf16*)alloc(1024ull * 1024 * 2);
  __bf16* cwqT  = (__bf16*)alloc(1024ull * 1024 * 2);
  __bf16* cwkvT = (__bf16*)alloc(2048ull * 768 * 2);
  __bf16* cwoT  = (__bf16*)alloc(1024ull * 1024 * 2);
  __bf16* ff1T  = (__bf16*)alloc(4096ull * 1024 * 2);
  __bf16* ff2T  = (__bf16*)alloc(1024ull * 4096 * 2);
  float*  mods  = (float*)alloc(4ull * 2 * 1024 * 4);
  float2* tbl   = (float2*)alloc(1024ull * 32 * 8);
  __bf16* ain   = (__bf16*)alloc(2048ull * 1024 * 2);
  float*  Qf    = (float*)alloc(2048ull * 1024 * 4);
  float*  KVf   = (float*)alloc(2048ull * 2048 * 4);
  __bf16* Qr    = (__bf16*)alloc(2048ull * 1024 * 2);
  __bf16* Kr    = (__bf16*)alloc(2048ull * 1024 * 2);
  __bf16* VTb   = (__bf16*)alloc(2048ull * 1024 * 2);
  __bf16* Ob    = (__bf16*)alloc(2048ull * 1024 * 2);
  __bf16* ctxn  = (__bf16*)alloc(1024ull * 768 * 2);
  float*  x1    = (float*)alloc(2048ull * 1024 * 4);
  float*  x2    = (float*)alloc(2048ull * 1024 * 4);
  __bf16* hb    = (__bf16*)KVf;  // reuse 16MB KV region for FFN hidden (2048x4096 bf16)

  // ---- weight prep (every call; deterministic) ----
  wt_kernel<<<dim3(32, 32), 256, 0, stream>>>(sa_wq, wqT, 1024, 1024);
  wt_kernel<<<dim3(64, 32), 256, 0, stream>>>(sa_wkv, wkvT, 1024, 2048);
  wt_kernel<<<dim3(32, 32), 256, 0, stream>>>(sa_wo, woT, 1024, 1024);
  wt_kernel<<<dim3(32, 32), 256, 0, stream>>>(ca_wq, cwqT, 1024, 1024);
  wt_kernel<<<dim3(64, 24), 256, 0, stream>>>(ca_wkv, cwkvT, 768, 2048);
  wt_kernel<<<dim3(32, 32), 256, 0, stream>>>(ca_wo, cwoT, 1024, 1024);
  wt_kernel<<<dim3(128, 32), 256, 0, stream>>>(ff_w1, ff1T, 1024, 4096);
  wt_kernel<<<dim3(32, 128), 256, 0, stream>>>(ff_w2, ff2T, 4096, 1024);
  rope_tbl_kernel<<<128, 256, 0, stream>>>(tbl);
  mod_gemv_kernel<<<dim3(4, 2, 4), 256, 0, stream>>>(cond, g1_w, g1_b, b1_w, b1_b,
                                                     g2_w, g2_b, b2_w, b2_b, mods);

  // ---- self attention ----
  adaln_kernel<<<2048, 256, 0, stream>>>(x, ln1_w, ln1_b, mods, 0, 1, ain);
  gemm_bt<0><<<dim3(16, 8), 256, 0, stream>>>(ain, wqT, nullptr, nullptr, Qf, 2048, 1024, 1024);
  gemm_bt<0><<<dim3(16, 16), 256, 0, stream>>>(ain, wkvT, nullptr, nullptr, KVf, 2048, 2048, 1024);
  rope_kernel<<<4096, 256, 0, stream>>>(Qf, 1024, 0, tbl, Qr, 1024);
  rope_kernel<<<4096, 256, 0, stream>>>(KVf, 2048, 0, tbl, Kr, 1024);
  vt_kernel<<<dim3(32, 32, 2), 256, 0, stream>>>(KVf, 2048, 1024, VTb, 1024);
  attn_kernel<<<dim3(16, 32), 256, 0, stream>>>(Qr, Kr, VTb, Ob, 1024, 1024);
  gemm_bt<1><<<dim3(16, 8), 256, 0, stream>>>(Ob, woT, sa_bo, x, x1, 2048, 1024, 1024);

  // ---- cross attention ----
  adaln_kernel<<<2048, 256, 0, stream>>>(x1, ln1_w, ln1_b, mods, 0, 1, ain);
  ctxln_kernel<<<1024, 256, 0, stream>>>(ctx, ca_lnc_w, ca_lnc_b, ctxn);
  gemm_bt<0><<<dim3(16, 8), 256, 0, stream>>>(ain, cwqT, nullptr, nullptr, Qf, 2048, 1024, 1024);
  gemm_bt<0><<<dim3(8, 16), 256, 0, stream>>>(ctxn, cwkvT, nullptr, nullptr, KVf, 1024, 2048, 768);
  rope_kernel<<<4096, 256, 0, stream>>>(Qf, 1024, 0, tbl, Qr, 1024);
  rope_kernel<<<2048, 256, 0, stream>>>(KVf, 2048, 0, tbl, Kr, 512);
  vt_kernel<<<dim3(32, 16, 2), 256, 0, stream>>>(KVf, 2048, 1024, VTb, 512);
  attn_kernel<<<dim3(16, 32), 256, 0, stream>>>(Qr, Kr, VTb, Ob, 1024, 512);
  gemm_bt<1><<<dim3(16, 8), 256, 0, stream>>>(Ob, cwoT, ca_bo, x1, x2, 2048, 1024, 1024);

  // ---- FFN ----
  adaln_kernel<<<2048, 256, 0, stream>>>(x2, ln2_w, ln2_b, mods, 2, 3, ain);
  gemm_bt<2><<<dim3(16, 32), 256, 0, stream>>>(ain, ff1T, ff_b1, nullptr, hb, 2048, 4096, 1024);
  gemm_bt<1><<<dim3(16, 8), 256, 0, stream>>>(hb, ff2T, ff_b2, x2, out, 2048, 1024, 4096);
}

// Round 2
// 428.771 us; speedup vs baseline: 1.1780x; 1.1780x over previous
//
#include <hip/hip_runtime.h>
#include <hip/hip_bf16.h>
#include <math.h>

// B=2 N=1024 M=512 D=1024 H=16 DH=64 MID=1024 DC=768 MULT=4
// All GEMMs: bf16 inputs (pre-converted), fp32 MFMA accumulate.
// ws usage ~92.8 MB (same as round 0, which passed).

typedef float f32x4 __attribute__((ext_vector_type(4)));
typedef __bf16 bf16x8 __attribute__((ext_vector_type(8)));
typedef __bf16 bf16x4 __attribute__((ext_vector_type(4)));

#define DEVI __device__ __forceinline__

DEVI void gload16(const void* g, void* l) {
  __builtin_amdgcn_global_load_lds((const __attribute__((address_space(1))) void*)g,
                                   (__attribute__((address_space(3))) void*)l, 16, 0, 0);
}

// ---------------- weight fp32 -> bf16 transposed: WT[n][k] = W[k][n] ----------------
__global__ __launch_bounds__(256) void wt_kernel(const float* __restrict__ W,
                                                 __bf16* __restrict__ WT, int K, int N) {
  __shared__ float tile[32][33];
  int n0 = blockIdx.x * 32, k0 = blockIdx.y * 32;
  int tx = threadIdx.x & 31, ty = threadIdx.x >> 5;
#pragma unroll
  for (int i = 0; i < 4; ++i) {
    int k = ty + i * 8;
    tile[k][tx] = W[(size_t)(k0 + k) * N + n0 + tx];
  }
  __syncthreads();
#pragma unroll
  for (int i = 0; i < 4; ++i) {
    int n = ty + i * 8;
    WT[(size_t)(n0 + n) * K + k0 + tx] = (__bf16)tile[tx][n];
  }
}

// ---------------- cond @ {g1,b1,g2,b2} (B=2, tiny GEMV) ----------------
__global__ __launch_bounds__(256) void mod_gemv_kernel(
    const float* __restrict__ cond,
    const float* __restrict__ g1w, const float* __restrict__ g1b,
    const float* __restrict__ b1w, const float* __restrict__ b1b,
    const float* __restrict__ g2w, const float* __restrict__ g2b,
    const float* __restrict__ b2w, const float* __restrict__ b2b,
    float* __restrict__ mods) {
  __shared__ float sc[1024];
  int b = blockIdx.y, mat = blockIdx.z;
  const float* W  = (mat == 0) ? g1w : (mat == 1) ? b1w : (mat == 2) ? g2w : b2w;
  const float* Bv = (mat == 0) ? g1b : (mat == 1) ? b1b : (mat == 2) ? g2b : b2b;
  for (int i = threadIdx.x; i < 1024; i += 256) sc[i] = cond[b * 1024 + i];
  __syncthreads();
  int d = blockIdx.x * 256 + threadIdx.x;
  float acc = 0.f;
#pragma unroll 8
  for (int k = 0; k < 1024; ++k) acc += sc[k] * W[(size_t)k * 1024 + d];
  mods[(size_t)(mat * 2 + b) * 1024 + d] = acc + Bv[d];
}

// ---------------- adaLN: out_bf16 = LN(x)*(1+g)+bt ----------------
__global__ __launch_bounds__(256) void adaln_kernel(const float* __restrict__ X,
                                                    const float* __restrict__ lnw,
                                                    const float* __restrict__ lnb,
                                                    const float* __restrict__ mods,
                                                    int gi, int bi,
                                                    __bf16* __restrict__ out) {
  __shared__ float red[2][4];
  int row = blockIdx.x;  // 0..2047
  int b = row >> 10;
  int t = threadIdx.x;
  const float4 xv = ((const float4*)(X + (size_t)row * 1024))[t];
  float s  = xv.x + xv.y + xv.z + xv.w;
  float s2 = xv.x * xv.x + xv.y * xv.y + xv.z * xv.z + xv.w * xv.w;
  int lane = t & 63, w = t >> 6;
#pragma unroll
  for (int off = 32; off > 0; off >>= 1) {
    s += __shfl_down(s, off);
    s2 += __shfl_down(s2, off);
  }
  if (lane == 0) { red[0][w] = s; red[1][w] = s2; }
  __syncthreads();
  s  = red[0][0] + red[0][1] + red[0][2] + red[0][3];
  s2 = red[1][0] + red[1][1] + red[1][2] + red[1][3];
  float mu = s * (1.0f / 1024.0f);
  float var = s2 * (1.0f / 1024.0f) - mu * mu;
  float rstd = rsqrtf(var + 1e-5f);
  const float4 wv = ((const float4*)lnw)[t];
  const float4 bv = ((const float4*)lnb)[t];
  const float4 gv = ((const float4*)(mods + (size_t)(gi * 2 + b) * 1024))[t];
  const float4 tv = ((const float4*)(mods + (size_t)(bi * 2 + b) * 1024))[t];
  bf16x4 ov;
  ov[0] = (__bf16)(((xv.x - mu) * rstd * wv.x + bv.x) * (1.0f + gv.x) + tv.x);
  ov[1] = (__bf16)(((xv.y - mu) * rstd * wv.y + bv.y) * (1.0f + gv.y) + tv.y);
  ov[2] = (__bf16)(((xv.z - mu) * rstd * wv.z + bv.z) * (1.0f + gv.z) + tv.z);
  ov[3] = (__bf16)(((xv.w - mu) * rstd * wv.w + bv.w) * (1.0f + gv.w) + tv.w);
  *(bf16x4*)(out + (size_t)row * 1024 + t * 4) = ov;
}

// ---------------- context LN (D=768) ----------------
__global__ __launch_bounds__(256) void ctxln_kernel(const float* __restrict__ X,
                                                    const float* __restrict__ w,
                                                    const float* __restrict__ bias,
                                                    __bf16* __restrict__ out) {
  __shared__ float red[2][4];
  int row = blockIdx.x;  // 0..1023
  int t = threadIdx.x;
  const float* xp = X + (size_t)row * 768;
  float v[3];
  float s = 0.f, s2 = 0.f;
#pragma unroll
  for (int i = 0; i < 3; ++i) {
    v[i] = xp[t + i * 256];
    s += v[i];
    s2 += v[i] * v[i];
  }
  int lane = t & 63, wv_ = t >> 6;
#pragma unroll
  for (int off = 32; off > 0; off >>= 1) {
    s += __shfl_down(s, off);
    s2 += __shfl_down(s2, off);
  }
  if (lane == 0) { red[0][wv_] = s; red[1][wv_] = s2; }
  __syncthreads();
  s  = red[0][0] + red[0][1] + red[0][2] + red[0][3];
  s2 = red[1][0] + red[1][1] + red[1][2] + red[1][3];
  float mu = s * (1.0f / 768.0f);
  float var = s2 * (1.0f / 768.0f) - mu * mu;
  float rstd = rsqrtf(var + 1e-5f);
#pragma unroll
  for (int i = 0; i < 3; ++i) {
    int c = t + i * 256;
    out[(size_t)row * 768 + c] = (__bf16)((v[i] - mu) * rstd * w[c] + bias[c]);
  }
}

// ---------------- rope table ----------------
__global__ __launch_bounds__(256) void rope_tbl_kernel(float2* __restrict__ tbl) {
  int idx = blockIdx.x * 256 + threadIdx.x;  // 1024*32
  int n = idx >> 5, i = idx & 31;
  float inv = expf(-(float)(2 * i) * (1.0f / 64.0f) * 9.210340371976184f);  // ln(10000)
  float ang = (float)n * inv;
  tbl[idx] = make_float2(sinf(ang), cosf(ang));
}

// ---------------- rope + head-layout ----------------
__global__ __launch_bounds__(256) void rope_kernel(const float* __restrict__ X, int ldx, int col0,
                                                   const float2* __restrict__ tbl,
                                                   __bf16* __restrict__ out, int Ntok) {
  int idx = blockIdx.x * 256 + threadIdx.x;  // B*Ntok*16*32
  int i = idx & 31;
  int h = (idx >> 5) & 15;
  int nn = idx >> 9;
  int n = nn % Ntok;
  int b = nn / Ntok;
  const float* xp = X + (size_t)(b * Ntok + n) * ldx + col0 + h * 64 + 2 * i;
  float xe = xp[0], xo = xp[1];
  float2 sc2 = tbl[n * 32 + i];
  float re = xe * sc2.y - xo * sc2.x;
  float ro = xe * sc2.x + xo * sc2.y;
  __bf16* op = out + ((size_t)(b * 16 + h) * Ntok + n) * 64 + 2 * i;
  op[0] = (__bf16)re;
  op[1] = (__bf16)ro;
}

// ---------------- V transpose ----------------
__global__ __launch_bounds__(256) void vt_kernel(const float* __restrict__ KV, int ld, int col0,
                                                 __bf16* __restrict__ VT, int Ntok) {
  __shared__ float tile[32][33];
  int bh = blockIdx.x;
  int n0 = blockIdx.y * 32, d0 = blockIdx.z * 32;
  int b = bh >> 4, h = bh & 15;
  int tx = threadIdx.x & 31, ty = threadIdx.x >> 5;
#pragma unroll
  for (int i = 0; i < 4; ++i) {
    int n = ty + i * 8;
    tile[n][tx] = KV[(size_t)(b * Ntok + n0 + n) * ld + col0 + h * 64 + d0 + tx];
  }
  __syncthreads();
#pragma unroll
  for (int i = 0; i < 4; ++i) {
    int d = ty + i * 8;
    VT[((size_t)bh * 64 + d0 + d) * Ntok + n0 + tx] = (__bf16)tile[tx][d];
  }
}

// ---------------- pipelined bf16 GEMM: C[M,N] = A[M,K] @ BT[N,K]^T ----------------
// 4 waves, wave tile (BM/2)x(BN/2), BK=32, double-buffered LDS, 2-phase pipeline.
// EPI: 0 fp32 out; 1 fp32 out+bias+res; 2 bf16 gelu(acc+bias); 3 fp32 partial at slice z
template <int BM, int BN, int EPI>
__global__ __launch_bounds__(256) void gemm3(const __bf16* __restrict__ A,
                                             const __bf16* __restrict__ BT,
                                             const float* __restrict__ bias,
                                             const float* __restrict__ res,
                                             void* __restrict__ outv,
                                             int M, int N, int K, int kslices) {
  constexpr int MI = BM / 32, NI = BN / 32;
  __shared__ __bf16 sA[2][BM * 32];
  __shared__ __bf16 sB[2][BN * 32];
  const int t = threadIdx.x;
  const int w = t >> 6, lane = t & 63;
  const int lr = lane & 15, lg = lane >> 4;
  const int bm = blockIdx.x, bn = blockIdx.y, bz = blockIdx.z;
  const int wm = (w >> 1) * (BM / 2), wn = (w & 1) * (BN / 2);
  const int kper = K / kslices;
  const int k0 = bz * kper;
  f32x4 acc[MI][NI] = {};

  auto stage = [&](int buf, int kt) {
#pragma unroll
    for (int i = 0; i < BM / 64; ++i) {
      int e = (i * 256 + t) * 8;
      int row = e >> 5, col = e & 31;
      gload16(A + (size_t)(bm * BM + row) * K + kt + col, &sA[buf][e]);
    }
#pragma unroll
    for (int i = 0; i < BN / 64; ++i) {
      int e = (i * 256 + t) * 8;
      int row = e >> 5, col = e & 31;
      gload16(BT + (size_t)(bn * BN + row) * K + kt + col, &sB[buf][e]);
    }
  };

  stage(0, k0);
  __syncthreads();
  int cur = 0;
  for (int kt = k0; kt < k0 + kper; kt += 32) {
    if (kt + 32 < k0 + kper) stage(cur ^ 1, kt + 32);  // prefetch next tile (in flight during MFMA)
    bf16x8 af[MI], bfr[NI];
#pragma unroll
    for (int mi = 0; mi < MI; ++mi)
      af[mi] = *(const bf16x8*)(&sA[cur][(wm + mi * 16 + lr) * 32 + lg * 8]);
#pragma unroll
    for (int ni = 0; ni < NI; ++ni)
      bfr[ni] = *(const bf16x8*)(&sB[cur][(wn + ni * 16 + lr) * 32 + lg * 8]);
#pragma unroll
    for (int mi = 0; mi < MI; ++mi)
#pragma unroll
      for (int ni = 0; ni < NI; ++ni)
        acc[mi][ni] = __builtin_amdgcn_mfma_f32_16x16x32_bf16(af[mi], bfr[ni], acc[mi][ni], 0, 0, 0);
    __syncthreads();  // drains vmcnt(0): next buffer ready; everyone done with cur
    cur ^= 1;
  }
#pragma unroll
  for (int mi = 0; mi < MI; ++mi) {
    int row = bm * BM + wm + mi * 16 + lg * 4;
#pragma unroll
    for (int ni = 0; ni < NI; ++ni) {
      int col = bn * BN + wn + ni * 16 + lr;
#pragma unroll
      for (int r = 0; r < 4; ++r) {
        float v = acc[mi][ni][r];
        size_t off = (size_t)(row + r) * N + col;
        if (EPI == 0) {
          ((float*)outv)[off] = v;
        } else if (EPI == 1) {
          ((float*)outv)[off] = v + bias[col] + res[off];
        } else if (EPI == 2) {
          float xg = v + bias[col];
          ((__bf16*)outv)[off] = (__bf16)(0.5f * xg * (1.0f + erff(xg * 0.7071067811865475f)));
        } else {
          ((float*)outv)[(size_t)bz * M * N + off] = v;
        }
      }
    }
  }
}

// ---------------- split-K reduce for ff2: out = p0+p1+bias+res ----------------
__global__ __launch_bounds__(256) void ff2red_kernel(const float* __restrict__ part,
                                                     const float* __restrict__ bias,
                                                     const float* __restrict__ res,
                                                     float* __restrict__ out, int MN, int N) {
  int idx = blockIdx.x * 256 + threadIdx.x;
  float4 p0 = ((const float4*)part)[idx];
  float4 p1 = ((const float4*)(part + MN))[idx];
  float4 rr = ((const float4*)res)[idx];
  int colb = (idx * 4) & (N - 1);
  float4 bb = *(const float4*)(bias + colb);
  float4 o;
  o.x = p0.x + p1.x + bb.x + rr.x;
  o.y = p0.y + p1.y + bb.y + rr.y;
  o.z = p0.z + p1.z + bb.z + rr.z;
  o.w = p0.w + p1.w + bb.w + rr.w;
  ((float4*)out)[idx] = o;
}

// ---------------- fused attention (unchanged) ----------------
__global__ __launch_bounds__(256) void attn_kernel(const __bf16* __restrict__ Qr,
                                                   const __bf16* __restrict__ Kr,
                                                   const __bf16* __restrict__ VT,
                                                   __bf16* __restrict__ O,
                                                   int Nq, int Nk) {
  __shared__ __bf16 Pl[4][16 * 32];
  const int t = threadIdx.x, w = t >> 6, lane = t & 63;
  const int lr = lane & 15, lg = lane >> 4;
  const int bh = blockIdx.y, q0 = blockIdx.x * 64 + w * 16;
  const int b = bh >> 4, h = bh & 15;
  bf16x8 qf[2];
#pragma unroll
  for (int kh = 0; kh < 2; ++kh)
    qf[kh] = *(const bf16x8*)(Qr + ((size_t)bh * Nq + q0 + lr) * 64 + kh * 32 + lg * 8);
  f32x4 accO[4] = {};
  float mrow[4], lrow[4];
#pragma unroll
  for (int r = 0; r < 4; ++r) { mrow[r] = -INFINITY; lrow[r] = 0.f; }
  for (int kt = 0; kt < Nk; kt += 32) {
    f32x4 s[2] = {};
#pragma unroll
    for (int nf = 0; nf < 2; ++nf) {
#pragma unroll
      for (int kh = 0; kh < 2; ++kh) {
        bf16x8 kf = *(const bf16x8*)(Kr + ((size_t)bh * Nk + kt + nf * 16 + lr) * 64 + kh * 32 + lg * 8);
        s[nf] = __builtin_amdgcn_mfma_f32_16x16x32_bf16(qf[kh], kf, s[nf], 0, 0, 0);
      }
    }
    float p0s[4], p1s[4];
#pragma unroll
    for (int r = 0; r < 4; ++r) {
      float a0 = s[0][r] * 0.125f, a1 = s[1][r] * 0.125f;
      float tm = fmaxf(a0, a1);
#pragma unroll
      for (int off = 1; off < 16; off <<= 1) tm = fmaxf(tm, __shfl_xor(tm, off));
      float mnew = fmaxf(mrow[r], tm);
      float resc = __expf(mrow[r] - mnew);
      float p0 = __expf(a0 - mnew), p1 = __expf(a1 - mnew);
      float rs = p0 + p1;
#pragma unroll
      for (int off = 1; off < 16; off <<= 1) rs += __shfl_xor(rs, off);
      lrow[r] = lrow[r] * resc + rs;
      mrow[r] = mnew;
#pragma unroll
      for (int df = 0; df < 4; ++df) accO[df][r] *= resc;
      p0s[r] = p0;
      p1s[r] = p1;
    }
    __syncthreads();
#pragma unroll
    for (int r = 0; r < 4; ++r) {
      Pl[w][(lg * 4 + r) * 32 + lr] = (__bf16)p0s[r];
      Pl[w][(lg * 4 + r) * 32 + 16 + lr] = (__bf16)p1s[r];
    }
    __syncthreads();
    bf16x8 pa = *(const bf16x8*)(&Pl[w][lr * 32 + lg * 8]);
#pragma unroll
    for (int df = 0; df < 4; ++df) {
      bf16x8 vf = *(const bf16x8*)(VT + ((size_t)bh * 64 + df * 16 + lr) * Nk + kt + lg * 8);
      accO[df] = __builtin_amdgcn_mfma_f32_16x16x32_bf16(pa, vf, accO[df], 0, 0, 0);
    }
  }
#pragma unroll
  for (int r = 0; r < 4; ++r) {
    float inv = 1.0f / lrow[r];
    int n = q0 + lg * 4 + r;
#pragma unroll
    for (int df = 0; df < 4; ++df) {
      O[(size_t)(b * 1024 + n) * 1024 + h * 64 + df * 16 + lr] = (__bf16)(accO[df][r] * inv);
    }
  }
}

extern "C" void kernel_launch(void* const* d_in, const int* in_sizes, int n_in,
                              void* d_out, int out_size, void* d_ws, size_t ws_size,
                              hipStream_t stream) {
  (void)in_sizes; (void)n_in; (void)out_size; (void)ws_size;
  const float* x       = (const float*)d_in[0];
  const float* cond    = (const float*)d_in[1];
  const float* ctx     = (const float*)d_in[2];
  const float* ln1_w   = (const float*)d_in[3];
  const float* ln1_b   = (const float*)d_in[4];
  const float* g1_w    = (const float*)d_in[5];
  const float* g1_b    = (const float*)d_in[6];
  const float* b1_w    = (const float*)d_in[7];
  const float* b1_b    = (const float*)d_in[8];
  const float* ln2_w   = (const float*)d_in[9];
  const float* ln2_b   = (const float*)d_in[10];
  const float* g2_w    = (const float*)d_in[11];
  const float* g2_b    = (const float*)d_in[12];
  const float* b2_w    = (const float*)d_in[13];
  const float* b2_b    = (const float*)d_in[14];
  const float* sa_wq   = (const float*)d_in[15];
  const float* sa_wkv  = (const float*)d_in[16];
  const float* sa_wo   = (const float*)d_in[17];
  const float* sa_bo   = (const float*)d_in[18];
  const float* ca_lnc_w = (const float*)d_in[19];
  const float* ca_lnc_b = (const float*)d_in[20];
  const float* ca_wq   = (const float*)d_in[21];
  const float* ca_wkv  = (const float*)d_in[22];
  const float* ca_wo   = (const float*)d_in[23];
  const float* ca_bo   = (const float*)d_in[24];
  const float* ff_w1   = (const float*)d_in[25];
  const float* ff_b1   = (const float*)d_in[26];
  const float* ff_w2   = (const float*)d_in[27];
  const float* ff_b2   = (const float*)d_in[28];
  float* out = (float*)d_out;

  char* ws = (char*)d_ws;
  size_t o = 0;
  auto alloc = [&](size_t bytes) {
    void* p = ws + o;
    o += (bytes + 255) & ~(size_t)255;
    return p;
  };

  __bf16* wqT   = (__bf16*)alloc(1024ull * 1024 * 2);
  __bf16* wkvT  = (__bf16*)alloc(2048ull * 1024 * 2);
  __bf16* woT   = (__bf16*)alloc(1024ull * 1024 * 2);
  __bf16* cwqT  = (__bf16*)alloc(1024ull * 1024 * 2);
  __bf16* cwkvT = (__bf16*)alloc(2048ull * 768 * 2);
  __bf16* cwoT  = (__bf16*)alloc(1024ull * 1024 * 2);
  __bf16* ff1T  = (__bf16*)alloc(4096ull * 1024 * 2);
  __bf16* ff2T  = (__bf16*)alloc(1024ull * 4096 * 2);
  float*  mods  = (float*)alloc(4ull * 2 * 1024 * 4);
  float2* tbl   = (float2*)alloc(1024ull * 32 * 8);
  __bf16* ain   = (__bf16*)alloc(2048ull * 1024 * 2);
  float*  Qf    = (float*)alloc(2048ull * 1024 * 4);
  float*  KVf   = (float*)alloc(2048ull * 2048 * 4);
  __bf16* ctxn  = (__bf16*)alloc(1024ull * 768 * 2);
  __bf16* Qr    = (__bf16*)alloc(2048ull * 1024 * 2);  // Qr..Ob contiguous 16MB, reused as ff2 partials
  __bf16* Kr    = (__bf16*)alloc(2048ull * 1024 * 2);
  __bf16* VTb   = (__bf16*)alloc(2048ull * 1024 * 2);
  __bf16* Ob    = (__bf16*)alloc(2048ull * 1024 * 2);
  float*  x1    = (float*)alloc(2048ull * 1024 * 4);
  float*  x2    = (float*)alloc(2048ull * 1024 * 4);
  __bf16* hb    = (__bf16*)KVf;  // FFN hidden (2048x4096 bf16) overlays KV fp32 region
  float*  pbuf  = (float*)Qr;    // ff2 split-K partials: 2 x 8MB over Qr..Ob

  // ---- weight prep ----
  wt_kernel<<<dim3(32, 32), 256, 0, stream>>>(sa_wq, wqT, 1024, 1024);
  wt_kernel<<<dim3(64, 32), 256, 0, stream>>>(sa_wkv, wkvT, 1024, 2048);
  wt_kernel<<<dim3(32, 32), 256, 0, stream>>>(sa_wo, woT, 1024, 1024);
  wt_kernel<<<dim3(32, 32), 256, 0, stream>>>(ca_wq, cwqT, 1024, 1024);
  wt_kernel<<<dim3(64, 24), 256, 0, stream>>>(ca_wkv, cwkvT, 768, 2048);
  wt_kernel<<<dim3(32, 32), 256, 0, stream>>>(ca_wo, cwoT, 1024, 1024);
  wt_kernel<<<dim3(128, 32), 256, 0, stream>>>(ff_w1, ff1T, 1024, 4096);
  wt_kernel<<<dim3(32, 128), 256, 0, stream>>>(ff_w2, ff2T, 4096, 1024);
  rope_tbl_kernel<<<128, 256, 0, stream>>>(tbl);
  mod_gemv_kernel<<<dim3(4, 2, 4), 256, 0, stream>>>(cond, g1_w, g1_b, b1_w, b1_b,
                                                     g2_w, g2_b, b2_w, b2_b, mods);

  // ---- self attention ----
  adaln_kernel<<<2048, 256, 0, stream>>>(x, ln1_w, ln1_b, mods, 0, 1, ain);
  gemm3<128, 64, 0><<<dim3(16, 16), 256, 0, stream>>>(ain, wqT, nullptr, nullptr, Qf, 2048, 1024, 1024, 1);
  gemm3<128, 128, 0><<<dim3(16, 16), 256, 0, stream>>>(ain, wkvT, nullptr, nullptr, KVf, 2048, 2048, 1024, 1);
  rope_kernel<<<4096, 256, 0, stream>>>(Qf, 1024, 0, tbl, Qr, 1024);
  rope_kernel<<<4096, 256, 0, stream>>>(KVf, 2048, 0, tbl, Kr, 1024);
  vt_kernel<<<dim3(32, 32, 2), 256, 0, stream>>>(KVf, 2048, 1024, VTb, 1024);
  attn_kernel<<<dim3(16, 32), 256, 0, stream>>>(Qr, Kr, VTb, Ob, 1024, 1024);
  gemm3<128, 64, 1><<<dim3(16, 16), 256, 0, stream>>>(Ob, woT, sa_bo, x, x1, 2048, 1024, 1024, 1);

  // ---- cross attention ----
  adaln_kernel<<<2048, 256, 0, stream>>>(x1, ln1_w, ln1_b, mods, 0, 1, ain);
  ctxln_kernel<<<1024, 256, 0, stream>>>(ctx, ca_lnc_w, ca_lnc_b, ctxn);
  gemm3<128, 64, 0><<<dim3(16, 16), 256, 0, stream>>>(ain, cwqT, nullptr, nullptr, Qf, 2048, 1024, 1024, 1);
  gemm3<64, 128, 0><<<dim3(16, 16), 256, 0, stream>>>(ctxn, cwkvT, nullptr, nullptr, KVf, 1024, 2048, 768, 1);
  rope_kernel<<<4096, 256, 0, stream>>>(Qf, 1024, 0, tbl, Qr, 1024);
  rope_kernel<<<2048, 256, 0, stream>>>(KVf, 2048, 0, tbl, Kr, 512);
  vt_kernel<<<dim3(32, 16, 2), 256, 0, stream>>>(KVf, 2048, 1024, VTb, 512);
  attn_kernel<<<dim3(16, 32), 256, 0, stream>>>(Qr, Kr, VTb, Ob, 1024, 512);
  gemm3<128, 64, 1><<<dim3(16, 16), 256, 0, stream>>>(Ob, cwoT, ca_bo, x1, x2, 2048, 1024, 1024, 1);

  // ---- FFN ----
  adaln_kernel<<<2048, 256, 0, stream>>>(x2, ln2_w, ln2_b, mods, 2, 3, ain);
  gemm3<128, 128, 2><<<dim3(16, 32), 256, 0, stream>>>(ain, ff1T, ff_b1, nullptr, hb, 2048, 4096, 1024, 1);
  gemm3<128, 64, 3><<<dim3(16, 16, 2), 256, 0, stream>>>(hb, ff2T, nullptr, nullptr, pbuf, 2048, 1024, 4096, 2);
  ff2red_kernel<<<2048, 256, 0, stream>>>(pbuf, ff_b2, x2, out, 2048 * 1024, 1024);
}

// Round 3
// 363.957 us; speedup vs baseline: 1.3877x; 1.1781x over previous
//
#include <hip/hip_runtime.h>
#include <hip/hip_bf16.h>
#include <math.h>

// B=2 N=1024 M=512 D=1024 H=16 DH=64 MID=1024 DC=768 MULT=4
// All GEMMs: bf16 inputs (pre-converted), fp32 MFMA accumulate.

typedef float f32x4 __attribute__((ext_vector_type(4)));
typedef __bf16 bf16x8 __attribute__((ext_vector_type(8)));
typedef __bf16 bf16x4 __attribute__((ext_vector_type(4)));
typedef __bf16 bf16x2 __attribute__((ext_vector_type(2)));

#define DEVI __device__ __forceinline__

DEVI void gload16(const void* g, void* l) {
  __builtin_amdgcn_global_load_lds((const __attribute__((address_space(1))) void*)g,
                                   (__attribute__((address_space(3))) void*)l, 16, 0, 0);
}

// ---------------- weight fp32 -> bf16 transposed: WT[n][k] = W[k][n] ----------------
__global__ __launch_bounds__(256) void wt_kernel(const float* __restrict__ W,
                                                 __bf16* __restrict__ WT, int K, int N) {
  __shared__ float tile[32][33];
  int n0 = blockIdx.x * 32, k0 = blockIdx.y * 32;
  int tx = threadIdx.x & 31, ty = threadIdx.x >> 5;
#pragma unroll
  for (int i = 0; i < 4; ++i) {
    int k = ty + i * 8;
    tile[k][tx] = W[(size_t)(k0 + k) * N + n0 + tx];
  }
  __syncthreads();
#pragma unroll
  for (int i = 0; i < 4; ++i) {
    int n = ty + i * 8;
    WT[(size_t)(n0 + n) * K + k0 + tx] = (__bf16)tile[tx][n];
  }
}

// ---------------- modulation GEMV, k-split partials: part[(mat*8+ks)*2+b][1024] ----------------
__global__ __launch_bounds__(256) void mod_part_kernel(
    const float* __restrict__ cond,
    const float* __restrict__ g1w, const float* __restrict__ b1w,
    const float* __restrict__ g2w, const float* __restrict__ b2w,
    float* __restrict__ part) {
  __shared__ float sc[128];
  int dchunk = blockIdx.x, b = blockIdx.y;
  int mat = blockIdx.z >> 3, ks = blockIdx.z & 7;
  const float* W = (mat == 0) ? g1w : (mat == 1) ? b1w : (mat == 2) ? g2w : b2w;
  if (threadIdx.x < 128) sc[threadIdx.x] = cond[b * 1024 + ks * 128 + threadIdx.x];
  __syncthreads();
  int d = dchunk * 256 + threadIdx.x;
  const float* Wp = W + (size_t)(ks * 128) * 1024 + d;
  float acc = 0.f;
#pragma unroll 8
  for (int k = 0; k < 128; ++k) acc += sc[k] * Wp[(size_t)k * 1024];
  part[(size_t)(blockIdx.z * 2 + b) * 1024 + d] = acc;
}

__global__ __launch_bounds__(256) void mod_reduce_kernel(
    const float* __restrict__ part,
    const float* __restrict__ g1b, const float* __restrict__ b1b,
    const float* __restrict__ g2b, const float* __restrict__ b2b,
    float* __restrict__ mods) {
  int idx = blockIdx.x * 256 + threadIdx.x;  // 0..8191
  int mat = idx >> 11, b = (idx >> 10) & 1, d = idx & 1023;
  float s = 0.f;
#pragma unroll
  for (int ks = 0; ks < 8; ++ks) s += part[(size_t)((mat * 8 + ks) * 2 + b) * 1024 + d];
  const float* Bv = (mat == 0) ? g1b : (mat == 1) ? b1b : (mat == 2) ? g2b : b2b;
  mods[(size_t)(mat * 2 + b) * 1024 + d] = s + Bv[d];
}

// ---------------- adaLN: out_bf16 = LN(x)*(1+g)+bt ----------------
__global__ __launch_bounds__(256) void adaln_kernel(const float* __restrict__ X,
                                                    const float* __restrict__ lnw,
                                                    const float* __restrict__ lnb,
                                                    const float* __restrict__ mods,
                                                    int gi, int bi,
                                                    __bf16* __restrict__ out) {
  __shared__ float red[2][4];
  int row = blockIdx.x;  // 0..2047
  int b = row >> 10;
  int t = threadIdx.x;
  const float4 xv = ((const float4*)(X + (size_t)row * 1024))[t];
  float s  = xv.x + xv.y + xv.z + xv.w;
  float s2 = xv.x * xv.x + xv.y * xv.y + xv.z * xv.z + xv.w * xv.w;
  int lane = t & 63, w = t >> 6;
#pragma unroll
  for (int off = 32; off > 0; off >>= 1) {
    s += __shfl_down(s, off);
    s2 += __shfl_down(s2, off);
  }
  if (lane == 0) { red[0][w] = s; red[1][w] = s2; }
  __syncthreads();
  s  = red[0][0] + red[0][1] + red[0][2] + red[0][3];
  s2 = red[1][0] + red[1][1] + red[1][2] + red[1][3];
  float mu = s * (1.0f / 1024.0f);
  float var = s2 * (1.0f / 1024.0f) - mu * mu;
  float rstd = rsqrtf(var + 1e-5f);
  const float4 wv = ((const float4*)lnw)[t];
  const float4 bv = ((const float4*)lnb)[t];
  const float4 gv = ((const float4*)(mods + (size_t)(gi * 2 + b) * 1024))[t];
  const float4 tv = ((const float4*)(mods + (size_t)(bi * 2 + b) * 1024))[t];
  bf16x4 ov;
  ov[0] = (__bf16)(((xv.x - mu) * rstd * wv.x + bv.x) * (1.0f + gv.x) + tv.x);
  ov[1] = (__bf16)(((xv.y - mu) * rstd * wv.y + bv.y) * (1.0f + gv.y) + tv.y);
  ov[2] = (__bf16)(((xv.z - mu) * rstd * wv.z + bv.z) * (1.0f + gv.z) + tv.z);
  ov[3] = (__bf16)(((xv.w - mu) * rstd * wv.w + bv.w) * (1.0f + gv.w) + tv.w);
  *(bf16x4*)(out + (size_t)row * 1024 + t * 4) = ov;
}

// ---------------- context LN (D=768) ----------------
__global__ __launch_bounds__(256) void ctxln_kernel(const float* __restrict__ X,
                                                    const float* __restrict__ w,
                                                    const float* __restrict__ bias,
                                                    __bf16* __restrict__ out) {
  __shared__ float red[2][4];
  int row = blockIdx.x;  // 0..1023
  int t = threadIdx.x;
  const float* xp = X + (size_t)row * 768;
  float v[3];
  float s = 0.f, s2 = 0.f;
#pragma unroll
  for (int i = 0; i < 3; ++i) {
    v[i] = xp[t + i * 256];
    s += v[i];
    s2 += v[i] * v[i];
  }
  int lane = t & 63, wv_ = t >> 6;
#pragma unroll
  for (int off = 32; off > 0; off >>= 1) {
    s += __shfl_down(s, off);
    s2 += __shfl_down(s2, off);
  }
  if (lane == 0) { red[0][wv_] = s; red[1][wv_] = s2; }
  __syncthreads();
  s  = red[0][0] + red[0][1] + red[0][2] + red[0][3];
  s2 = red[1][0] + red[1][1] + red[1][2] + red[1][3];
  float mu = s * (1.0f / 768.0f);
  float var = s2 * (1.0f / 768.0f) - mu * mu;
  float rstd = rsqrtf(var + 1e-5f);
#pragma unroll
  for (int i = 0; i < 3; ++i) {
    int c = t + i * 256;
    out[(size_t)row * 768 + c] = (__bf16)((v[i] - mu) * rstd * w[c] + bias[c]);
  }
}

// ---------------- rope table ----------------
__global__ __launch_bounds__(256) void rope_tbl_kernel(float2* __restrict__ tbl) {
  int idx = blockIdx.x * 256 + threadIdx.x;  // 1024*32
  int n = idx >> 5, i = idx & 31;
  float inv = expf(-(float)(2 * i) * (1.0f / 64.0f) * 9.210340371976184f);  // ln(10000)
  float ang = (float)n * inv;
  tbl[idx] = make_float2(sinf(ang), cosf(ang));
}

// ---------------- rope + head-layout ----------------
__global__ __launch_bounds__(256) void rope_kernel(const float* __restrict__ X, int ldx, int col0,
                                                   const float2* __restrict__ tbl,
                                                   __bf16* __restrict__ out, int Ntok) {
  int idx = blockIdx.x * 256 + threadIdx.x;  // B*Ntok*16*32
  int i = idx & 31;
  int h = (idx >> 5) & 15;
  int nn = idx >> 9;
  int n = nn % Ntok;
  int b = nn / Ntok;
  const float* xp = X + (size_t)(b * Ntok + n) * ldx + col0 + h * 64 + 2 * i;
  float xe = xp[0], xo = xp[1];
  float2 sc2 = tbl[n * 32 + i];
  float re = xe * sc2.y - xo * sc2.x;
  float ro = xe * sc2.x + xo * sc2.y;
  __bf16* op = out + ((size_t)(b * 16 + h) * Ntok + n) * 64 + 2 * i;
  op[0] = (__bf16)re;
  op[1] = (__bf16)ro;
}

// ---------------- V transpose ----------------
__global__ __launch_bounds__(256) void vt_kernel(const float* __restrict__ KV, int ld, int col0,
                                                 __bf16* __restrict__ VT, int Ntok) {
  __shared__ float tile[32][33];
  int bh = blockIdx.x;
  int n0 = blockIdx.y * 32, d0 = blockIdx.z * 32;
  int b = bh >> 4, h = bh & 15;
  int tx = threadIdx.x & 31, ty = threadIdx.x >> 5;
#pragma unroll
  for (int i = 0; i < 4; ++i) {
    int n = ty + i * 8;
    tile[n][tx] = KV[(size_t)(b * Ntok + n0 + n) * ld + col0 + h * 64 + d0 + tx];
  }
  __syncthreads();
#pragma unroll
  for (int i = 0; i < 4; ++i) {
    int d = ty + i * 8;
    VT[((size_t)bh * 64 + d0 + d) * Ntok + n0 + tx] = (__bf16)tile[tx][d];
  }
}

// ---------------- pipelined bf16 GEMM: C[M,N] = A[M,K] @ BT[N,K]^T ----------------
// EPI: 0 fp32 out; 1 fp32 out+bias+res; 2 bf16 gelu(acc+bias); 3 fp32 partial at slice z
template <int BM, int BN, int EPI>
__global__ __launch_bounds__(256) void gemm3(const __bf16* __restrict__ A,
                                             const __bf16* __restrict__ BT,
                                             const float* __restrict__ bias,
                                             const float* __restrict__ res,
                                             void* __restrict__ outv,
                                             int M, int N, int K, int kslices) {
  constexpr int MI = BM / 32, NI = BN / 32;
  __shared__ __bf16 sA[2][BM * 32];
  __shared__ __bf16 sB[2][BN * 32];
  const int t = threadIdx.x;
  const int w = t >> 6, lane = t & 63;
  const int lr = lane & 15, lg = lane >> 4;
  const int bm = blockIdx.x, bn = blockIdx.y, bz = blockIdx.z;
  const int wm = (w >> 1) * (BM / 2), wn = (w & 1) * (BN / 2);
  const int kper = K / kslices;
  const int k0 = bz * kper;
  f32x4 acc[MI][NI] = {};

  auto stage = [&](int buf, int kt) {
#pragma unroll
    for (int i = 0; i < BM / 64; ++i) {
      int e = (i * 256 + t) * 8;
      int row = e >> 5, col = e & 31;
      gload16(A + (size_t)(bm * BM + row) * K + kt + col, &sA[buf][e]);
    }
#pragma unroll
    for (int i = 0; i < BN / 64; ++i) {
      int e = (i * 256 + t) * 8;
      int row = e >> 5, col = e & 31;
      gload16(BT + (size_t)(bn * BN + row) * K + kt + col, &sB[buf][e]);
    }
  };

  stage(0, k0);
  __syncthreads();
  int cur = 0;
  for (int kt = k0; kt < k0 + kper; kt += 32) {
    if (kt + 32 < k0 + kper) stage(cur ^ 1, kt + 32);  // prefetch next tile
    bf16x8 af[MI], bfr[NI];
#pragma unroll
    for (int mi = 0; mi < MI; ++mi)
      af[mi] = *(const bf16x8*)(&sA[cur][(wm + mi * 16 + lr) * 32 + lg * 8]);
#pragma unroll
    for (int ni = 0; ni < NI; ++ni)
      bfr[ni] = *(const bf16x8*)(&sB[cur][(wn + ni * 16 + lr) * 32 + lg * 8]);
#pragma unroll
    for (int mi = 0; mi < MI; ++mi)
#pragma unroll
      for (int ni = 0; ni < NI; ++ni)
        acc[mi][ni] = __builtin_amdgcn_mfma_f32_16x16x32_bf16(af[mi], bfr[ni], acc[mi][ni], 0, 0, 0);
    __syncthreads();
    cur ^= 1;
  }
#pragma unroll
  for (int mi = 0; mi < MI; ++mi) {
    int row = bm * BM + wm + mi * 16 + lg * 4;
#pragma unroll
    for (int ni = 0; ni < NI; ++ni) {
      int col = bn * BN + wn + ni * 16 + lr;
#pragma unroll
      for (int r = 0; r < 4; ++r) {
        float v = acc[mi][ni][r];
        size_t off = (size_t)(row + r) * N + col;
        if (EPI == 0) {
          ((float*)outv)[off] = v;
        } else if (EPI == 1) {
          ((float*)outv)[off] = v + bias[col] + res[off];
        } else if (EPI == 2) {
          float xg = v + bias[col];
          ((__bf16*)outv)[off] = (__bf16)(0.5f * xg * (1.0f + erff(xg * 0.7071067811865475f)));
        } else {
          ((float*)outv)[(size_t)bz * M * N + off] = v;
        }
      }
    }
  }
}

// ---------------- split-K reduce for ff2 ----------------
__global__ __launch_bounds__(256) void ff2red_kernel(const float* __restrict__ part,
                                                     const float* __restrict__ bias,
                                                     const float* __restrict__ res,
                                                     float* __restrict__ out, int MN, int N) {
  int idx = blockIdx.x * 256 + threadIdx.x;
  float4 p0 = ((const float4*)part)[idx];
  float4 p1 = ((const float4*)(part + MN))[idx];
  float4 rr = ((const float4*)res)[idx];
  int colb = (idx * 4) & (N - 1);
  float4 bb = *(const float4*)(bias + colb);
  float4 o;
  o.x = p0.x + p1.x + bb.x + rr.x;
  o.y = p0.y + p1.y + bb.y + rr.y;
  o.z = p0.z + p1.z + bb.z + rr.z;
  o.w = p0.w + p1.w + bb.w + rr.w;
  ((float4*)out)[idx] = o;
}

// ---------------- fused attention, swapped QK^T (S^T = K·Q^T) wave-parallel softmax ----------------
// Qr[bh][n][dh], Kr[bh][nk][dh], VT[bh][dh][nk]; O token-major [b*1024+n][h*64+dh] bf16
// Per wave: 16 q-rows. S^T fragment: q = lane&15, k = nf*16 + lg*4 + r  ->  row softmax needs
// only in-lane reduce + shfl_xor(16,32). Pl is wave-private: NO barriers in the k-loop.
__global__ __launch_bounds__(256) void attn_kernel(const __bf16* __restrict__ Qr,
                                                   const __bf16* __restrict__ Kr,
                                                   const __bf16* __restrict__ VT,
                                                   __bf16* __restrict__ O,
                                                   int Nq, int Nk) {
  __shared__ __bf16 Pl[4][16 * 32];
  const int t = threadIdx.x, w = t >> 6, lane = t & 63;
  const int lr = lane & 15, lg = lane >> 4;
  const int lsrc = lane & 48;
  const int bh = blockIdx.y, q0 = blockIdx.x * 64 + w * 16;
  const int b = bh >> 4, h = bh & 15;
  bf16x8 qf[2];
#pragma unroll
  for (int kh = 0; kh < 2; ++kh)
    qf[kh] = *(const bf16x8*)(Qr + ((size_t)bh * Nq + q0 + lr) * 64 + kh * 32 + lg * 8);
  f32x4 accO[4] = {};
  float m = -INFINITY, l = 0.f;
  for (int kt = 0; kt < Nk; kt += 32) {
    f32x4 s[2] = {};
#pragma unroll
    for (int nf = 0; nf < 2; ++nf) {
#pragma unroll
      for (int kh = 0; kh < 2; ++kh) {
        bf16x8 kf = *(const bf16x8*)(Kr + ((size_t)bh * Nk + kt + nf * 16 + lr) * 64 + kh * 32 + lg * 8);
        s[nf] = __builtin_amdgcn_mfma_f32_16x16x32_bf16(kf, qf[kh], s[nf], 0, 0, 0);
      }
    }
    float p[8];
#pragma unroll
    for (int j = 0; j < 8; ++j) p[j] = s[j >> 2][j & 3] * 0.125f;
    float tm = p[0];
#pragma unroll
    for (int j = 1; j < 8; ++j) tm = fmaxf(tm, p[j]);
    tm = fmaxf(tm, __shfl_xor(tm, 16));
    tm = fmaxf(tm, __shfl_xor(tm, 32));
    float mnew = fmaxf(m, tm);
    float resc = __expf(m - mnew);
    float rs = 0.f;
#pragma unroll
    for (int j = 0; j < 8; ++j) { p[j] = __expf(p[j] - mnew); rs += p[j]; }
    rs += __shfl_xor(rs, 16);
    rs += __shfl_xor(rs, 32);
    l = l * resc + rs;
    m = mnew;
    float rq[4];
#pragma unroll
    for (int r = 0; r < 4; ++r) rq[r] = __shfl(resc, lsrc | (lg * 4 + r));
#pragma unroll
    for (int df = 0; df < 4; ++df)
#pragma unroll
      for (int r = 0; r < 4; ++r) accO[df][r] *= rq[r];
    // write P[q=lr][k] to wave-private LDS (pairs of adjacent k)
#pragma unroll
    for (int nf = 0; nf < 2; ++nf)
#pragma unroll
      for (int jj = 0; jj < 2; ++jj) {
        bf16x2 pk;
        pk[0] = (__bf16)p[nf * 4 + 2 * jj];
        pk[1] = (__bf16)p[nf * 4 + 2 * jj + 1];
        *(bf16x2*)(&Pl[w][lr * 32 + nf * 16 + lg * 4 + 2 * jj]) = pk;
      }
    bf16x8 pa = *(const bf16x8*)(&Pl[w][lr * 32 + lg * 8]);
#pragma unroll
    for (int df = 0; df < 4; ++df) {
      bf16x8 vf = *(const bf16x8*)(VT + ((size_t)bh * 64 + df * 16 + lr) * Nk + kt + lg * 8);
      accO[df] = __builtin_amdgcn_mfma_f32_16x16x32_bf16(pa, vf, accO[df], 0, 0, 0);
    }
  }
  float lq[4];
#pragma unroll
  for (int r = 0; r < 4; ++r) lq[r] = __shfl(l, lsrc | (lg * 4 + r));
#pragma unroll
  for (int r = 0; r < 4; ++r) {
    float inv = 1.0f / lq[r];
    int n = q0 + lg * 4 + r;
#pragma unroll
    for (int df = 0; df < 4; ++df) {
      O[(size_t)(b * 1024 + n) * 1024 + h * 64 + df * 16 + lr] = (__bf16)(accO[df][r] * inv);
    }
  }
}

extern "C" void kernel_launch(void* const* d_in, const int* in_sizes, int n_in,
                              void* d_out, int out_size, void* d_ws, size_t ws_size,
                              hipStream_t stream) {
  (void)in_sizes; (void)n_in; (void)out_size; (void)ws_size;
  const float* x       = (const float*)d_in[0];
  const float* cond    = (const float*)d_in[1];
  const float* ctx     = (const float*)d_in[2];
  const float* ln1_w   = (const float*)d_in[3];
  const float* ln1_b   = (const float*)d_in[4];
  const float* g1_w    = (const float*)d_in[5];
  const float* g1_b    = (const float*)d_in[6];
  const float* b1_w    = (const float*)d_in[7];
  const float* b1_b    = (const float*)d_in[8];
  const float* ln2_w   = (const float*)d_in[9];
  const float* ln2_b   = (const float*)d_in[10];
  const float* g2_w    = (const float*)d_in[11];
  const float* g2_b    = (const float*)d_in[12];
  const float* b2_w    = (const float*)d_in[13];
  const float* b2_b    = (const float*)d_in[14];
  const float* sa_wq   = (const float*)d_in[15];
  const float* sa_wkv  = (const float*)d_in[16];
  const float* sa_wo   = (const float*)d_in[17];
  const float* sa_bo   = (const float*)d_in[18];
  const float* ca_lnc_w = (const float*)d_in[19];
  const float* ca_lnc_b = (const float*)d_in[20];
  const float* ca_wq   = (const float*)d_in[21];
  const float* ca_wkv  = (const float*)d_in[22];
  const float* ca_wo   = (const float*)d_in[23];
  const float* ca_bo   = (const float*)d_in[24];
  const float* ff_w1   = (const float*)d_in[25];
  const float* ff_b1   = (const float*)d_in[26];
  const float* ff_w2   = (const float*)d_in[27];
  const float* ff_b2   = (const float*)d_in[28];
  float* out = (float*)d_out;

  char* ws = (char*)d_ws;
  size_t o = 0;
  auto alloc = [&](size_t bytes) {
    void* p = ws + o;
    o += (bytes + 255) & ~(size_t)255;
    return p;
  };

  __bf16* wqT   = (__bf16*)alloc(1024ull * 1024 * 2);
  __bf16* wkvT  = (__bf16*)alloc(2048ull * 1024 * 2);
  __bf16* woT   = (__bf16*)alloc(1024ull * 1024 * 2);
  __bf16* cwqT  = (__bf16*)alloc(1024ull * 1024 * 2);
  __bf16* cwkvT = (__bf16*)alloc(2048ull * 768 * 2);
  __bf16* cwoT  = (__bf16*)alloc(1024ull * 1024 * 2);
  __bf16* ff1T  = (__bf16*)alloc(4096ull * 1024 * 2);
  __bf16* ff2T  = (__bf16*)alloc(1024ull * 4096 * 2);
  float*  mods  = (float*)alloc(4ull * 2 * 1024 * 4);
  float2* tbl   = (float2*)alloc(1024ull * 32 * 8);
  __bf16* ain   = (__bf16*)alloc(2048ull * 1024 * 2);
  float*  Qf    = (float*)alloc(2048ull * 1024 * 4);
  float*  KVf   = (float*)alloc(2048ull * 2048 * 4);
  __bf16* ctxn  = (__bf16*)alloc(1024ull * 768 * 2);
  __bf16* Qr    = (__bf16*)alloc(2048ull * 1024 * 2);  // Qr..Ob contiguous 16MB, reused as ff2 partials
  __bf16* Kr    = (__bf16*)alloc(2048ull * 1024 * 2);
  __bf16* VTb   = (__bf16*)alloc(2048ull * 1024 * 2);
  __bf16* Ob    = (__bf16*)alloc(2048ull * 1024 * 2);
  float*  x1    = (float*)alloc(2048ull * 1024 * 4);
  float*  x2    = (float*)alloc(2048ull * 1024 * 4);
  __bf16* hb    = (__bf16*)KVf;  // FFN hidden (2048x4096 bf16) overlays KV fp32 region
  float*  pbuf  = (float*)Qr;    // ff2 split-K partials: 2 x 8MB over Qr..Ob
  float*  mpart = (float*)Qf;    // mod GEMV partials (256KB), dead before Qf's first GEMM use

  // ---- weight prep ----
  wt_kernel<<<dim3(32, 32), 256, 0, stream>>>(sa_wq, wqT, 1024, 1024);
  wt_kernel<<<dim3(64, 32), 256, 0, stream>>>(sa_wkv, wkvT, 1024, 2048);
  wt_kernel<<<dim3(32, 32), 256, 0, stream>>>(sa_wo, woT, 1024, 1024);
  wt_kernel<<<dim3(32, 32), 256, 0, stream>>>(ca_wq, cwqT, 1024, 1024);
  wt_kernel<<<dim3(64, 24), 256, 0, stream>>>(ca_wkv, cwkvT, 768, 2048);
  wt_kernel<<<dim3(32, 32), 256, 0, stream>>>(ca_wo, cwoT, 1024, 1024);
  wt_kernel<<<dim3(128, 32), 256, 0, stream>>>(ff_w1, ff1T, 1024, 4096);
  wt_kernel<<<dim3(32, 128), 256, 0, stream>>>(ff_w2, ff2T, 4096, 1024);
  rope_tbl_kernel<<<128, 256, 0, stream>>>(tbl);
  mod_part_kernel<<<dim3(4, 2, 32), 256, 0, stream>>>(cond, g1_w, b1_w, g2_w, b2_w, mpart);
  mod_reduce_kernel<<<32, 256, 0, stream>>>(mpart, g1_b, b1_b, g2_b, b2_b, mods);

  // ---- self attention ----
  adaln_kernel<<<2048, 256, 0, stream>>>(x, ln1_w, ln1_b, mods, 0, 1, ain);
  gemm3<128, 64, 0><<<dim3(16, 16), 256, 0, stream>>>(ain, wqT, nullptr, nullptr, Qf, 2048, 1024, 1024, 1);
  gemm3<128, 128, 0><<<dim3(16, 16), 256, 0, stream>>>(ain, wkvT, nullptr, nullptr, KVf, 2048, 2048, 1024, 1);
  rope_kernel<<<4096, 256, 0, stream>>>(Qf, 1024, 0, tbl, Qr, 1024);
  rope_kernel<<<4096, 256, 0, stream>>>(KVf, 2048, 0, tbl, Kr, 1024);
  vt_kernel<<<dim3(32, 32, 2), 256, 0, stream>>>(KVf, 2048, 1024, VTb, 1024);
  attn_kernel<<<dim3(16, 32), 256, 0, stream>>>(Qr, Kr, VTb, Ob, 1024, 1024);
  gemm3<128, 64, 1><<<dim3(16, 16), 256, 0, stream>>>(Ob, woT, sa_bo, x, x1, 2048, 1024, 1024, 1);

  // ---- cross attention ----
  adaln_kernel<<<2048, 256, 0, stream>>>(x1, ln1_w, ln1_b, mods, 0, 1, ain);
  ctxln_kernel<<<1024, 256, 0, stream>>>(ctx, ca_lnc_w, ca_lnc_b, ctxn);
  gemm3<128, 64, 0><<<dim3(16, 16), 256, 0, stream>>>(ain, cwqT, nullptr, nullptr, Qf, 2048, 1024, 1024, 1);
  gemm3<64, 128, 0><<<dim3(16, 16), 256, 0, stream>>>(ctxn, cwkvT, nullptr, nullptr, KVf, 1024, 2048, 768, 1);
  rope_kernel<<<4096, 256, 0, stream>>>(Qf, 1024, 0, tbl, Qr, 1024);
  rope_kernel<<<2048, 256, 0, stream>>>(KVf, 2048, 0, tbl, Kr, 512);
  vt_kernel<<<dim3(32, 16, 2), 256, 0, stream>>>(KVf, 2048, 1024, VTb, 512);
  attn_kernel<<<dim3(16, 32), 256, 0, stream>>>(Qr, Kr, VTb, Ob, 1024, 512);
  gemm3<128, 64, 1><<<dim3(16, 16), 256, 0, stream>>>(Ob, cwoT, ca_bo, x1, x2, 2048, 1024, 1024, 1);

  // ---- FFN ----
  adaln_kernel<<<2048, 256, 0, stream>>>(x2, ln2_w, ln2_b, mods, 2, 3, ain);
  gemm3<128, 128, 2><<<dim3(16, 32), 256, 0, stream>>>(ain, ff1T, ff_b1, nullptr, hb, 2048, 4096, 1024, 1);
  gemm3<128, 64, 3><<<dim3(16, 16, 2), 256, 0, stream>>>(hb, ff2T, nullptr, nullptr, pbuf, 2048, 1024, 4096, 2);
  ff2red_kernel<<<2048, 256, 0, stream>>>(pbuf, ff_b2, x2, out, 2048 * 1024, 1024);
}

// Round 4
// 358.521 us; speedup vs baseline: 1.4088x; 1.0152x over previous
//
#include <hip/hip_runtime.h>
#include <hip/hip_bf16.h>
#include <math.h>

// B=2 N=1024 M=512 D=1024 H=16 DH=64 MID=1024 DC=768 MULT=4

typedef float f32x4 __attribute__((ext_vector_type(4)));
typedef __bf16 bf16x8 __attribute__((ext_vector_type(8)));
typedef __bf16 bf16x4 __attribute__((ext_vector_type(4)));
typedef __bf16 bf16x2 __attribute__((ext_vector_type(2)));

#define DEVI __device__ __forceinline__

DEVI void gload16(const void* g, void* l) {
  __builtin_amdgcn_global_load_lds((const __attribute__((address_space(1))) void*)g,
                                   (__attribute__((address_space(3))) void*)l, 16, 0, 0);
}

// ---------------- weight fp32 -> bf16 transposed: WT[n][k] = W[k][n] ----------------
__global__ __launch_bounds__(256) void wt_kernel(const float* __restrict__ W,
                                                 __bf16* __restrict__ WT, int K, int N) {
  __shared__ float tile[32][33];
  int n0 = blockIdx.x * 32, k0 = blockIdx.y * 32;
  int tx = threadIdx.x & 31, ty = threadIdx.x >> 5;
#pragma unroll
  for (int i = 0; i < 4; ++i) {
    int k = ty + i * 8;
    tile[k][tx] = W[(size_t)(k0 + k) * N + n0 + tx];
  }
  __syncthreads();
#pragma unroll
  for (int i = 0; i < 4; ++i) {
    int n = ty + i * 8;
    WT[(size_t)(n0 + n) * K + k0 + tx] = (__bf16)tile[tx][n];
  }
}

// ---------------- modulation GEMV, k-split partials ----------------
__global__ __launch_bounds__(256) void mod_part_kernel(
    const float* __restrict__ cond,
    const float* __restrict__ g1w, const float* __restrict__ b1w,
    const float* __restrict__ g2w, const float* __restrict__ b2w,
    float* __restrict__ part) {
  __shared__ float sc[128];
  int dchunk = blockIdx.x, b = blockIdx.y;
  int mat = blockIdx.z >> 3, ks = blockIdx.z & 7;
  const float* W = (mat == 0) ? g1w : (mat == 1) ? b1w : (mat == 2) ? g2w : b2w;
  if (threadIdx.x < 128) sc[threadIdx.x] = cond[b * 1024 + ks * 128 + threadIdx.x];
  __syncthreads();
  int d = dchunk * 256 + threadIdx.x;
  const float* Wp = W + (size_t)(ks * 128) * 1024 + d;
  float acc = 0.f;
#pragma unroll 8
  for (int k = 0; k < 128; ++k) acc += sc[k] * Wp[(size_t)k * 1024];
  part[(size_t)(blockIdx.z * 2 + b) * 1024 + d] = acc;
}

__global__ __launch_bounds__(256) void mod_reduce_kernel(
    const float* __restrict__ part,
    const float* __restrict__ g1b, const float* __restrict__ b1b,
    const float* __restrict__ g2b, const float* __restrict__ b2b,
    float* __restrict__ mods) {
  int idx = blockIdx.x * 256 + threadIdx.x;  // 0..8191
  int mat = idx >> 11, b = (idx >> 10) & 1, d = idx & 1023;
  float s = 0.f;
#pragma unroll
  for (int ks = 0; ks < 8; ++ks) s += part[(size_t)((mat * 8 + ks) * 2 + b) * 1024 + d];
  const float* Bv = (mat == 0) ? g1b : (mat == 1) ? b1b : (mat == 2) ? g2b : b2b;
  mods[(size_t)(mat * 2 + b) * 1024 + d] = s + Bv[d];
}

// ---------------- adaLN: out_bf16 = LN(x)*(1+g)+bt ----------------
__global__ __launch_bounds__(256) void adaln_kernel(const float* __restrict__ X,
                                                    const float* __restrict__ lnw,
                                                    const float* __restrict__ lnb,
                                                    const float* __restrict__ mods,
                                                    int gi, int bi,
                                                    __bf16* __restrict__ out) {
  __shared__ float red[2][4];
  int row = blockIdx.x;  // 0..2047
  int b = row >> 10;
  int t = threadIdx.x;
  const float4 xv = ((const float4*)(X + (size_t)row * 1024))[t];
  float s  = xv.x + xv.y + xv.z + xv.w;
  float s2 = xv.x * xv.x + xv.y * xv.y + xv.z * xv.z + xv.w * xv.w;
  int lane = t & 63, w = t >> 6;
#pragma unroll
  for (int off = 32; off > 0; off >>= 1) {
    s += __shfl_down(s, off);
    s2 += __shfl_down(s2, off);
  }
  if (lane == 0) { red[0][w] = s; red[1][w] = s2; }
  __syncthreads();
  s  = red[0][0] + red[0][1] + red[0][2] + red[0][3];
  s2 = red[1][0] + red[1][1] + red[1][2] + red[1][3];
  float mu = s * (1.0f / 1024.0f);
  float var = s2 * (1.0f / 1024.0f) - mu * mu;
  float rstd = rsqrtf(var + 1e-5f);
  const float4 wv = ((const float4*)lnw)[t];
  const float4 bv = ((const float4*)lnb)[t];
  const float4 gv = ((const float4*)(mods + (size_t)(gi * 2 + b) * 1024))[t];
  const float4 tv = ((const float4*)(mods + (size_t)(bi * 2 + b) * 1024))[t];
  bf16x4 ov;
  ov[0] = (__bf16)(((xv.x - mu) * rstd * wv.x + bv.x) * (1.0f + gv.x) + tv.x);
  ov[1] = (__bf16)(((xv.y - mu) * rstd * wv.y + bv.y) * (1.0f + gv.y) + tv.y);
  ov[2] = (__bf16)(((xv.z - mu) * rstd * wv.z + bv.z) * (1.0f + gv.z) + tv.z);
  ov[3] = (__bf16)(((xv.w - mu) * rstd * wv.w + bv.w) * (1.0f + gv.w) + tv.w);
  *(bf16x4*)(out + (size_t)row * 1024 + t * 4) = ov;
}

// ---------------- context LN (D=768) ----------------
__global__ __launch_bounds__(256) void ctxln_kernel(const float* __restrict__ X,
                                                    const float* __restrict__ w,
                                                    const float* __restrict__ bias,
                                                    __bf16* __restrict__ out) {
  __shared__ float red[2][4];
  int row = blockIdx.x;  // 0..1023
  int t = threadIdx.x;
  const float* xp = X + (size_t)row * 768;
  float v[3];
  float s = 0.f, s2 = 0.f;
#pragma unroll
  for (int i = 0; i < 3; ++i) {
    v[i] = xp[t + i * 256];
    s += v[i];
    s2 += v[i] * v[i];
  }
  int lane = t & 63, wv_ = t >> 6;
#pragma unroll
  for (int off = 32; off > 0; off >>= 1) {
    s += __shfl_down(s, off);
    s2 += __shfl_down(s2, off);
  }
  if (lane == 0) { red[0][wv_] = s; red[1][wv_] = s2; }
  __syncthreads();
  s  = red[0][0] + red[0][1] + red[0][2] + red[0][3];
  s2 = red[1][0] + red[1][1] + red[1][2] + red[1][3];
  float mu = s * (1.0f / 768.0f);
  float var = s2 * (1.0f / 768.0f) - mu * mu;
  float rstd = rsqrtf(var + 1e-5f);
#pragma unroll
  for (int i = 0; i < 3; ++i) {
    int c = t + i * 256;
    out[(size_t)row * 768 + c] = (__bf16)((v[i] - mu) * rstd * w[c] + bias[c]);
  }
}

// ---------------- rope table ----------------
__global__ __launch_bounds__(256) void rope_tbl_kernel(float2* __restrict__ tbl) {
  int idx = blockIdx.x * 256 + threadIdx.x;  // 1024*32
  int n = idx >> 5, i = idx & 31;
  float inv = expf(-(float)(2 * i) * (1.0f / 64.0f) * 9.210340371976184f);  // ln(10000)
  float ang = (float)n * inv;
  tbl[idx] = make_float2(sinf(ang), cosf(ang));
}

// ---------------- rope + head-layout (+ optional scale, exact pow2) ----------------
__global__ __launch_bounds__(256) void rope_kernel(const float* __restrict__ X, int ldx, int col0,
                                                   const float2* __restrict__ tbl,
                                                   __bf16* __restrict__ out, int Ntok, float scale) {
  int idx = blockIdx.x * 256 + threadIdx.x;  // B*Ntok*16*32
  int i = idx & 31;
  int h = (idx >> 5) & 15;
  int nn = idx >> 9;
  int n = nn % Ntok;
  int b = nn / Ntok;
  const float* xp = X + (size_t)(b * Ntok + n) * ldx + col0 + h * 64 + 2 * i;
  float xe = xp[0], xo = xp[1];
  float2 sc2 = tbl[n * 32 + i];
  float re = (xe * sc2.y - xo * sc2.x) * scale;
  float ro = (xe * sc2.x + xo * sc2.y) * scale;
  __bf16* op = out + ((size_t)(b * 16 + h) * Ntok + n) * 64 + 2 * i;
  op[0] = (__bf16)re;
  op[1] = (__bf16)ro;
}

// ---------------- V transpose ----------------
__global__ __launch_bounds__(256) void vt_kernel(const float* __restrict__ KV, int ld, int col0,
                                                 __bf16* __restrict__ VT, int Ntok) {
  __shared__ float tile[32][33];
  int bh = blockIdx.x;
  int n0 = blockIdx.y * 32, d0 = blockIdx.z * 32;
  int b = bh >> 4, h = bh & 15;
  int tx = threadIdx.x & 31, ty = threadIdx.x >> 5;
#pragma unroll
  for (int i = 0; i < 4; ++i) {
    int n = ty + i * 8;
    tile[n][tx] = KV[(size_t)(b * Ntok + n0 + n) * ld + col0 + h * 64 + d0 + tx];
  }
  __syncthreads();
#pragma unroll
  for (int i = 0; i < 4; ++i) {
    int d = ty + i * 8;
    VT[((size_t)bh * 64 + d0 + d) * Ntok + n0 + tx] = (__bf16)tile[tx][d];
  }
}

// ---------------- pipelined bf16 GEMM: C[M,N] = A[M,K] @ BT[N,K]^T ----------------
// EPI: 0 fp32 out; 1 fp32 out+bias+res; 2 bf16 gelu(acc+bias); 3 fp32 partial at slice z
template <int BM, int BN, int EPI>
__global__ __launch_bounds__(256) void gemm3(const __bf16* __restrict__ A,
                                             const __bf16* __restrict__ BT,
                                             const float* __restrict__ bias,
                                             const float* __restrict__ res,
                                             void* __restrict__ outv,
                                             int M, int N, int K, int kslices) {
  constexpr int MI = BM / 32, NI = BN / 32;
  __shared__ __bf16 sA[2][BM * 32];
  __shared__ __bf16 sB[2][BN * 32];
  const int t = threadIdx.x;
  const int w = t >> 6, lane = t & 63;
  const int lr = lane & 15, lg = lane >> 4;
  const int bm = blockIdx.x, bn = blockIdx.y, bz = blockIdx.z;
  const int wm = (w >> 1) * (BM / 2), wn = (w & 1) * (BN / 2);
  const int kper = K / kslices;
  const int k0 = bz * kper;
  f32x4 acc[MI][NI] = {};

  auto stage = [&](int buf, int kt) {
#pragma unroll
    for (int i = 0; i < BM / 64; ++i) {
      int e = (i * 256 + t) * 8;
      int row = e >> 5, col = e & 31;
      gload16(A + (size_t)(bm * BM + row) * K + kt + col, &sA[buf][e]);
    }
#pragma unroll
    for (int i = 0; i < BN / 64; ++i) {
      int e = (i * 256 + t) * 8;
      int row = e >> 5, col = e & 31;
      gload16(BT + (size_t)(bn * BN + row) * K + kt + col, &sB[buf][e]);
    }
  };

  stage(0, k0);
  __syncthreads();
  int cur = 0;
  for (int kt = k0; kt < k0 + kper; kt += 32) {
    if (kt + 32 < k0 + kper) stage(cur ^ 1, kt + 32);  // prefetch next tile
    bf16x8 af[MI], bfr[NI];
#pragma unroll
    for (int mi = 0; mi < MI; ++mi)
      af[mi] = *(const bf16x8*)(&sA[cur][(wm + mi * 16 + lr) * 32 + lg * 8]);
#pragma unroll
    for (int ni = 0; ni < NI; ++ni)
      bfr[ni] = *(const bf16x8*)(&sB[cur][(wn + ni * 16 + lr) * 32 + lg * 8]);
#pragma unroll
    for (int mi = 0; mi < MI; ++mi)
#pragma unroll
      for (int ni = 0; ni < NI; ++ni)
        acc[mi][ni] = __builtin_amdgcn_mfma_f32_16x16x32_bf16(af[mi], bfr[ni], acc[mi][ni], 0, 0, 0);
    __syncthreads();
    cur ^= 1;
  }
#pragma unroll
  for (int mi = 0; mi < MI; ++mi) {
    int row = bm * BM + wm + mi * 16 + lg * 4;
#pragma unroll
    for (int ni = 0; ni < NI; ++ni) {
      int col = bn * BN + wn + ni * 16 + lr;
#pragma unroll
      for (int r = 0; r < 4; ++r) {
        float v = acc[mi][ni][r];
        size_t off = (size_t)(row + r) * N + col;
        if (EPI == 0) {
          ((float*)outv)[off] = v;
        } else if (EPI == 1) {
          ((float*)outv)[off] = v + bias[col] + res[off];
        } else if (EPI == 2) {
          float xg = v + bias[col];
          ((__bf16*)outv)[off] = (__bf16)(0.5f * xg * (1.0f + erff(xg * 0.7071067811865475f)));
        } else {
          ((float*)outv)[(size_t)bz * M * N + off] = v;
        }
      }
    }
  }
}

// ---------------- split-K reduce for ff2 ----------------
__global__ __launch_bounds__(256) void ff2red_kernel(const float* __restrict__ part,
                                                     const float* __restrict__ bias,
                                                     const float* __restrict__ res,
                                                     float* __restrict__ out, int MN, int N) {
  int idx = blockIdx.x * 256 + threadIdx.x;
  float4 p0 = ((const float4*)part)[idx];
  float4 p1 = ((const float4*)(part + MN))[idx];
  float4 rr = ((const float4*)res)[idx];
  int colb = (idx * 4) & (N - 1);
  float4 bb = *(const float4*)(bias + colb);
  float4 o;
  o.x = p0.x + p1.x + bb.x + rr.x;
  o.y = p0.y + p1.y + bb.y + rr.y;
  o.z = p0.z + p1.z + bb.z + rr.z;
  o.w = p0.w + p1.w + bb.w + rr.w;
  ((float4*)out)[idx] = o;
}

// ---------------- attention, split-K flash partials ----------------
// Q pre-scaled by DH^-0.5. Per wave 16 q rows; KVBLK=64 per iter; S^T via mfma(K,Q):
// lane (lg,lr): holds S[k = kt+nf*16+lg*4+r][q = q0+lr]. m,l per q-row live in lanes by lr.
// P tile LDS XOR-swizzled (elem ^ ((lr&7)<<3)) -> conflict-free-ish write + b128 read.
// Writes unnormalized O partial + (m,l) per slice z; combine kernel merges.
template <int KITERS>
__global__ __launch_bounds__(256) void attn_part_kernel(const __bf16* __restrict__ Qr,
                                                        const __bf16* __restrict__ Kr,
                                                        const __bf16* __restrict__ VT,
                                                        float* __restrict__ pO,
                                                        float* __restrict__ pml,
                                                        int Nq, int Nk) {
  __shared__ __bf16 Pl[4][16 * 64];
  const int t = threadIdx.x, w = t >> 6, lane = t & 63;
  const int lr = lane & 15, lg = lane >> 4;
  const int lsrc = lane & 48;
  const int swz = (lr & 7) << 3;
  const int bh = blockIdx.y, q0 = blockIdx.x * 64 + w * 16;
  const int z = blockIdx.z;
  const int k0 = z * (KITERS * 64);
  bf16x8 qf[2];
#pragma unroll
  for (int kh = 0; kh < 2; ++kh)
    qf[kh] = *(const bf16x8*)(Qr + ((size_t)bh * Nq + q0 + lr) * 64 + kh * 32 + lg * 8);
  f32x4 accO[4] = {};
  float m = -INFINITY, l = 0.f;
#pragma unroll
  for (int it = 0; it < KITERS; ++it) {
    const int kt = k0 + it * 64;
    f32x4 s[4] = {};
#pragma unroll
    for (int nf = 0; nf < 4; ++nf)
#pragma unroll
      for (int kh = 0; kh < 2; ++kh) {
        bf16x8 kf = *(const bf16x8*)(Kr + ((size_t)bh * Nk + kt + nf * 16 + lr) * 64 + kh * 32 + lg * 8);
        s[nf] = __builtin_amdgcn_mfma_f32_16x16x32_bf16(kf, qf[kh], s[nf], 0, 0, 0);
      }
    float p[16];
#pragma unroll
    for (int j = 0; j < 16; ++j) p[j] = s[j >> 2][j & 3];
    float pm = p[0];
#pragma unroll
    for (int j = 1; j < 16; ++j) pm = fmaxf(pm, p[j]);
    pm = fmaxf(pm, __shfl_xor(pm, 16));
    pm = fmaxf(pm, __shfl_xor(pm, 32));
    if (!__all(pm <= m + 8.f)) {  // defer-max: rescale only on real max growth
      float mnew = fmaxf(m, pm);
      float resc = __expf(m - mnew);
      float rq[4];
#pragma unroll
      for (int r = 0; r < 4; ++r) rq[r] = __shfl(resc, lsrc | (lg * 4 + r));
#pragma unroll
      for (int df = 0; df < 4; ++df)
#pragma unroll
        for (int r = 0; r < 4; ++r) accO[df][r] *= rq[r];
      l *= resc;
      m = mnew;
    }
    float rs = 0.f;
#pragma unroll
    for (int j = 0; j < 16; ++j) { p[j] = __expf(p[j] - m); rs += p[j]; }
    rs += __shfl_xor(rs, 16);
    rs += __shfl_xor(rs, 32);
    l += rs;
    // P write: row q=lr, col k=nf*16+lg*4+j, swizzled
#pragma unroll
    for (int nf = 0; nf < 4; ++nf)
#pragma unroll
      for (int jj = 0; jj < 2; ++jj) {
        int k = nf * 16 + lg * 4 + 2 * jj;
        bf16x2 pk;
        pk[0] = (__bf16)p[nf * 4 + 2 * jj];
        pk[1] = (__bf16)p[nf * 4 + 2 * jj + 1];
        *(bf16x2*)(&Pl[w][lr * 64 + (k ^ swz)]) = pk;
      }
    // per-wave LDS ordering guarantees write->read; Pl is wave-private (no barrier)
    bf16x8 pa0 = *(const bf16x8*)(&Pl[w][lr * 64 + ((lg * 8) ^ swz)]);
    bf16x8 pa1 = *(const bf16x8*)(&Pl[w][lr * 64 + ((32 + lg * 8) ^ swz)]);
#pragma unroll
    for (int df = 0; df < 4; ++df) {
      const __bf16* vp = VT + ((size_t)bh * 64 + df * 16 + lr) * Nk + kt;
      bf16x8 vf0 = *(const bf16x8*)(vp + lg * 8);
      bf16x8 vf1 = *(const bf16x8*)(vp + 32 + lg * 8);
      accO[df] = __builtin_amdgcn_mfma_f32_16x16x32_bf16(pa0, vf0, accO[df], 0, 0, 0);
      accO[df] = __builtin_amdgcn_mfma_f32_16x16x32_bf16(pa1, vf1, accO[df], 0, 0, 0);
    }
  }
  const size_t rbase = (size_t)(z * 32 + bh) * Nq + q0;
  if (lg == 0) {
    pml[(rbase + lr) * 2] = m;
    pml[(rbase + lr) * 2 + 1] = l;
  }
#pragma unroll
  for (int r = 0; r < 4; ++r)
#pragma unroll
    for (int df = 0; df < 4; ++df)
      pO[(rbase + lg * 4 + r) * 64 + df * 16 + lr] = accO[df][r];
}

// ---------------- combine 2 flash slices -> O token-major bf16 ----------------
__global__ __launch_bounds__(256) void attn_combine_kernel(const float* __restrict__ pO,
                                                           const float* __restrict__ pml,
                                                           __bf16* __restrict__ O) {
  int idx = blockIdx.x * 256 + threadIdx.x;  // 32768*64 threads
  int r = idx >> 6, dh = idx & 63;
  float m0 = pml[2 * r], l0 = pml[2 * r + 1];
  float m1 = pml[2 * (r + 32768)], l1 = pml[2 * (r + 32768) + 1];
  float O0 = pO[(size_t)r * 64 + dh];
  float O1 = pO[((size_t)r + 32768) * 64 + dh];
  float mm = fmaxf(m0, m1);
  float w0 = __expf(m0 - mm), w1 = __expf(m1 - mm);
  float val = (O0 * w0 + O1 * w1) / (l0 * w0 + l1 * w1);
  int bh = r >> 10, n = r & 1023;
  int b = bh >> 4, h = bh & 15;
  O[(size_t)(b * 1024 + n) * 1024 + h * 64 + dh] = (__bf16)val;
}

extern "C" void kernel_launch(void* const* d_in, const int* in_sizes, int n_in,
                              void* d_out, int out_size, void* d_ws, size_t ws_size,
                              hipStream_t stream) {
  (void)in_sizes; (void)n_in; (void)out_size; (void)ws_size;
  const float* x       = (const float*)d_in[0];
  const float* cond    = (const float*)d_in[1];
  const float* ctx     = (const float*)d_in[2];
  const float* ln1_w   = (const float*)d_in[3];
  const float* ln1_b   = (const float*)d_in[4];
  const float* g1_w    = (const float*)d_in[5];
  const float* g1_b    = (const float*)d_in[6];
  const float* b1_w    = (const float*)d_in[7];
  const float* b1_b    = (const float*)d_in[8];
  const float* ln2_w   = (const float*)d_in[9];
  const float* ln2_b   = (const float*)d_in[10];
  const float* g2_w    = (const float*)d_in[11];
  const float* g2_b    = (const float*)d_in[12];
  const float* b2_w    = (const float*)d_in[13];
  const float* b2_b    = (const float*)d_in[14];
  const float* sa_wq   = (const float*)d_in[15];
  const float* sa_wkv  = (const float*)d_in[16];
  const float* sa_wo   = (const float*)d_in[17];
  const float* sa_bo   = (const float*)d_in[18];
  const float* ca_lnc_w = (const float*)d_in[19];
  const float* ca_lnc_b = (const float*)d_in[20];
  const float* ca_wq   = (const float*)d_in[21];
  const float* ca_wkv  = (const float*)d_in[22];
  const float* ca_wo   = (const float*)d_in[23];
  const float* ca_bo   = (const float*)d_in[24];
  const float* ff_w1   = (const float*)d_in[25];
  const float* ff_b1   = (const float*)d_in[26];
  const float* ff_w2   = (const float*)d_in[27];
  const float* ff_b2   = (const float*)d_in[28];
  float* out = (float*)d_out;

  char* ws = (char*)d_ws;
  size_t o = 0;
  auto alloc = [&](size_t bytes) {
    void* p = ws + o;
    o += (bytes + 255) & ~(size_t)255;
    return p;
  };

  __bf16* wqT   = (__bf16*)alloc(1024ull * 1024 * 2);
  __bf16* wkvT  = (__bf16*)alloc(2048ull * 1024 * 2);
  __bf16* woT   = (__bf16*)alloc(1024ull * 1024 * 2);
  __bf16* cwqT  = (__bf16*)alloc(1024ull * 1024 * 2);
  __bf16* cwkvT = (__bf16*)alloc(2048ull * 768 * 2);
  __bf16* cwoT  = (__bf16*)alloc(1024ull * 1024 * 2);
  __bf16* ff1T  = (__bf16*)alloc(4096ull * 1024 * 2);
  __bf16* ff2T  = (__bf16*)alloc(1024ull * 4096 * 2);
  float*  mods  = (float*)alloc(4ull * 2 * 1024 * 4);
  float2* tbl   = (float2*)alloc(1024ull * 32 * 8);
  __bf16* ain   = (__bf16*)alloc(2048ull * 1024 * 2);
  float*  Qf    = (float*)alloc(2048ull * 1024 * 4);   // also: pml (512KB) after rope
  float*  KVf   = (float*)alloc(2048ull * 2048 * 4);   // also: attn pO (16MB) / FFN hidden
  __bf16* ctxn  = (__bf16*)alloc(1024ull * 768 * 2);
  __bf16* Qr    = (__bf16*)alloc(2048ull * 1024 * 2);  // Qr..Ob 16MB, reused as ff2 partials
  __bf16* Kr    = (__bf16*)alloc(2048ull * 1024 * 2);
  __bf16* VTb   = (__bf16*)alloc(2048ull * 1024 * 2);
  __bf16* Ob    = (__bf16*)alloc(2048ull * 1024 * 2);
  float*  x1    = (float*)alloc(2048ull * 1024 * 4);
  float*  x2    = (float*)alloc(2048ull * 1024 * 4);
  __bf16* hb    = (__bf16*)KVf;  // FFN hidden (2048x4096 bf16)
  float*  pbuf  = (float*)Qr;    // ff2 split-K partials: 2 x 8MB
  float*  mpart = (float*)Qf;    // mod GEMV partials (256KB)
  float*  pO    = (float*)KVf;   // attn partials: 2 x 32768 x 64 fp32 = 16MB
  float*  pml   = (float*)Qf;    // attn m/l: 2 x 32768 x 2 fp32 = 512KB

  // ---- weight prep ----
  wt_kernel<<<dim3(32, 32), 256, 0, stream>>>(sa_wq, wqT, 1024, 1024);
  wt_kernel<<<dim3(64, 32), 256, 0, stream>>>(sa_wkv, wkvT, 1024, 2048);
  wt_kernel<<<dim3(32, 32), 256, 0, stream>>>(sa_wo, woT, 1024, 1024);
  wt_kernel<<<dim3(32, 32), 256, 0, stream>>>(ca_wq, cwqT, 1024, 1024);
  wt_kernel<<<dim3(64, 24), 256, 0, stream>>>(ca_wkv, cwkvT, 768, 2048);
  wt_kernel<<<dim3(32, 32), 256, 0, stream>>>(ca_wo, cwoT, 1024, 1024);
  wt_kernel<<<dim3(128, 32), 256, 0, stream>>>(ff_w1, ff1T, 1024, 4096);
  wt_kernel<<<dim3(32, 128), 256, 0, stream>>>(ff_w2, ff2T, 4096, 1024);
  rope_tbl_kernel<<<128, 256, 0, stream>>>(tbl);
  mod_part_kernel<<<dim3(4, 2, 32), 256, 0, stream>>>(cond, g1_w, b1_w, g2_w, b2_w, mpart);
  mod_reduce_kernel<<<32, 256, 0, stream>>>(mpart, g1_b, b1_b, g2_b, b2_b, mods);

  // ---- self attention ----
  adaln_kernel<<<2048, 256, 0, stream>>>(x, ln1_w, ln1_b, mods, 0, 1, ain);
  gemm3<64, 64, 0><<<dim3(32, 16), 256, 0, stream>>>(ain, wqT, nullptr, nullptr, Qf, 2048, 1024, 1024, 1);
  gemm3<64, 128, 0><<<dim3(32, 16), 256, 0, stream>>>(ain, wkvT, nullptr, nullptr, KVf, 2048, 2048, 1024, 1);
  rope_kernel<<<4096, 256, 0, stream>>>(Qf, 1024, 0, tbl, Qr, 1024, 0.125f);
  rope_kernel<<<4096, 256, 0, stream>>>(KVf, 2048, 0, tbl, Kr, 1024, 1.0f);
  vt_kernel<<<dim3(32, 32, 2), 256, 0, stream>>>(KVf, 2048, 1024, VTb, 1024);
  attn_part_kernel<8><<<dim3(16, 32, 2), 256, 0, stream>>>(Qr, Kr, VTb, pO, pml, 1024, 1024);
  attn_combine_kernel<<<8192, 256, 0, stream>>>(pO, pml, Ob);
  gemm3<64, 64, 1><<<dim3(32, 16), 256, 0, stream>>>(Ob, woT, sa_bo, x, x1, 2048, 1024, 1024, 1);

  // ---- cross attention ----
  adaln_kernel<<<2048, 256, 0, stream>>>(x1, ln1_w, ln1_b, mods, 0, 1, ain);
  ctxln_kernel<<<1024, 256, 0, stream>>>(ctx, ca_lnc_w, ca_lnc_b, ctxn);
  gemm3<64, 64, 0><<<dim3(32, 16), 256, 0, stream>>>(ain, cwqT, nullptr, nullptr, Qf, 2048, 1024, 1024, 1);
  gemm3<64, 64, 0><<<dim3(16, 32), 256, 0, stream>>>(ctxn, cwkvT, nullptr, nullptr, KVf, 1024, 2048, 768, 1);
  rope_kernel<<<4096, 256, 0, stream>>>(Qf, 1024, 0, tbl, Qr, 1024, 0.125f);
  rope_kernel<<<2048, 256, 0, stream>>>(KVf, 2048, 0, tbl, Kr, 512, 1.0f);
  vt_kernel<<<dim3(32, 16, 2), 256, 0, stream>>>(KVf, 2048, 1024, VTb, 512);
  attn_part_kernel<4><<<dim3(16, 32, 2), 256, 0, stream>>>(Qr, Kr, VTb, pO, pml, 1024, 512);
  attn_combine_kernel<<<8192, 256, 0, stream>>>(pO, pml, Ob);
  gemm3<64, 64, 1><<<dim3(32, 16), 256, 0, stream>>>(Ob, cwoT, ca_bo, x1, x2, 2048, 1024, 1024, 1);

  // ---- FFN ----
  adaln_kernel<<<2048, 256, 0, stream>>>(x2, ln2_w, ln2_b, mods, 2, 3, ain);
  gemm3<64, 128, 2><<<dim3(32, 32), 256, 0, stream>>>(ain, ff1T, ff_b1, nullptr, hb, 2048, 4096, 1024, 1);
  gemm3<64, 64, 3><<<dim3(32, 16, 2), 256, 0, stream>>>(hb, ff2T, nullptr, nullptr, pbuf, 2048, 1024, 4096, 2);
  ff2red_kernel<<<2048, 256, 0, stream>>>(pbuf, ff_b2, x2, out, 2048 * 1024, 1024);
}

// Round 5
// 301.852 us; speedup vs baseline: 1.6732x; 1.1877x over previous
//
#include <hip/hip_runtime.h>
#include <hip/hip_bf16.h>
#include <math.h>

// B=2 N=1024 M=512 D=1024 H=16 DH=64 MID=1024 DC=768 MULT=4

typedef float f32x4 __attribute__((ext_vector_type(4)));
typedef __bf16 bf16x8 __attribute__((ext_vector_type(8)));
typedef __bf16 bf16x4 __attribute__((ext_vector_type(4)));
typedef __bf16 bf16x2 __attribute__((ext_vector_type(2)));

#define DEVI __device__ __forceinline__

DEVI void gload16(const void* g, void* l) {
  __builtin_amdgcn_global_load_lds((const __attribute__((address_space(1))) void*)g,
                                   (__attribute__((address_space(3))) void*)l, 16, 0, 0);
}

// ---------------- weight fp32 -> bf16 transposed: WT[n][k] = W[k][n] ----------------
__global__ __launch_bounds__(256) void wt_kernel(const float* __restrict__ W,
                                                 __bf16* __restrict__ WT, int K, int N) {
  __shared__ float tile[32][33];
  int n0 = blockIdx.x * 32, k0 = blockIdx.y * 32;
  int tx = threadIdx.x & 31, ty = threadIdx.x >> 5;
#pragma unroll
  for (int i = 0; i < 4; ++i) {
    int k = ty + i * 8;
    tile[k][tx] = W[(size_t)(k0 + k) * N + n0 + tx];
  }
  __syncthreads();
#pragma unroll
  for (int i = 0; i < 4; ++i) {
    int n = ty + i * 8;
    WT[(size_t)(n0 + n) * K + k0 + tx] = (__bf16)tile[tx][n];
  }
}

// ---------------- modulation GEMV, k-split partials ----------------
__global__ __launch_bounds__(256) void mod_part_kernel(
    const float* __restrict__ cond,
    const float* __restrict__ g1w, const float* __restrict__ b1w,
    const float* __restrict__ g2w, const float* __restrict__ b2w,
    float* __restrict__ part) {
  __shared__ float sc[128];
  int dchunk = blockIdx.x, b = blockIdx.y;
  int mat = blockIdx.z >> 3, ks = blockIdx.z & 7;
  const float* W = (mat == 0) ? g1w : (mat == 1) ? b1w : (mat == 2) ? g2w : b2w;
  if (threadIdx.x < 128) sc[threadIdx.x] = cond[b * 1024 + ks * 128 + threadIdx.x];
  __syncthreads();
  int d = dchunk * 256 + threadIdx.x;
  const float* Wp = W + (size_t)(ks * 128) * 1024 + d;
  float acc = 0.f;
#pragma unroll 8
  for (int k = 0; k < 128; ++k) acc += sc[k] * Wp[(size_t)k * 1024];
  part[(size_t)(blockIdx.z * 2 + b) * 1024 + d] = acc;
}

__global__ __launch_bounds__(256) void mod_reduce_kernel(
    const float* __restrict__ part,
    const float* __restrict__ g1b, const float* __restrict__ b1b,
    const float* __restrict__ g2b, const float* __restrict__ b2b,
    float* __restrict__ mods) {
  int idx = blockIdx.x * 256 + threadIdx.x;  // 0..8191
  int mat = idx >> 11, b = (idx >> 10) & 1, d = idx & 1023;
  float s = 0.f;
#pragma unroll
  for (int ks = 0; ks < 8; ++ks) s += part[(size_t)((mat * 8 + ks) * 2 + b) * 1024 + d];
  const float* Bv = (mat == 0) ? g1b : (mat == 1) ? b1b : (mat == 2) ? g2b : b2b;
  mods[(size_t)(mat * 2 + b) * 1024 + d] = s + Bv[d];
}

// ---------------- adaLN: out_bf16 = LN(x)*(1+g)+bt ----------------
__global__ __launch_bounds__(256) void adaln_kernel(const float* __restrict__ X,
                                                    const float* __restrict__ lnw,
                                                    const float* __restrict__ lnb,
                                                    const float* __restrict__ mods,
                                                    int gi, int bi,
                                                    __bf16* __restrict__ out) {
  __shared__ float red[2][4];
  int row = blockIdx.x;  // 0..2047
  int b = row >> 10;
  int t = threadIdx.x;
  const float4 xv = ((const float4*)(X + (size_t)row * 1024))[t];
  float s  = xv.x + xv.y + xv.z + xv.w;
  float s2 = xv.x * xv.x + xv.y * xv.y + xv.z * xv.z + xv.w * xv.w;
  int lane = t & 63, w = t >> 6;
#pragma unroll
  for (int off = 32; off > 0; off >>= 1) {
    s += __shfl_down(s, off);
    s2 += __shfl_down(s2, off);
  }
  if (lane == 0) { red[0][w] = s; red[1][w] = s2; }
  __syncthreads();
  s  = red[0][0] + red[0][1] + red[0][2] + red[0][3];
  s2 = red[1][0] + red[1][1] + red[1][2] + red[1][3];
  float mu = s * (1.0f / 1024.0f);
  float var = s2 * (1.0f / 1024.0f) - mu * mu;
  float rstd = rsqrtf(var + 1e-5f);
  const float4 wv = ((const float4*)lnw)[t];
  const float4 bv = ((const float4*)lnb)[t];
  const float4 gv = ((const float4*)(mods + (size_t)(gi * 2 + b) * 1024))[t];
  const float4 tv = ((const float4*)(mods + (size_t)(bi * 2 + b) * 1024))[t];
  bf16x4 ov;
  ov[0] = (__bf16)(((xv.x - mu) * rstd * wv.x + bv.x) * (1.0f + gv.x) + tv.x);
  ov[1] = (__bf16)(((xv.y - mu) * rstd * wv.y + bv.y) * (1.0f + gv.y) + tv.y);
  ov[2] = (__bf16)(((xv.z - mu) * rstd * wv.z + bv.z) * (1.0f + gv.z) + tv.z);
  ov[3] = (__bf16)(((xv.w - mu) * rstd * wv.w + bv.w) * (1.0f + gv.w) + tv.w);
  *(bf16x4*)(out + (size_t)row * 1024 + t * 4) = ov;
}

// ---------------- context LN (D=768) ----------------
__global__ __launch_bounds__(256) void ctxln_kernel(const float* __restrict__ X,
                                                    const float* __restrict__ w,
                                                    const float* __restrict__ bias,
                                                    __bf16* __restrict__ out) {
  __shared__ float red[2][4];
  int row = blockIdx.x;  // 0..1023
  int t = threadIdx.x;
  const float* xp = X + (size_t)row * 768;
  float v[3];
  float s = 0.f, s2 = 0.f;
#pragma unroll
  for (int i = 0; i < 3; ++i) {
    v[i] = xp[t + i * 256];
    s += v[i];
    s2 += v[i] * v[i];
  }
  int lane = t & 63, wv_ = t >> 6;
#pragma unroll
  for (int off = 32; off > 0; off >>= 1) {
    s += __shfl_down(s, off);
    s2 += __shfl_down(s2, off);
  }
  if (lane == 0) { red[0][wv_] = s; red[1][wv_] = s2; }
  __syncthreads();
  s  = red[0][0] + red[0][1] + red[0][2] + red[0][3];
  s2 = red[1][0] + red[1][1] + red[1][2] + red[1][3];
  float mu = s * (1.0f / 768.0f);
  float var = s2 * (1.0f / 768.0f) - mu * mu;
  float rstd = rsqrtf(var + 1e-5f);
#pragma unroll
  for (int i = 0; i < 3; ++i) {
    int c = t + i * 256;
    out[(size_t)row * 768 + c] = (__bf16)((v[i] - mu) * rstd * w[c] + bias[c]);
  }
}

// ---------------- rope table ----------------
__global__ __launch_bounds__(256) void rope_tbl_kernel(float2* __restrict__ tbl) {
  int idx = blockIdx.x * 256 + threadIdx.x;  // 1024*32
  int n = idx >> 5, i = idx & 31;
  float inv = expf(-(float)(2 * i) * (1.0f / 64.0f) * 9.210340371976184f);  // ln(10000)
  float ang = (float)n * inv;
  tbl[idx] = make_float2(sinf(ang), cosf(ang));
}

// ---------------- rope + head-layout (+ optional scale) ----------------
__global__ __launch_bounds__(256) void rope_kernel(const float* __restrict__ X, int ldx, int col0,
                                                   const float2* __restrict__ tbl,
                                                   __bf16* __restrict__ out, int Ntok, float scale) {
  int idx = blockIdx.x * 256 + threadIdx.x;  // B*Ntok*16*32
  int i = idx & 31;
  int h = (idx >> 5) & 15;
  int nn = idx >> 9;
  int n = nn % Ntok;
  int b = nn / Ntok;
  const float* xp = X + (size_t)(b * Ntok + n) * ldx + col0 + h * 64 + 2 * i;
  float xe = xp[0], xo = xp[1];
  float2 sc2 = tbl[n * 32 + i];
  float re = (xe * sc2.y - xo * sc2.x) * scale;
  float ro = (xe * sc2.x + xo * sc2.y) * scale;
  __bf16* op = out + ((size_t)(b * 16 + h) * Ntok + n) * 64 + 2 * i;
  op[0] = (__bf16)re;
  op[1] = (__bf16)ro;
}

// ---------------- V transpose ----------------
__global__ __launch_bounds__(256) void vt_kernel(const float* __restrict__ KV, int ld, int col0,
                                                 __bf16* __restrict__ VT, int Ntok) {
  __shared__ float tile[32][33];
  int bh = blockIdx.x;
  int n0 = blockIdx.y * 32, d0 = blockIdx.z * 32;
  int b = bh >> 4, h = bh & 15;
  int tx = threadIdx.x & 31, ty = threadIdx.x >> 5;
#pragma unroll
  for (int i = 0; i < 4; ++i) {
    int n = ty + i * 8;
    tile[n][tx] = KV[(size_t)(b * Ntok + n0 + n) * ld + col0 + h * 64 + d0 + tx];
  }
  __syncthreads();
#pragma unroll
  for (int i = 0; i < 4; ++i) {
    int d = ty + i * 8;
    VT[((size_t)bh * 64 + d0 + d) * Ntok + n0 + tx] = (__bf16)tile[tx][d];
  }
}

// ---------------- pipelined bf16 GEMM: C[M,N] = A[M,K] @ BT[N,K]^T ----------------
// EPI: 0 fp32 out; 1 fp32 out+bias+res; 2 bf16 gelu(acc+bias); 3 fp32 partial at slice z
template <int BM, int BN, int EPI>
__global__ __launch_bounds__(256) void gemm3(const __bf16* __restrict__ A,
                                             const __bf16* __restrict__ BT,
                                             const float* __restrict__ bias,
                                             const float* __restrict__ res,
                                             void* __restrict__ outv,
                                             int M, int N, int K, int kslices) {
  constexpr int MI = BM / 32, NI = BN / 32;
  __shared__ __bf16 sA[2][BM * 32];
  __shared__ __bf16 sB[2][BN * 32];
  const int t = threadIdx.x;
  const int w = t >> 6, lane = t & 63;
  const int lr = lane & 15, lg = lane >> 4;
  // XCD-aware bijective block swizzle (all grids are multiples of 8)
  int nwg = gridDim.x * gridDim.y * gridDim.z;
  int flat = blockIdx.x + gridDim.x * (blockIdx.y + gridDim.y * blockIdx.z);
  flat = (flat & 7) * (nwg >> 3) + (flat >> 3);
  const int bm = flat % gridDim.x;
  int rest = flat / gridDim.x;
  const int bn = rest % gridDim.y;
  const int bz = rest / gridDim.y;
  const int wm = (w >> 1) * (BM / 2), wn = (w & 1) * (BN / 2);
  const int kper = K / kslices;
  const int k0 = bz * kper;
  f32x4 acc[MI][NI] = {};

  auto stage = [&](int buf, int kt) {
#pragma unroll
    for (int i = 0; i < BM / 64; ++i) {
      int e = (i * 256 + t) * 8;
      int row = e >> 5, col = e & 31;
      gload16(A + (size_t)(bm * BM + row) * K + kt + col, &sA[buf][e]);
    }
#pragma unroll
    for (int i = 0; i < BN / 64; ++i) {
      int e = (i * 256 + t) * 8;
      int row = e >> 5, col = e & 31;
      gload16(BT + (size_t)(bn * BN + row) * K + kt + col, &sB[buf][e]);
    }
  };

  stage(0, k0);
  __syncthreads();
  int cur = 0;
  for (int kt = k0; kt < k0 + kper; kt += 32) {
    if (kt + 32 < k0 + kper) stage(cur ^ 1, kt + 32);  // prefetch next tile
    bf16x8 af[MI], bfr[NI];
#pragma unroll
    for (int mi = 0; mi < MI; ++mi)
      af[mi] = *(const bf16x8*)(&sA[cur][(wm + mi * 16 + lr) * 32 + lg * 8]);
#pragma unroll
    for (int ni = 0; ni < NI; ++ni)
      bfr[ni] = *(const bf16x8*)(&sB[cur][(wn + ni * 16 + lr) * 32 + lg * 8]);
#pragma unroll
    for (int mi = 0; mi < MI; ++mi)
#pragma unroll
      for (int ni = 0; ni < NI; ++ni)
        acc[mi][ni] = __builtin_amdgcn_mfma_f32_16x16x32_bf16(af[mi], bfr[ni], acc[mi][ni], 0, 0, 0);
    __syncthreads();
    cur ^= 1;
  }
#pragma unroll
  for (int mi = 0; mi < MI; ++mi) {
    int row = bm * BM + wm + mi * 16 + lg * 4;
#pragma unroll
    for (int ni = 0; ni < NI; ++ni) {
      int col = bn * BN + wn + ni * 16 + lr;
#pragma unroll
      for (int r = 0; r < 4; ++r) {
        float v = acc[mi][ni][r];
        size_t off = (size_t)(row + r) * N + col;
        if (EPI == 0) {
          ((float*)outv)[off] = v;
        } else if (EPI == 1) {
          ((float*)outv)[off] = v + bias[col] + res[off];
        } else if (EPI == 2) {
          float xg = v + bias[col];
          ((__bf16*)outv)[off] = (__bf16)(0.5f * xg * (1.0f + erff(xg * 0.7071067811865475f)));
        } else {
          ((float*)outv)[(size_t)bz * M * N + off] = v;
        }
      }
    }
  }
}

// ---------------- split-K reduce for ff2 ----------------
__global__ __launch_bounds__(256) void ff2red_kernel(const float* __restrict__ part,
                                                     const float* __restrict__ bias,
                                                     const float* __restrict__ res,
                                                     float* __restrict__ out, int MN, int N) {
  int idx = blockIdx.x * 256 + threadIdx.x;
  float4 p0 = ((const float4*)part)[idx];
  float4 p1 = ((const float4*)(part + MN))[idx];
  float4 rr = ((const float4*)res)[idx];
  int colb = (idx * 4) & (N - 1);
  float4 bb = *(const float4*)(bias + colb);
  float4 o;
  o.x = p0.x + p1.x + bb.x + rr.x;
  o.y = p0.y + p1.y + bb.y + rr.y;
  o.z = p0.z + p1.z + bb.z + rr.z;
  o.w = p0.w + p1.w + bb.w + rr.w;
  ((float4*)out)[idx] = o;
}

// ---------------- attention, split-K flash partials, LDS-staged K/V ----------------
// Q pre-scaled by DH^-0.5. Per block: 64 q-rows (4 waves x 16), KVBLK=64 per iter.
// K/V tiles double-buffered in LDS via global_load_lds with pre-swizzled source
// (LDS[row][col8^(row&7)] holds original [row][col8]); frag reads XOR back.
// S^T via mfma(K,Q): lane (lg,lr) holds S[k=nf*16+lg*4+r][q=lr].
// XCD swizzle: contiguous 128-block chunks per XCD -> same (bh,z) K/V L2-resident.
template <int KITERS>
__global__ __launch_bounds__(256) void attn_part_kernel(const __bf16* __restrict__ Qr,
                                                        const __bf16* __restrict__ Kr,
                                                        const __bf16* __restrict__ VT,
                                                        float* __restrict__ pO,
                                                        float* __restrict__ pml,
                                                        int Nq, int Nk) {
  __shared__ __bf16 sK[2][64 * 64];
  __shared__ __bf16 sV[2][64 * 64];
  __shared__ __bf16 Pl[4][16 * 64];
  const int t = threadIdx.x, w = t >> 6, lane = t & 63;
  const int lr = lane & 15, lg = lane >> 4;
  const int lsrc = lane & 48;
  const int swz = (lr & 7) << 3;
  int flat = blockIdx.x + (blockIdx.y << 4) + (blockIdx.z << 9);  // grid 16x32x2
  flat = (flat & 7) * 128 + (flat >> 3);
  const int bh = (flat >> 4) & 31, z = flat >> 9;
  const int q0 = (flat & 15) * 64 + w * 16;
  const int k0 = z * (KITERS * 64);

  auto stage = [&](int buf, int kt) {
#pragma unroll
    for (int i = 0; i < 2; ++i) {
      int e8 = i * 256 + t;                  // 16B-unit index in [0,512)
      int row = e8 >> 3, col8 = e8 & 7;
      int scol = (col8 ^ (row & 7)) << 3;    // pre-swizzled source column
      gload16(Kr + ((size_t)bh * Nk + kt + row) * 64 + scol, &sK[buf][e8 * 8]);
      gload16(VT + ((size_t)bh * 64 + row) * Nk + kt + scol, &sV[buf][e8 * 8]);
    }
  };

  bf16x8 qf[2];
#pragma unroll
  for (int kh = 0; kh < 2; ++kh)
    qf[kh] = *(const bf16x8*)(Qr + ((size_t)bh * Nq + q0 + lr) * 64 + kh * 32 + lg * 8);
  f32x4 accO[4] = {};
  float m = -INFINITY, l = 0.f;

  stage(0, k0);
  __syncthreads();
  int cur = 0;
#pragma unroll
  for (int it = 0; it < KITERS; ++it) {
    if (it + 1 < KITERS) stage(cur ^ 1, k0 + (it + 1) * 64);  // async prefetch
    f32x4 s[4] = {};
#pragma unroll
    for (int nf = 0; nf < 4; ++nf) {
      int r = nf * 16 + lr;
#pragma unroll
      for (int kh = 0; kh < 2; ++kh) {
        bf16x8 kf = *(const bf16x8*)(&sK[cur][r * 64 + (((kh * 4 + lg) ^ (lr & 7)) << 3)]);
        s[nf] = __builtin_amdgcn_mfma_f32_16x16x32_bf16(kf, qf[kh], s[nf], 0, 0, 0);
      }
    }
    float p[16];
#pragma unroll
    for (int j = 0; j < 16; ++j) p[j] = s[j >> 2][j & 3];
    float pm = p[0];
#pragma unroll
    for (int j = 1; j < 16; ++j) pm = fmaxf(pm, p[j]);
    pm = fmaxf(pm, __shfl_xor(pm, 16));
    pm = fmaxf(pm, __shfl_xor(pm, 32));
    if (!__all(pm <= m + 8.f)) {  // defer-max
      float mnew = fmaxf(m, pm);
      float resc = __expf(m - mnew);
      float rq[4];
#pragma unroll
      for (int r = 0; r < 4; ++r) rq[r] = __shfl(resc, lsrc | (lg * 4 + r));
#pragma unroll
      for (int df = 0; df < 4; ++df)
#pragma unroll
        for (int r = 0; r < 4; ++r) accO[df][r] *= rq[r];
      l *= resc;
      m = mnew;
    }
    float rs = 0.f;
#pragma unroll
    for (int j = 0; j < 16; ++j) { p[j] = __expf(p[j] - m); rs += p[j]; }
    rs += __shfl_xor(rs, 16);
    rs += __shfl_xor(rs, 32);
    l += rs;
    // P write: row q=lr, col k=nf*16+lg*4+jj*2, elem-XOR-swizzled
#pragma unroll
    for (int nf = 0; nf < 4; ++nf)
#pragma unroll
      for (int jj = 0; jj < 2; ++jj) {
        int k = nf * 16 + lg * 4 + 2 * jj;
        bf16x2 pk;
        pk[0] = (__bf16)p[nf * 4 + 2 * jj];
        pk[1] = (__bf16)p[nf * 4 + 2 * jj + 1];
        *(bf16x2*)(&Pl[w][lr * 64 + (k ^ swz)]) = pk;
      }
    bf16x8 pa0 = *(const bf16x8*)(&Pl[w][lr * 64 + ((lg * 8) ^ swz)]);
    bf16x8 pa1 = *(const bf16x8*)(&Pl[w][lr * 64 + ((32 + lg * 8) ^ swz)]);
#pragma unroll
    for (int df = 0; df < 4; ++df) {
      int d = df * 16 + lr;
      bf16x8 vf0 = *(const bf16x8*)(&sV[cur][d * 64 + ((lg ^ (lr & 7)) << 3)]);
      bf16x8 vf1 = *(const bf16x8*)(&sV[cur][d * 64 + (((4 + lg) ^ (lr & 7)) << 3)]);
      accO[df] = __builtin_amdgcn_mfma_f32_16x16x32_bf16(pa0, vf0, accO[df], 0, 0, 0);
      accO[df] = __builtin_amdgcn_mfma_f32_16x16x32_bf16(pa1, vf1, accO[df], 0, 0, 0);
    }
    __syncthreads();  // next buffer staged (vmcnt drained) + all waves done with cur
    cur ^= 1;
  }
  const size_t rbase = (size_t)(z * 32 + bh) * Nq + q0;
  if (lg == 0) {
    pml[(rbase + lr) * 2] = m;
    pml[(rbase + lr) * 2 + 1] = l;
  }
#pragma unroll
  for (int r = 0; r < 4; ++r)
#pragma unroll
    for (int df = 0; df < 4; ++df)
      pO[(rbase + lg * 4 + r) * 64 + df * 16 + lr] = accO[df][r];
}

// ---------------- combine 2 flash slices -> O token-major bf16 ----------------
__global__ __launch_bounds__(256) void attn_combine_kernel(const float* __restrict__ pO,
                                                           const float* __restrict__ pml,
                                                           __bf16* __restrict__ O) {
  int idx = blockIdx.x * 256 + threadIdx.x;  // 32768*64 threads
  int r = idx >> 6, dh = idx & 63;
  float m0 = pml[2 * r], l0 = pml[2 * r + 1];
  float m1 = pml[2 * (r + 32768)], l1 = pml[2 * (r + 32768) + 1];
  float O0 = pO[(size_t)r * 64 + dh];
  float O1 = pO[((size_t)r + 32768) * 64 + dh];
  float mm = fmaxf(m0, m1);
  float w0 = __expf(m0 - mm), w1 = __expf(m1 - mm);
  float val = (O0 * w0 + O1 * w1) / (l0 * w0 + l1 * w1);
  int bh = r >> 10, n = r & 1023;
  int b = bh >> 4, h = bh & 15;
  O[(size_t)(b * 1024 + n) * 1024 + h * 64 + dh] = (__bf16)val;
}

extern "C" void kernel_launch(void* const* d_in, const int* in_sizes, int n_in,
                              void* d_out, int out_size, void* d_ws, size_t ws_size,
                              hipStream_t stream) {
  (void)in_sizes; (void)n_in; (void)out_size; (void)ws_size;
  const float* x       = (const float*)d_in[0];
  const float* cond    = (const float*)d_in[1];
  const float* ctx     = (const float*)d_in[2];
  const float* ln1_w   = (const float*)d_in[3];
  const float* ln1_b   = (const float*)d_in[4];
  const float* g1_w    = (const float*)d_in[5];
  const float* g1_b    = (const float*)d_in[6];
  const float* b1_w    = (const float*)d_in[7];
  const float* b1_b    = (const float*)d_in[8];
  const float* ln2_w   = (const float*)d_in[9];
  const float* ln2_b   = (const float*)d_in[10];
  const float* g2_w    = (const float*)d_in[11];
  const float* g2_b    = (const float*)d_in[12];
  const float* b2_w    = (const float*)d_in[13];
  const float* b2_b    = (const float*)d_in[14];
  const float* sa_wq   = (const float*)d_in[15];
  const float* sa_wkv  = (const float*)d_in[16];
  const float* sa_wo   = (const float*)d_in[17];
  const float* sa_bo   = (const float*)d_in[18];
  const float* ca_lnc_w = (const float*)d_in[19];
  const float* ca_lnc_b = (const float*)d_in[20];
  const float* ca_wq   = (const float*)d_in[21];
  const float* ca_wkv  = (const float*)d_in[22];
  const float* ca_wo   = (const float*)d_in[23];
  const float* ca_bo   = (const float*)d_in[24];
  const float* ff_w1   = (const float*)d_in[25];
  const float* ff_b1   = (const float*)d_in[26];
  const float* ff_w2   = (const float*)d_in[27];
  const float* ff_b2   = (const float*)d_in[28];
  float* out = (float*)d_out;

  char* ws = (char*)d_ws;
  size_t o = 0;
  auto alloc = [&](size_t bytes) {
    void* p = ws + o;
    o += (bytes + 255) & ~(size_t)255;
    return p;
  };

  __bf16* wqT   = (__bf16*)alloc(1024ull * 1024 * 2);
  __bf16* wkvT  = (__bf16*)alloc(2048ull * 1024 * 2);
  __bf16* woT   = (__bf16*)alloc(1024ull * 1024 * 2);
  __bf16* cwqT  = (__bf16*)alloc(1024ull * 1024 * 2);
  __bf16* cwkvT = (__bf16*)alloc(2048ull * 768 * 2);
  __bf16* cwoT  = (__bf16*)alloc(1024ull * 1024 * 2);
  __bf16* ff1T  = (__bf16*)alloc(4096ull * 1024 * 2);
  __bf16* ff2T  = (__bf16*)alloc(1024ull * 4096 * 2);
  float*  mods  = (float*)alloc(4ull * 2 * 1024 * 4);
  float2* tbl   = (float2*)alloc(1024ull * 32 * 8);
  __bf16* ain   = (__bf16*)alloc(2048ull * 1024 * 2);
  float*  Qf    = (float*)alloc(2048ull * 1024 * 4);   // also: pml / mod partials
  float*  KVf   = (float*)alloc(2048ull * 2048 * 4);   // also: attn pO / FFN hidden
  __bf16* ctxn  = (__bf16*)alloc(1024ull * 768 * 2);
  __bf16* Qr    = (__bf16*)alloc(2048ull * 1024 * 2);  // Qr..Ob 16MB, reused as ff2 partials
  __bf16* Kr    = (__bf16*)alloc(2048ull * 1024 * 2);
  __bf16* VTb   = (__bf16*)alloc(2048ull * 1024 * 2);
  __bf16* Ob    = (__bf16*)alloc(2048ull * 1024 * 2);
  float*  x1    = (float*)alloc(2048ull * 1024 * 4);
  float*  x2    = (float*)alloc(2048ull * 1024 * 4);
  __bf16* hb    = (__bf16*)KVf;
  float*  pbuf  = (float*)Qr;
  float*  mpart = (float*)Qf;
  float*  pO    = (float*)KVf;
  float*  pml   = (float*)Qf;

  // ---- weight prep ----
  wt_kernel<<<dim3(32, 32), 256, 0, stream>>>(sa_wq, wqT, 1024, 1024);
  wt_kernel<<<dim3(64, 32), 256, 0, stream>>>(sa_wkv, wkvT, 1024, 2048);
  wt_kernel<<<dim3(32, 32), 256, 0, stream>>>(sa_wo, woT, 1024, 1024);
  wt_kernel<<<dim3(32, 32), 256, 0, stream>>>(ca_wq, cwqT, 1024, 1024);
  wt_kernel<<<dim3(64, 24), 256, 0, stream>>>(ca_wkv, cwkvT, 768, 2048);
  wt_kernel<<<dim3(32, 32), 256, 0, stream>>>(ca_wo, cwoT, 1024, 1024);
  wt_kernel<<<dim3(128, 32), 256, 0, stream>>>(ff_w1, ff1T, 1024, 4096);
  wt_kernel<<<dim3(32, 128), 256, 0, stream>>>(ff_w2, ff2T, 4096, 1024);
  rope_tbl_kernel<<<128, 256, 0, stream>>>(tbl);
  mod_part_kernel<<<dim3(4, 2, 32), 256, 0, stream>>>(cond, g1_w, b1_w, g2_w, b2_w, mpart);
  mod_reduce_kernel<<<32, 256, 0, stream>>>(mpart, g1_b, b1_b, g2_b, b2_b, mods);

  // ---- self attention ----
  adaln_kernel<<<2048, 256, 0, stream>>>(x, ln1_w, ln1_b, mods, 0, 1, ain);
  gemm3<64, 64, 0><<<dim3(32, 16), 256, 0, stream>>>(ain, wqT, nullptr, nullptr, Qf, 2048, 1024, 1024, 1);
  gemm3<64, 128, 0><<<dim3(32, 16), 256, 0, stream>>>(ain, wkvT, nullptr, nullptr, KVf, 2048, 2048, 1024, 1);
  rope_kernel<<<4096, 256, 0, stream>>>(Qf, 1024, 0, tbl, Qr, 1024, 0.125f);
  rope_kernel<<<4096, 256, 0, stream>>>(KVf, 2048, 0, tbl, Kr, 1024, 1.0f);
  vt_kernel<<<dim3(32, 32, 2), 256, 0, stream>>>(KVf, 2048, 1024, VTb, 1024);
  attn_part_kernel<8><<<dim3(16, 32, 2), 256, 0, stream>>>(Qr, Kr, VTb, pO, pml, 1024, 1024);
  attn_combine_kernel<<<8192, 256, 0, stream>>>(pO, pml, Ob);
  gemm3<64, 64, 1><<<dim3(32, 16), 256, 0, stream>>>(Ob, woT, sa_bo, x, x1, 2048, 1024, 1024, 1);

  // ---- cross attention ----
  adaln_kernel<<<2048, 256, 0, stream>>>(x1, ln1_w, ln1_b, mods, 0, 1, ain);
  ctxln_kernel<<<1024, 256, 0, stream>>>(ctx, ca_lnc_w, ca_lnc_b, ctxn);
  gemm3<64, 64, 0><<<dim3(32, 16), 256, 0, stream>>>(ain, cwqT, nullptr, nullptr, Qf, 2048, 1024, 1024, 1);
  gemm3<64, 64, 0><<<dim3(16, 32), 256, 0, stream>>>(ctxn, cwkvT, nullptr, nullptr, KVf, 1024, 2048, 768, 1);
  rope_kernel<<<4096, 256, 0, stream>>>(Qf, 1024, 0, tbl, Qr, 1024, 0.125f);
  rope_kernel<<<2048, 256, 0, stream>>>(KVf, 2048, 0, tbl, Kr, 512, 1.0f);
  vt_kernel<<<dim3(32, 16, 2), 256, 0, stream>>>(KVf, 2048, 1024, VTb, 512);
  attn_part_kernel<4><<<dim3(16, 32, 2), 256, 0, stream>>>(Qr, Kr, VTb, pO, pml, 1024, 512);
  attn_combine_kernel<<<8192, 256, 0, stream>>>(pO, pml, Ob);
  gemm3<64, 64, 1><<<dim3(32, 16), 256, 0, stream>>>(Ob, cwoT, ca_bo, x1, x2, 2048, 1024, 1024, 1);

  // ---- FFN ----
  adaln_kernel<<<2048, 256, 0, stream>>>(x2, ln2_w, ln2_b, mods, 2, 3, ain);
  gemm3<64, 128, 2><<<dim3(32, 32), 256, 0, stream>>>(ain, ff1T, ff_b1, nullptr, hb, 2048, 4096, 1024, 1);
  gemm3<64, 64, 3><<<dim3(32, 16, 2), 256, 0, stream>>>(hb, ff2T, nullptr, nullptr, pbuf, 2048, 1024, 4096, 2);
  ff2red_kernel<<<2048, 256, 0, stream>>>(pbuf, ff_b2, x2, out, 2048 * 1024, 1024);
}

// Round 6
// 295.316 us; speedup vs baseline: 1.7103x; 1.0221x over previous
//
#include <hip/hip_runtime.h>
#include <hip/hip_bf16.h>
#include <math.h>

// B=2 N=1024 M=512 D=1024 H=16 DH=64 MID=1024 DC=768 MULT=4

typedef float f32x4 __attribute__((ext_vector_type(4)));
typedef __bf16 bf16x8 __attribute__((ext_vector_type(8)));
typedef __bf16 bf16x4 __attribute__((ext_vector_type(4)));
typedef __bf16 bf16x2 __attribute__((ext_vector_type(2)));

#define DEVI __device__ __forceinline__

DEVI void gload16(const void* g, void* l) {
  __builtin_amdgcn_global_load_lds((const __attribute__((address_space(1))) void*)g,
                                   (__attribute__((address_space(3))) void*)l, 16, 0, 0);
}

// ---------------- fused weight transpose: 8 matrices, one launch ----------------
struct WtDesc {
  const float* src[8];
  __bf16* dst[8];
  int K[8], N[8];
  int tstart[9];  // cumulative 32x32-tile offsets
};

__global__ __launch_bounds__(256) void wt_all_kernel(WtDesc d) {
  __shared__ float tile[32][33];
  int blk = blockIdx.x;
  int e = 0;
#pragma unroll
  for (int i = 0; i < 7; ++i) e += (blk >= d.tstart[i + 1]) ? 1 : 0;
  int li = blk - d.tstart[e];
  const float* W = d.src[e];
  __bf16* WT = d.dst[e];
  int K = d.K[e], N = d.N[e];
  int ntx = N >> 5;
  int n0 = (li % ntx) * 32, k0 = (li / ntx) * 32;
  int tx = threadIdx.x & 31, ty = threadIdx.x >> 5;
#pragma unroll
  for (int i = 0; i < 4; ++i) {
    int k = ty + i * 8;
    tile[k][tx] = W[(size_t)(k0 + k) * N + n0 + tx];
  }
  __syncthreads();
#pragma unroll
  for (int i = 0; i < 4; ++i) {
    int n = ty + i * 8;
    WT[(size_t)(n0 + n) * K + k0 + tx] = (__bf16)tile[tx][n];
  }
}

// ---------------- modulation GEMV, k-split partials ----------------
__global__ __launch_bounds__(256) void mod_part_kernel(
    const float* __restrict__ cond,
    const float* __restrict__ g1w, const float* __restrict__ b1w,
    const float* __restrict__ g2w, const float* __restrict__ b2w,
    float* __restrict__ part) {
  __shared__ float sc[128];
  int dchunk = blockIdx.x, b = blockIdx.y;
  int mat = blockIdx.z >> 3, ks = blockIdx.z & 7;
  const float* W = (mat == 0) ? g1w : (mat == 1) ? b1w : (mat == 2) ? g2w : b2w;
  if (threadIdx.x < 128) sc[threadIdx.x] = cond[b * 1024 + ks * 128 + threadIdx.x];
  __syncthreads();
  int d = dchunk * 256 + threadIdx.x;
  const float* Wp = W + (size_t)(ks * 128) * 1024 + d;
  float acc = 0.f;
#pragma unroll 8
  for (int k = 0; k < 128; ++k) acc += sc[k] * Wp[(size_t)k * 1024];
  part[(size_t)(blockIdx.z * 2 + b) * 1024 + d] = acc;
}

__global__ __launch_bounds__(256) void mod_reduce_kernel(
    const float* __restrict__ part,
    const float* __restrict__ g1b, const float* __restrict__ b1b,
    const float* __restrict__ g2b, const float* __restrict__ b2b,
    float* __restrict__ mods) {
  int idx = blockIdx.x * 256 + threadIdx.x;  // 0..8191
  int mat = idx >> 11, b = (idx >> 10) & 1, d = idx & 1023;
  float s = 0.f;
#pragma unroll
  for (int ks = 0; ks < 8; ++ks) s += part[(size_t)((mat * 8 + ks) * 2 + b) * 1024 + d];
  const float* Bv = (mat == 0) ? g1b : (mat == 1) ? b1b : (mat == 2) ? g2b : b2b;
  mods[(size_t)(mat * 2 + b) * 1024 + d] = s + Bv[d];
}

// ---------------- adaLN: out_bf16 = LN(x)*(1+g)+bt ----------------
__global__ __launch_bounds__(256) void adaln_kernel(const float* __restrict__ X,
                                                    const float* __restrict__ lnw,
                                                    const float* __restrict__ lnb,
                                                    const float* __restrict__ mods,
                                                    int gi, int bi,
                                                    __bf16* __restrict__ out) {
  __shared__ float red[2][4];
  int row = blockIdx.x;  // 0..2047
  int b = row >> 10;
  int t = threadIdx.x;
  const float4 xv = ((const float4*)(X + (size_t)row * 1024))[t];
  float s  = xv.x + xv.y + xv.z + xv.w;
  float s2 = xv.x * xv.x + xv.y * xv.y + xv.z * xv.z + xv.w * xv.w;
  int lane = t & 63, w = t >> 6;
#pragma unroll
  for (int off = 32; off > 0; off >>= 1) {
    s += __shfl_down(s, off);
    s2 += __shfl_down(s2, off);
  }
  if (lane == 0) { red[0][w] = s; red[1][w] = s2; }
  __syncthreads();
  s  = red[0][0] + red[0][1] + red[0][2] + red[0][3];
  s2 = red[1][0] + red[1][1] + red[1][2] + red[1][3];
  float mu = s * (1.0f / 1024.0f);
  float var = s2 * (1.0f / 1024.0f) - mu * mu;
  float rstd = rsqrtf(var + 1e-5f);
  const float4 wv = ((const float4*)lnw)[t];
  const float4 bv = ((const float4*)lnb)[t];
  const float4 gv = ((const float4*)(mods + (size_t)(gi * 2 + b) * 1024))[t];
  const float4 tv = ((const float4*)(mods + (size_t)(bi * 2 + b) * 1024))[t];
  bf16x4 ov;
  ov[0] = (__bf16)(((xv.x - mu) * rstd * wv.x + bv.x) * (1.0f + gv.x) + tv.x);
  ov[1] = (__bf16)(((xv.y - mu) * rstd * wv.y + bv.y) * (1.0f + gv.y) + tv.y);
  ov[2] = (__bf16)(((xv.z - mu) * rstd * wv.z + bv.z) * (1.0f + gv.z) + tv.z);
  ov[3] = (__bf16)(((xv.w - mu) * rstd * wv.w + bv.w) * (1.0f + gv.w) + tv.w);
  *(bf16x4*)(out + (size_t)row * 1024 + t * 4) = ov;
}

// ---------------- context LN (D=768) ----------------
__global__ __launch_bounds__(256) void ctxln_kernel(const float* __restrict__ X,
                                                    const float* __restrict__ w,
                                                    const float* __restrict__ bias,
                                                    __bf16* __restrict__ out) {
  __shared__ float red[2][4];
  int row = blockIdx.x;  // 0..1023
  int t = threadIdx.x;
  const float* xp = X + (size_t)row * 768;
  float v[3];
  float s = 0.f, s2 = 0.f;
#pragma unroll
  for (int i = 0; i < 3; ++i) {
    v[i] = xp[t + i * 256];
    s += v[i];
    s2 += v[i] * v[i];
  }
  int lane = t & 63, wv_ = t >> 6;
#pragma unroll
  for (int off = 32; off > 0; off >>= 1) {
    s += __shfl_down(s, off);
    s2 += __shfl_down(s2, off);
  }
  if (lane == 0) { red[0][wv_] = s; red[1][wv_] = s2; }
  __syncthreads();
  s  = red[0][0] + red[0][1] + red[0][2] + red[0][3];
  s2 = red[1][0] + red[1][1] + red[1][2] + red[1][3];
  float mu = s * (1.0f / 768.0f);
  float var = s2 * (1.0f / 768.0f) - mu * mu;
  float rstd = rsqrtf(var + 1e-5f);
#pragma unroll
  for (int i = 0; i < 3; ++i) {
    int c = t + i * 256;
    out[(size_t)row * 768 + c] = (__bf16)((v[i] - mu) * rstd * w[c] + bias[c]);
  }
}

// ---------------- rope table ----------------
__global__ __launch_bounds__(256) void rope_tbl_kernel(float2* __restrict__ tbl) {
  int idx = blockIdx.x * 256 + threadIdx.x;  // 1024*32
  int n = idx >> 5, i = idx & 31;
  float inv = expf(-(float)(2 * i) * (1.0f / 64.0f) * 9.210340371976184f);  // ln(10000)
  float ang = (float)n * inv;
  tbl[idx] = make_float2(sinf(ang), cosf(ang));
}

// ---------------- rope + head-layout (+ optional scale) ----------------
__global__ __launch_bounds__(256) void rope_kernel(const float* __restrict__ X, int ldx, int col0,
                                                   const float2* __restrict__ tbl,
                                                   __bf16* __restrict__ out, int Ntok, float scale) {
  int idx = blockIdx.x * 256 + threadIdx.x;  // B*Ntok*16*32
  int i = idx & 31;
  int h = (idx >> 5) & 15;
  int nn = idx >> 9;
  int n = nn % Ntok;
  int b = nn / Ntok;
  const float* xp = X + (size_t)(b * Ntok + n) * ldx + col0 + h * 64 + 2 * i;
  float xe = xp[0], xo = xp[1];
  float2 sc2 = tbl[n * 32 + i];
  float re = (xe * sc2.y - xo * sc2.x) * scale;
  float ro = (xe * sc2.x + xo * sc2.y) * scale;
  __bf16* op = out + ((size_t)(b * 16 + h) * Ntok + n) * 64 + 2 * i;
  op[0] = (__bf16)re;
  op[1] = (__bf16)ro;
}

// ---------------- V transpose ----------------
__global__ __launch_bounds__(256) void vt_kernel(const float* __restrict__ KV, int ld, int col0,
                                                 __bf16* __restrict__ VT, int Ntok) {
  __shared__ float tile[32][33];
  int bh = blockIdx.x;
  int n0 = blockIdx.y * 32, d0 = blockIdx.z * 32;
  int b = bh >> 4, h = bh & 15;
  int tx = threadIdx.x & 31, ty = threadIdx.x >> 5;
#pragma unroll
  for (int i = 0; i < 4; ++i) {
    int n = ty + i * 8;
    tile[n][tx] = KV[(size_t)(b * Ntok + n0 + n) * ld + col0 + h * 64 + d0 + tx];
  }
  __syncthreads();
#pragma unroll
  for (int i = 0; i < 4; ++i) {
    int d = ty + i * 8;
    VT[((size_t)bh * 64 + d0 + d) * Ntok + n0 + tx] = (__bf16)tile[tx][d];
  }
}

// ---------------- pipelined bf16 GEMM: C[M,N] = A[M,K] @ BT[N,K]^T ----------------
// EPI: 0 fp32 out; 1 fp32 out+bias+res; 2 bf16 gelu(acc+bias); 3 fp32 partial at slice z
template <int BM, int BN, int EPI>
__global__ __launch_bounds__(256) void gemm3(const __bf16* __restrict__ A,
                                             const __bf16* __restrict__ BT,
                                             const float* __restrict__ bias,
                                             const float* __restrict__ res,
                                             void* __restrict__ outv,
                                             int M, int N, int K, int kslices) {
  constexpr int MI = BM / 32, NI = BN / 32;
  __shared__ __bf16 sA[2][BM * 32];
  __shared__ __bf16 sB[2][BN * 32];
  const int t = threadIdx.x;
  const int w = t >> 6, lane = t & 63;
  const int lr = lane & 15, lg = lane >> 4;
  // XCD-aware bijective block swizzle (all grids are multiples of 8)
  int nwg = gridDim.x * gridDim.y * gridDim.z;
  int flat = blockIdx.x + gridDim.x * (blockIdx.y + gridDim.y * blockIdx.z);
  flat = (flat & 7) * (nwg >> 3) + (flat >> 3);
  const int bm = flat % gridDim.x;
  int rest = flat / gridDim.x;
  const int bn = rest % gridDim.y;
  const int bz = rest / gridDim.y;
  const int wm = (w >> 1) * (BM / 2), wn = (w & 1) * (BN / 2);
  const int kper = K / kslices;
  const int k0 = bz * kper;
  f32x4 acc[MI][NI] = {};

  auto stage = [&](int buf, int kt) {
#pragma unroll
    for (int i = 0; i < BM / 64; ++i) {
      int e = (i * 256 + t) * 8;
      int row = e >> 5, col = e & 31;
      gload16(A + (size_t)(bm * BM + row) * K + kt + col, &sA[buf][e]);
    }
#pragma unroll
    for (int i = 0; i < BN / 64; ++i) {
      int e = (i * 256 + t) * 8;
      int row = e >> 5, col = e & 31;
      gload16(BT + (size_t)(bn * BN + row) * K + kt + col, &sB[buf][e]);
    }
  };

  stage(0, k0);
  __syncthreads();
  int cur = 0;
  for (int kt = k0; kt < k0 + kper; kt += 32) {
    if (kt + 32 < k0 + kper) stage(cur ^ 1, kt + 32);  // prefetch next tile
    bf16x8 af[MI], bfr[NI];
#pragma unroll
    for (int mi = 0; mi < MI; ++mi)
      af[mi] = *(const bf16x8*)(&sA[cur][(wm + mi * 16 + lr) * 32 + lg * 8]);
#pragma unroll
    for (int ni = 0; ni < NI; ++ni)
      bfr[ni] = *(const bf16x8*)(&sB[cur][(wn + ni * 16 + lr) * 32 + lg * 8]);
#pragma unroll
    for (int mi = 0; mi < MI; ++mi)
#pragma unroll
      for (int ni = 0; ni < NI; ++ni)
        acc[mi][ni] = __builtin_amdgcn_mfma_f32_16x16x32_bf16(af[mi], bfr[ni], acc[mi][ni], 0, 0, 0);
    __syncthreads();
    cur ^= 1;
  }
#pragma unroll
  for (int mi = 0; mi < MI; ++mi) {
    int row = bm * BM + wm + mi * 16 + lg * 4;
#pragma unroll
    for (int ni = 0; ni < NI; ++ni) {
      int col = bn * BN + wn + ni * 16 + lr;
#pragma unroll
      for (int r = 0; r < 4; ++r) {
        float v = acc[mi][ni][r];
        size_t off = (size_t)(row + r) * N + col;
        if (EPI == 0) {
          ((float*)outv)[off] = v;
        } else if (EPI == 1) {
          ((float*)outv)[off] = v + bias[col] + res[off];
        } else if (EPI == 2) {
          float xg = v + bias[col];
          ((__bf16*)outv)[off] = (__bf16)(0.5f * xg * (1.0f + erff(xg * 0.7071067811865475f)));
        } else {
          ((float*)outv)[(size_t)bz * M * N + off] = v;
        }
      }
    }
  }
}

// ---------------- split-K reduce for ff2 ----------------
__global__ __launch_bounds__(256) void ff2red_kernel(const float* __restrict__ part,
                                                     const float* __restrict__ bias,
                                                     const float* __restrict__ res,
                                                     float* __restrict__ out, int MN, int N) {
  int idx = blockIdx.x * 256 + threadIdx.x;
  float4 p0 = ((const float4*)part)[idx];
  float4 p1 = ((const float4*)(part + MN))[idx];
  float4 rr = ((const float4*)res)[idx];
  int colb = (idx * 4) & (N - 1);
  float4 bb = *(const float4*)(bias + colb);
  float4 o;
  o.x = p0.x + p1.x + bb.x + rr.x;
  o.y = p0.y + p1.y + bb.y + rr.y;
  o.z = p0.z + p1.z + bb.z + rr.z;
  o.w = p0.w + p1.w + bb.w + rr.w;
  ((float4*)out)[idx] = o;
}

// ---------------- attention, split-K flash partials, LDS-staged K/V ----------------
template <int KITERS>
__global__ __launch_bounds__(256) void attn_part_kernel(const __bf16* __restrict__ Qr,
                                                        const __bf16* __restrict__ Kr,
                                                        const __bf16* __restrict__ VT,
                                                        float* __restrict__ pO,
                                                        float* __restrict__ pml,
                                                        int Nq, int Nk) {
  __shared__ __bf16 sK[2][64 * 64];
  __shared__ __bf16 sV[2][64 * 64];
  __shared__ __bf16 Pl[4][16 * 64];
  const int t = threadIdx.x, w = t >> 6, lane = t & 63;
  const int lr = lane & 15, lg = lane >> 4;
  const int lsrc = lane & 48;
  const int swz = (lr & 7) << 3;
  int flat = blockIdx.x + (blockIdx.y << 4) + (blockIdx.z << 9);  // grid 16x32x2
  flat = (flat & 7) * 128 + (flat >> 3);
  const int bh = (flat >> 4) & 31, z = flat >> 9;
  const int q0 = (flat & 15) * 64 + w * 16;
  const int k0 = z * (KITERS * 64);

  auto stage = [&](int buf, int kt) {
#pragma unroll
    for (int i = 0; i < 2; ++i) {
      int e8 = i * 256 + t;                  // 16B-unit index in [0,512)
      int row = e8 >> 3, col8 = e8 & 7;
      int scol = (col8 ^ (row & 7)) << 3;    // pre-swizzled source column
      gload16(Kr + ((size_t)bh * Nk + kt + row) * 64 + scol, &sK[buf][e8 * 8]);
      gload16(VT + ((size_t)bh * 64 + row) * Nk + kt + scol, &sV[buf][e8 * 8]);
    }
  };

  bf16x8 qf[2];
#pragma unroll
  for (int kh = 0; kh < 2; ++kh)
    qf[kh] = *(const bf16x8*)(Qr + ((size_t)bh * Nq + q0 + lr) * 64 + kh * 32 + lg * 8);
  f32x4 accO[4] = {};
  float m = -INFINITY, l = 0.f;

  stage(0, k0);
  __syncthreads();
  int cur = 0;
#pragma unroll
  for (int it = 0; it < KITERS; ++it) {
    if (it + 1 < KITERS) stage(cur ^ 1, k0 + (it + 1) * 64);  // async prefetch
    f32x4 s[4] = {};
#pragma unroll
    for (int nf = 0; nf < 4; ++nf) {
      int r = nf * 16 + lr;
#pragma unroll
      for (int kh = 0; kh < 2; ++kh) {
        bf16x8 kf = *(const bf16x8*)(&sK[cur][r * 64 + (((kh * 4 + lg) ^ (lr & 7)) << 3)]);
        s[nf] = __builtin_amdgcn_mfma_f32_16x16x32_bf16(kf, qf[kh], s[nf], 0, 0, 0);
      }
    }
    float p[16];
#pragma unroll
    for (int j = 0; j < 16; ++j) p[j] = s[j >> 2][j & 3];
    float pm = p[0];
#pragma unroll
    for (int j = 1; j < 16; ++j) pm = fmaxf(pm, p[j]);
    pm = fmaxf(pm, __shfl_xor(pm, 16));
    pm = fmaxf(pm, __shfl_xor(pm, 32));
    if (!__all(pm <= m + 8.f)) {  // defer-max
      float mnew = fmaxf(m, pm);
      float resc = __expf(m - mnew);
      float rq[4];
#pragma unroll
      for (int r = 0; r < 4; ++r) rq[r] = __shfl(resc, lsrc | (lg * 4 + r));
#pragma unroll
      for (int df = 0; df < 4; ++df)
#pragma unroll
        for (int r = 0; r < 4; ++r) accO[df][r] *= rq[r];
      l *= resc;
      m = mnew;
    }
    float rs = 0.f;
#pragma unroll
    for (int j = 0; j < 16; ++j) { p[j] = __expf(p[j] - m); rs += p[j]; }
    rs += __shfl_xor(rs, 16);
    rs += __shfl_xor(rs, 32);
    l += rs;
#pragma unroll
    for (int nf = 0; nf < 4; ++nf)
#pragma unroll
      for (int jj = 0; jj < 2; ++jj) {
        int k = nf * 16 + lg * 4 + 2 * jj;
        bf16x2 pk;
        pk[0] = (__bf16)p[nf * 4 + 2 * jj];
        pk[1] = (__bf16)p[nf * 4 + 2 * jj + 1];
        *(bf16x2*)(&Pl[w][lr * 64 + (k ^ swz)]) = pk;
      }
    bf16x8 pa0 = *(const bf16x8*)(&Pl[w][lr * 64 + ((lg * 8) ^ swz)]);
    bf16x8 pa1 = *(const bf16x8*)(&Pl[w][lr * 64 + ((32 + lg * 8) ^ swz)]);
#pragma unroll
    for (int df = 0; df < 4; ++df) {
      int d = df * 16 + lr;
      bf16x8 vf0 = *(const bf16x8*)(&sV[cur][d * 64 + ((lg ^ (lr & 7)) << 3)]);
      bf16x8 vf1 = *(const bf16x8*)(&sV[cur][d * 64 + (((4 + lg) ^ (lr & 7)) << 3)]);
      accO[df] = __builtin_amdgcn_mfma_f32_16x16x32_bf16(pa0, vf0, accO[df], 0, 0, 0);
      accO[df] = __builtin_amdgcn_mfma_f32_16x16x32_bf16(pa1, vf1, accO[df], 0, 0, 0);
    }
    __syncthreads();
    cur ^= 1;
  }
  const size_t rbase = (size_t)(z * 32 + bh) * Nq + q0;
  if (lg == 0) {
    pml[(rbase + lr) * 2] = m;
    pml[(rbase + lr) * 2 + 1] = l;
  }
#pragma unroll
  for (int r = 0; r < 4; ++r)
#pragma unroll
    for (int df = 0; df < 4; ++df)
      pO[(rbase + lg * 4 + r) * 64 + df * 16 + lr] = accO[df][r];
}

// ---------------- combine 2 flash slices -> O token-major bf16 ----------------
__global__ __launch_bounds__(256) void attn_combine_kernel(const float* __restrict__ pO,
                                                           const float* __restrict__ pml,
                                                           __bf16* __restrict__ O) {
  int idx = blockIdx.x * 256 + threadIdx.x;  // 32768*64 threads
  int r = idx >> 6, dh = idx & 63;
  float m0 = pml[2 * r], l0 = pml[2 * r + 1];
  float m1 = pml[2 * (r + 32768)], l1 = pml[2 * (r + 32768) + 1];
  float O0 = pO[(size_t)r * 64 + dh];
  float O1 = pO[((size_t)r + 32768) * 64 + dh];
  float mm = fmaxf(m0, m1);
  float w0 = __expf(m0 - mm), w1 = __expf(m1 - mm);
  float val = (O0 * w0 + O1 * w1) / (l0 * w0 + l1 * w1);
  int bh = r >> 10, n = r & 1023;
  int b = bh >> 4, h = bh & 15;
  O[(size_t)(b * 1024 + n) * 1024 + h * 64 + dh] = (__bf16)val;
}

extern "C" void kernel_launch(void* const* d_in, const int* in_sizes, int n_in,
                              void* d_out, int out_size, void* d_ws, size_t ws_size,
                              hipStream_t stream) {
  (void)in_sizes; (void)n_in; (void)out_size; (void)ws_size;
  const float* x       = (const float*)d_in[0];
  const float* cond    = (const float*)d_in[1];
  const float* ctx     = (const float*)d_in[2];
  const float* ln1_w   = (const float*)d_in[3];
  const float* ln1_b   = (const float*)d_in[4];
  const float* g1_w    = (const float*)d_in[5];
  const float* g1_b    = (const float*)d_in[6];
  const float* b1_w    = (const float*)d_in[7];
  const float* b1_b    = (const float*)d_in[8];
  const float* ln2_w   = (const float*)d_in[9];
  const float* ln2_b   = (const float*)d_in[10];
  const float* g2_w    = (const float*)d_in[11];
  const float* g2_b    = (const float*)d_in[12];
  const float* b2_w    = (const float*)d_in[13];
  const float* b2_b    = (const float*)d_in[14];
  const float* sa_wq   = (const float*)d_in[15];
  const float* sa_wkv  = (const float*)d_in[16];
  const float* sa_wo   = (const float*)d_in[17];
  const float* sa_bo   = (const float*)d_in[18];
  const float* ca_lnc_w = (const float*)d_in[19];
  const float* ca_lnc_b = (const float*)d_in[20];
  const float* ca_wq   = (const float*)d_in[21];
  const float* ca_wkv  = (const float*)d_in[22];
  const float* ca_wo   = (const float*)d_in[23];
  const float* ca_bo   = (const float*)d_in[24];
  const float* ff_w1   = (const float*)d_in[25];
  const float* ff_b1   = (const float*)d_in[26];
  const float* ff_w2   = (const float*)d_in[27];
  const float* ff_b2   = (const float*)d_in[28];
  float* out = (float*)d_out;

  char* ws = (char*)d_ws;
  size_t o = 0;
  auto alloc = [&](size_t bytes) {
    void* p = ws + o;
    o += (bytes + 255) & ~(size_t)255;
    return p;
  };

  __bf16* wqT   = (__bf16*)alloc(1024ull * 1024 * 2);  // wqT+wkvT contiguous => BT[3072][1024]
  __bf16* wkvT  = (__bf16*)alloc(2048ull * 1024 * 2);
  __bf16* woT   = (__bf16*)alloc(1024ull * 1024 * 2);
  __bf16* cwqT  = (__bf16*)alloc(1024ull * 1024 * 2);
  __bf16* cwkvT = (__bf16*)alloc(2048ull * 768 * 2);
  __bf16* cwoT  = (__bf16*)alloc(1024ull * 1024 * 2);
  __bf16* ff1T  = (__bf16*)alloc(4096ull * 1024 * 2);
  __bf16* ff2T  = (__bf16*)alloc(1024ull * 4096 * 2);
  float*  mods  = (float*)alloc(4ull * 2 * 1024 * 4);
  float2* tbl   = (float2*)alloc(1024ull * 32 * 8);
  __bf16* ain   = (__bf16*)alloc(2048ull * 1024 * 2);
  float*  Qf    = (float*)alloc(2048ull * 1024 * 4);   // Qf+KVf = contiguous 24MB QKV span
  float*  KVf   = (float*)alloc(2048ull * 2048 * 4);
  __bf16* ctxn  = (__bf16*)alloc(1024ull * 768 * 2);
  __bf16* Qr    = (__bf16*)alloc(2048ull * 1024 * 2);
  __bf16* Kr    = (__bf16*)alloc(2048ull * 1024 * 2);
  __bf16* VTb   = (__bf16*)alloc(2048ull * 1024 * 2);
  __bf16* Ob    = (__bf16*)alloc(2048ull * 1024 * 2);
  float*  x1    = (float*)alloc(2048ull * 1024 * 4);
  float*  x2    = (float*)alloc(2048ull * 1024 * 4);
  float*  QKVf  = Qf;            // [2048][3072] fp32 self-attn fused output
  __bf16* hb    = (__bf16*)KVf;  // FFN hidden (2048x4096 bf16)
  float*  pbuf  = (float*)Qr;    // ff2 split-K partials: 2 x 8MB
  float*  mpart = (float*)Qf;    // mod GEMV partials
  float*  pO    = (float*)KVf;   // attn partials (16MB)
  float*  pml   = (float*)Qf;    // attn m/l (512KB)

  // ---- weight prep: one fused launch ----
  WtDesc wd;
  const float* srcs[8] = {sa_wq, sa_wkv, sa_wo, ca_wq, ca_wkv, ca_wo, ff_w1, ff_w2};
  __bf16* dsts[8] = {wqT, wkvT, woT, cwqT, cwkvT, cwoT, ff1T, ff2T};
  int Ks[8] = {1024, 1024, 1024, 1024, 768, 1024, 1024, 4096};
  int Ns[8] = {1024, 2048, 1024, 1024, 2048, 1024, 4096, 1024};
  int cum = 0;
  for (int i = 0; i < 8; ++i) {
    wd.src[i] = srcs[i]; wd.dst[i] = dsts[i]; wd.K[i] = Ks[i]; wd.N[i] = Ns[i];
    wd.tstart[i] = cum;
    cum += (Ks[i] >> 5) * (Ns[i] >> 5);
  }
  wd.tstart[8] = cum;  // 15872
  wt_all_kernel<<<cum, 256, 0, stream>>>(wd);
  rope_tbl_kernel<<<128, 256, 0, stream>>>(tbl);
  mod_part_kernel<<<dim3(4, 2, 32), 256, 0, stream>>>(cond, g1_w, b1_w, g2_w, b2_w, mpart);
  mod_reduce_kernel<<<32, 256, 0, stream>>>(mpart, g1_b, b1_b, g2_b, b2_b, mods);

  // ---- self attention (fused QKV projection: N=3072) ----
  adaln_kernel<<<2048, 256, 0, stream>>>(x, ln1_w, ln1_b, mods, 0, 1, ain);
  gemm3<128, 64, 0><<<dim3(16, 48), 256, 0, stream>>>(ain, wqT, nullptr, nullptr, QKVf, 2048, 3072, 1024, 1);
  rope_kernel<<<4096, 256, 0, stream>>>(QKVf, 3072, 0, tbl, Qr, 1024, 0.125f);
  rope_kernel<<<4096, 256, 0, stream>>>(QKVf, 3072, 1024, tbl, Kr, 1024, 1.0f);
  vt_kernel<<<dim3(32, 32, 2), 256, 0, stream>>>(QKVf, 3072, 2048, VTb, 1024);
  attn_part_kernel<8><<<dim3(16, 32, 2), 256, 0, stream>>>(Qr, Kr, VTb, pO, pml, 1024, 1024);
  attn_combine_kernel<<<8192, 256, 0, stream>>>(pO, pml, Ob);
  gemm3<128, 64, 1><<<dim3(16, 16), 256, 0, stream>>>(Ob, woT, sa_bo, x, x1, 2048, 1024, 1024, 1);

  // ---- cross attention ----
  adaln_kernel<<<2048, 256, 0, stream>>>(x1, ln1_w, ln1_b, mods, 0, 1, ain);
  ctxln_kernel<<<1024, 256, 0, stream>>>(ctx, ca_lnc_w, ca_lnc_b, ctxn);
  gemm3<128, 64, 0><<<dim3(16, 16), 256, 0, stream>>>(ain, cwqT, nullptr, nullptr, Qf, 2048, 1024, 1024, 1);
  gemm3<64, 128, 0><<<dim3(16, 16), 256, 0, stream>>>(ctxn, cwkvT, nullptr, nullptr, KVf, 1024, 2048, 768, 1);
  rope_kernel<<<4096, 256, 0, stream>>>(Qf, 1024, 0, tbl, Qr, 1024, 0.125f);
  rope_kernel<<<2048, 256, 0, stream>>>(KVf, 2048, 0, tbl, Kr, 512, 1.0f);
  vt_kernel<<<dim3(32, 16, 2), 256, 0, stream>>>(KVf, 2048, 1024, VTb, 512);
  attn_part_kernel<4><<<dim3(16, 32, 2), 256, 0, stream>>>(Qr, Kr, VTb, pO, pml, 1024, 512);
  attn_combine_kernel<<<8192, 256, 0, stream>>>(pO, pml, Ob);
  gemm3<128, 64, 1><<<dim3(16, 16), 256, 0, stream>>>(Ob, cwoT, ca_bo, x1, x2, 2048, 1024, 1024, 1);

  // ---- FFN ----
  adaln_kernel<<<2048, 256, 0, stream>>>(x2, ln2_w, ln2_b, mods, 2, 3, ain);
  gemm3<128, 128, 2><<<dim3(16, 32), 256, 0, stream>>>(ain, ff1T, ff_b1, nullptr, hb, 2048, 4096, 1024, 1);
  gemm3<128, 128, 3><<<dim3(16, 8, 2), 256, 0, stream>>>(hb, ff2T, nullptr, nullptr, pbuf, 2048, 1024, 4096, 2);
  ff2red_kernel<<<2048, 256, 0, stream>>>(pbuf, ff_b2, x2, out, 2048 * 1024, 1024);
}

// Round 7
// 285.229 us; speedup vs baseline: 1.7708x; 1.0354x over previous
//
#include <hip/hip_runtime.h>
#include <hip/hip_bf16.h>
#include <math.h>

// B=2 N=1024 M=512 D=1024 H=16 DH=64 MID=1024 DC=768 MULT=4

typedef float f32x4 __attribute__((ext_vector_type(4)));
typedef __bf16 bf16x8 __attribute__((ext_vector_type(8)));
typedef __bf16 bf16x4 __attribute__((ext_vector_type(4)));
typedef __bf16 bf16x2 __attribute__((ext_vector_type(2)));

#define DEVI __device__ __forceinline__

DEVI void gload16(const void* g, void* l) {
  __builtin_amdgcn_global_load_lds((const __attribute__((address_space(1))) void*)g,
                                   (__attribute__((address_space(3))) void*)l, 16, 0, 0);
}

// ---------------- fused weight transpose: 8 matrices, one launch ----------------
struct WtDesc {
  const float* src[8];
  __bf16* dst[8];
  int K[8], N[8];
  int tstart[9];  // cumulative 32x32-tile offsets
};

__global__ __launch_bounds__(256) void wt_all_kernel(WtDesc d) {
  __shared__ float tile[32][33];
  int blk = blockIdx.x;
  int e = 0;
#pragma unroll
  for (int i = 0; i < 7; ++i) e += (blk >= d.tstart[i + 1]) ? 1 : 0;
  int li = blk - d.tstart[e];
  const float* W = d.src[e];
  __bf16* WT = d.dst[e];
  int K = d.K[e], N = d.N[e];
  int ntx = N >> 5;
  int n0 = (li % ntx) * 32, k0 = (li / ntx) * 32;
  int tx = threadIdx.x & 31, ty = threadIdx.x >> 5;
#pragma unroll
  for (int i = 0; i < 4; ++i) {
    int k = ty + i * 8;
    tile[k][tx] = W[(size_t)(k0 + k) * N + n0 + tx];
  }
  __syncthreads();
#pragma unroll
  for (int i = 0; i < 4; ++i) {
    int n = ty + i * 8;
    WT[(size_t)(n0 + n) * K + k0 + tx] = (__bf16)tile[tx][n];
  }
}

// ---------------- modulation GEMV, k-split partials ----------------
__global__ __launch_bounds__(256) void mod_part_kernel(
    const float* __restrict__ cond,
    const float* __restrict__ g1w, const float* __restrict__ b1w,
    const float* __restrict__ g2w, const float* __restrict__ b2w,
    float* __restrict__ part) {
  __shared__ float sc[128];
  int dchunk = blockIdx.x, b = blockIdx.y;
  int mat = blockIdx.z >> 3, ks = blockIdx.z & 7;
  const float* W = (mat == 0) ? g1w : (mat == 1) ? b1w : (mat == 2) ? g2w : b2w;
  if (threadIdx.x < 128) sc[threadIdx.x] = cond[b * 1024 + ks * 128 + threadIdx.x];
  __syncthreads();
  int d = dchunk * 256 + threadIdx.x;
  const float* Wp = W + (size_t)(ks * 128) * 1024 + d;
  float acc = 0.f;
#pragma unroll 8
  for (int k = 0; k < 128; ++k) acc += sc[k] * Wp[(size_t)k * 1024];
  part[(size_t)(blockIdx.z * 2 + b) * 1024 + d] = acc;
}

__global__ __launch_bounds__(256) void mod_reduce_kernel(
    const float* __restrict__ part,
    const float* __restrict__ g1b, const float* __restrict__ b1b,
    const float* __restrict__ g2b, const float* __restrict__ b2b,
    float* __restrict__ mods) {
  int idx = blockIdx.x * 256 + threadIdx.x;  // 0..8191
  int mat = idx >> 11, b = (idx >> 10) & 1, d = idx & 1023;
  float s = 0.f;
#pragma unroll
  for (int ks = 0; ks < 8; ++ks) s += part[(size_t)((mat * 8 + ks) * 2 + b) * 1024 + d];
  const float* Bv = (mat == 0) ? g1b : (mat == 1) ? b1b : (mat == 2) ? g2b : b2b;
  mods[(size_t)(mat * 2 + b) * 1024 + d] = s + Bv[d];
}

// ---------------- adaLN: out_bf16 = LN(x)*(1+g)+bt ----------------
__global__ __launch_bounds__(256) void adaln_kernel(const float* __restrict__ X,
                                                    const float* __restrict__ lnw,
                                                    const float* __restrict__ lnb,
                                                    const float* __restrict__ mods,
                                                    int gi, int bi,
                                                    __bf16* __restrict__ out) {
  __shared__ float red[2][4];
  int row = blockIdx.x;  // 0..2047
  int b = row >> 10;
  int t = threadIdx.x;
  const float4 xv = ((const float4*)(X + (size_t)row * 1024))[t];
  float s  = xv.x + xv.y + xv.z + xv.w;
  float s2 = xv.x * xv.x + xv.y * xv.y + xv.z * xv.z + xv.w * xv.w;
  int lane = t & 63, w = t >> 6;
#pragma unroll
  for (int off = 32; off > 0; off >>= 1) {
    s += __shfl_down(s, off);
    s2 += __shfl_down(s2, off);
  }
  if (lane == 0) { red[0][w] = s; red[1][w] = s2; }
  __syncthreads();
  s  = red[0][0] + red[0][1] + red[0][2] + red[0][3];
  s2 = red[1][0] + red[1][1] + red[1][2] + red[1][3];
  float mu = s * (1.0f / 1024.0f);
  float var = s2 * (1.0f / 1024.0f) - mu * mu;
  float rstd = rsqrtf(var + 1e-5f);
  const float4 wv = ((const float4*)lnw)[t];
  const float4 bv = ((const float4*)lnb)[t];
  const float4 gv = ((const float4*)(mods + (size_t)(gi * 2 + b) * 1024))[t];
  const float4 tv = ((const float4*)(mods + (size_t)(bi * 2 + b) * 1024))[t];
  bf16x4 ov;
  ov[0] = (__bf16)(((xv.x - mu) * rstd * wv.x + bv.x) * (1.0f + gv.x) + tv.x);
  ov[1] = (__bf16)(((xv.y - mu) * rstd * wv.y + bv.y) * (1.0f + gv.y) + tv.y);
  ov[2] = (__bf16)(((xv.z - mu) * rstd * wv.z + bv.z) * (1.0f + gv.z) + tv.z);
  ov[3] = (__bf16)(((xv.w - mu) * rstd * wv.w + bv.w) * (1.0f + gv.w) + tv.w);
  *(bf16x4*)(out + (size_t)row * 1024 + t * 4) = ov;
}

// ---------------- context LN (D=768) ----------------
__global__ __launch_bounds__(256) void ctxln_kernel(const float* __restrict__ X,
                                                    const float* __restrict__ w,
                                                    const float* __restrict__ bias,
                                                    __bf16* __restrict__ out) {
  __shared__ float red[2][4];
  int row = blockIdx.x;  // 0..1023
  int t = threadIdx.x;
  const float* xp = X + (size_t)row * 768;
  float v[3];
  float s = 0.f, s2 = 0.f;
#pragma unroll
  for (int i = 0; i < 3; ++i) {
    v[i] = xp[t + i * 256];
    s += v[i];
    s2 += v[i] * v[i];
  }
  int lane = t & 63, wv_ = t >> 6;
#pragma unroll
  for (int off = 32; off > 0; off >>= 1) {
    s += __shfl_down(s, off);
    s2 += __shfl_down(s2, off);
  }
  if (lane == 0) { red[0][wv_] = s; red[1][wv_] = s2; }
  __syncthreads();
  s  = red[0][0] + red[0][1] + red[0][2] + red[0][3];
  s2 = red[1][0] + red[1][1] + red[1][2] + red[1][3];
  float mu = s * (1.0f / 768.0f);
  float var = s2 * (1.0f / 768.0f) - mu * mu;
  float rstd = rsqrtf(var + 1e-5f);
#pragma unroll
  for (int i = 0; i < 3; ++i) {
    int c = t + i * 256;
    out[(size_t)row * 768 + c] = (__bf16)((v[i] - mu) * rstd * w[c] + bias[c]);
  }
}

// ---------------- rope table ----------------
__global__ __launch_bounds__(256) void rope_tbl_kernel(float2* __restrict__ tbl) {
  int idx = blockIdx.x * 256 + threadIdx.x;  // 1024*32
  int n = idx >> 5, i = idx & 31;
  float inv = expf(-(float)(2 * i) * (1.0f / 64.0f) * 9.210340371976184f);  // ln(10000)
  float ang = (float)n * inv;
  tbl[idx] = make_float2(sinf(ang), cosf(ang));
}

// ---------------- rope + head-layout (+ optional scale) ----------------
__global__ __launch_bounds__(256) void rope_kernel(const float* __restrict__ X, int ldx, int col0,
                                                   const float2* __restrict__ tbl,
                                                   __bf16* __restrict__ out, int Ntok, float scale) {
  int idx = blockIdx.x * 256 + threadIdx.x;  // B*Ntok*16*32
  int i = idx & 31;
  int h = (idx >> 5) & 15;
  int nn = idx >> 9;
  int n = nn % Ntok;
  int b = nn / Ntok;
  const float* xp = X + (size_t)(b * Ntok + n) * ldx + col0 + h * 64 + 2 * i;
  float xe = xp[0], xo = xp[1];
  float2 sc2 = tbl[n * 32 + i];
  float re = (xe * sc2.y - xo * sc2.x) * scale;
  float ro = (xe * sc2.x + xo * sc2.y) * scale;
  __bf16* op = out + ((size_t)(b * 16 + h) * Ntok + n) * 64 + 2 * i;
  op[0] = (__bf16)re;
  op[1] = (__bf16)ro;
}

// ---------------- V transpose ----------------
__global__ __launch_bounds__(256) void vt_kernel(const float* __restrict__ KV, int ld, int col0,
                                                 __bf16* __restrict__ VT, int Ntok) {
  __shared__ float tile[32][33];
  int bh = blockIdx.x;
  int n0 = blockIdx.y * 32, d0 = blockIdx.z * 32;
  int b = bh >> 4, h = bh & 15;
  int tx = threadIdx.x & 31, ty = threadIdx.x >> 5;
#pragma unroll
  for (int i = 0; i < 4; ++i) {
    int n = ty + i * 8;
    tile[n][tx] = KV[(size_t)(b * Ntok + n0 + n) * ld + col0 + h * 64 + d0 + tx];
  }
  __syncthreads();
#pragma unroll
  for (int i = 0; i < 4; ++i) {
    int d = ty + i * 8;
    VT[((size_t)bh * 64 + d0 + d) * Ntok + n0 + tx] = (__bf16)tile[tx][d];
  }
}

// ---------------- pipelined bf16 GEMM, bank-conflict-free LDS ----------------
// LDS[r][chunk c] holds source chunk c ^ ((r>>1)&3)  (chunks = 8 bf16 = 16B; BK=32 -> 4/row).
// Stage pre-swizzles the GLOBAL source column (LDS dest linear, required by global_load_lds);
// frag reads XOR the same value (lane-constant (lr>>1)&3). 8-way -> 2-way (free).
// EPI: 0 fp32 out; 1 fp32 out+bias+res; 2 bf16 gelu(acc+bias); 3 fp32 partial at slice z
template <int BM, int BN, int EPI>
__global__ __launch_bounds__(256) void gemm3(const __bf16* __restrict__ A,
                                             const __bf16* __restrict__ BT,
                                             const float* __restrict__ bias,
                                             const float* __restrict__ res,
                                             void* __restrict__ outv,
                                             int M, int N, int K, int kslices) {
  constexpr int MI = BM / 32, NI = BN / 32;
  __shared__ __bf16 sA[2][BM * 32];
  __shared__ __bf16 sB[2][BN * 32];
  const int t = threadIdx.x;
  const int w = t >> 6, lane = t & 63;
  const int lr = lane & 15, lg = lane >> 4;
  const int fxor = (lr >> 1) & 3;  // frag-read chunk XOR (row>>1)&3 == (lr>>1)&3 since wm,mi*16 even*8
  // XCD-aware bijective block swizzle (all grids are multiples of 8)
  int nwg = gridDim.x * gridDim.y * gridDim.z;
  int flat = blockIdx.x + gridDim.x * (blockIdx.y + gridDim.y * blockIdx.z);
  flat = (flat & 7) * (nwg >> 3) + (flat >> 3);
  const int bm = flat % gridDim.x;
  int rest = flat / gridDim.x;
  const int bn = rest % gridDim.y;
  const int bz = rest / gridDim.y;
  const int wm = (w >> 1) * (BM / 2), wn = (w & 1) * (BN / 2);
  const int kper = K / kslices;
  const int k0 = bz * kper;
  f32x4 acc[MI][NI] = {};

  auto stage = [&](int buf, int kt) {
#pragma unroll
    for (int i = 0; i < BM / 64; ++i) {
      int e8 = i * 256 + t;                  // 16B-chunk index
      int row = e8 >> 2, c = e8 & 3;
      int scol = (c ^ ((row >> 1) & 3)) << 3;
      gload16(A + (size_t)(bm * BM + row) * K + kt + scol, &sA[buf][e8 * 8]);
    }
#pragma unroll
    for (int i = 0; i < BN / 64; ++i) {
      int e8 = i * 256 + t;
      int row = e8 >> 2, c = e8 & 3;
      int scol = (c ^ ((row >> 1) & 3)) << 3;
      gload16(BT + (size_t)(bn * BN + row) * K + kt + scol, &sB[buf][e8 * 8]);
    }
  };

  stage(0, k0);
  __syncthreads();
  int cur = 0;
  for (int kt = k0; kt < k0 + kper; kt += 32) {
    if (kt + 32 < k0 + kper) stage(cur ^ 1, kt + 32);  // prefetch next tile
    bf16x8 af[MI], bfr[NI];
#pragma unroll
    for (int mi = 0; mi < MI; ++mi)
      af[mi] = *(const bf16x8*)(&sA[cur][(wm + mi * 16 + lr) * 32 + ((lg ^ fxor) << 3)]);
#pragma unroll
    for (int ni = 0; ni < NI; ++ni)
      bfr[ni] = *(const bf16x8*)(&sB[cur][(wn + ni * 16 + lr) * 32 + ((lg ^ fxor) << 3)]);
#pragma unroll
    for (int mi = 0; mi < MI; ++mi)
#pragma unroll
      for (int ni = 0; ni < NI; ++ni)
        acc[mi][ni] = __builtin_amdgcn_mfma_f32_16x16x32_bf16(af[mi], bfr[ni], acc[mi][ni], 0, 0, 0);
    __syncthreads();
    cur ^= 1;
  }
#pragma unroll
  for (int mi = 0; mi < MI; ++mi) {
    int row = bm * BM + wm + mi * 16 + lg * 4;
#pragma unroll
    for (int ni = 0; ni < NI; ++ni) {
      int col = bn * BN + wn + ni * 16 + lr;
#pragma unroll
      for (int r = 0; r < 4; ++r) {
        float v = acc[mi][ni][r];
        size_t off = (size_t)(row + r) * N + col;
        if (EPI == 0) {
          ((float*)outv)[off] = v;
        } else if (EPI == 1) {
          ((float*)outv)[off] = v + bias[col] + res[off];
        } else if (EPI == 2) {
          float xg = v + bias[col];
          ((__bf16*)outv)[off] = (__bf16)(0.5f * xg * (1.0f + erff(xg * 0.7071067811865475f)));
        } else {
          ((float*)outv)[(size_t)bz * M * N + off] = v;
        }
      }
    }
  }
}

// ---------------- split-K reduce for ff2 ----------------
__global__ __launch_bounds__(256) void ff2red_kernel(const float* __restrict__ part,
                                                     const float* __restrict__ bias,
                                                     const float* __restrict__ res,
                                                     float* __restrict__ out, int MN, int N) {
  int idx = blockIdx.x * 256 + threadIdx.x;
  float4 p0 = ((const float4*)part)[idx];
  float4 p1 = ((const float4*)(part + MN))[idx];
  float4 rr = ((const float4*)res)[idx];
  int colb = (idx * 4) & (N - 1);
  float4 bb = *(const float4*)(bias + colb);
  float4 o;
  o.x = p0.x + p1.x + bb.x + rr.x;
  o.y = p0.y + p1.y + bb.y + rr.y;
  o.z = p0.z + p1.z + bb.z + rr.z;
  o.w = p0.w + p1.w + bb.w + rr.w;
  ((float4*)out)[idx] = o;
}

// ---------------- attention, split-K flash partials, LDS-staged K/V ----------------
template <int KITERS>
__global__ __launch_bounds__(256) void attn_part_kernel(const __bf16* __restrict__ Qr,
                                                        const __bf16* __restrict__ Kr,
                                                        const __bf16* __restrict__ VT,
                                                        float* __restrict__ pO,
                                                        float* __restrict__ pml,
                                                        int Nq, int Nk) {
  __shared__ __bf16 sK[2][64 * 64];
  __shared__ __bf16 sV[2][64 * 64];
  __shared__ __bf16 Pl[4][16 * 64];
  const int t = threadIdx.x, w = t >> 6, lane = t & 63;
  const int lr = lane & 15, lg = lane >> 4;
  const int lsrc = lane & 48;
  const int swz = (lr & 7) << 3;
  int flat = blockIdx.x + (blockIdx.y << 4) + (blockIdx.z << 9);  // grid 16x32x2
  flat = (flat & 7) * 128 + (flat >> 3);
  const int bh = (flat >> 4) & 31, z = flat >> 9;
  const int q0 = (flat & 15) * 64 + w * 16;
  const int k0 = z * (KITERS * 64);

  auto stage = [&](int buf, int kt) {
#pragma unroll
    for (int i = 0; i < 2; ++i) {
      int e8 = i * 256 + t;                  // 16B-unit index in [0,512)
      int row = e8 >> 3, col8 = e8 & 7;
      int scol = (col8 ^ (row & 7)) << 3;    // pre-swizzled source column
      gload16(Kr + ((size_t)bh * Nk + kt + row) * 64 + scol, &sK[buf][e8 * 8]);
      gload16(VT + ((size_t)bh * 64 + row) * Nk + kt + scol, &sV[buf][e8 * 8]);
    }
  };

  bf16x8 qf[2];
#pragma unroll
  for (int kh = 0; kh < 2; ++kh)
    qf[kh] = *(const bf16x8*)(Qr + ((size_t)bh * Nq + q0 + lr) * 64 + kh * 32 + lg * 8);
  f32x4 accO[4] = {};
  float m = -INFINITY, l = 0.f;

  stage(0, k0);
  __syncthreads();
  int cur = 0;
#pragma unroll
  for (int it = 0; it < KITERS; ++it) {
    if (it + 1 < KITERS) stage(cur ^ 1, k0 + (it + 1) * 64);  // async prefetch
    f32x4 s[4] = {};
#pragma unroll
    for (int nf = 0; nf < 4; ++nf) {
      int r = nf * 16 + lr;
#pragma unroll
      for (int kh = 0; kh < 2; ++kh) {
        bf16x8 kf = *(const bf16x8*)(&sK[cur][r * 64 + (((kh * 4 + lg) ^ (lr & 7)) << 3)]);
        s[nf] = __builtin_amdgcn_mfma_f32_16x16x32_bf16(kf, qf[kh], s[nf], 0, 0, 0);
      }
    }
    float p[16];
#pragma unroll
    for (int j = 0; j < 16; ++j) p[j] = s[j >> 2][j & 3];
    float pm = p[0];
#pragma unroll
    for (int j = 1; j < 16; ++j) pm = fmaxf(pm, p[j]);
    pm = fmaxf(pm, __shfl_xor(pm, 16));
    pm = fmaxf(pm, __shfl_xor(pm, 32));
    if (!__all(pm <= m + 8.f)) {  // defer-max
      float mnew = fmaxf(m, pm);
      float resc = __expf(m - mnew);
      float rq[4];
#pragma unroll
      for (int r = 0; r < 4; ++r) rq[r] = __shfl(resc, lsrc | (lg * 4 + r));
#pragma unroll
      for (int df = 0; df < 4; ++df)
#pragma unroll
        for (int r = 0; r < 4; ++r) accO[df][r] *= rq[r];
      l *= resc;
      m = mnew;
    }
    float rs = 0.f;
#pragma unroll
    for (int j = 0; j < 16; ++j) { p[j] = __expf(p[j] - m); rs += p[j]; }
    rs += __shfl_xor(rs, 16);
    rs += __shfl_xor(rs, 32);
    l += rs;
#pragma unroll
    for (int nf = 0; nf < 4; ++nf)
#pragma unroll
      for (int jj = 0; jj < 2; ++jj) {
        int k = nf * 16 + lg * 4 + 2 * jj;
        bf16x2 pk;
        pk[0] = (__bf16)p[nf * 4 + 2 * jj];
        pk[1] = (__bf16)p[nf * 4 + 2 * jj + 1];
        *(bf16x2*)(&Pl[w][lr * 64 + (k ^ swz)]) = pk;
      }
    bf16x8 pa0 = *(const bf16x8*)(&Pl[w][lr * 64 + ((lg * 8) ^ swz)]);
    bf16x8 pa1 = *(const bf16x8*)(&Pl[w][lr * 64 + ((32 + lg * 8) ^ swz)]);
#pragma unroll
    for (int df = 0; df < 4; ++df) {
      int d = df * 16 + lr;
      bf16x8 vf0 = *(const bf16x8*)(&sV[cur][d * 64 + ((lg ^ (lr & 7)) << 3)]);
      bf16x8 vf1 = *(const bf16x8*)(&sV[cur][d * 64 + (((4 + lg) ^ (lr & 7)) << 3)]);
      accO[df] = __builtin_amdgcn_mfma_f32_16x16x32_bf16(pa0, vf0, accO[df], 0, 0, 0);
      accO[df] = __builtin_amdgcn_mfma_f32_16x16x32_bf16(pa1, vf1, accO[df], 0, 0, 0);
    }
    __syncthreads();
    cur ^= 1;
  }
  const size_t rbase = (size_t)(z * 32 + bh) * Nq + q0;
  if (lg == 0) {
    pml[(rbase + lr) * 2] = m;
    pml[(rbase + lr) * 2 + 1] = l;
  }
#pragma unroll
  for (int r = 0; r < 4; ++r)
#pragma unroll
    for (int df = 0; df < 4; ++df)
      pO[(rbase + lg * 4 + r) * 64 + df * 16 + lr] = accO[df][r];
}

// ---------------- combine 2 flash slices -> O token-major bf16 ----------------
__global__ __launch_bounds__(256) void attn_combine_kernel(const float* __restrict__ pO,
                                                           const float* __restrict__ pml,
                                                           __bf16* __restrict__ O) {
  int idx = blockIdx.x * 256 + threadIdx.x;  // 32768*64 threads
  int r = idx >> 6, dh = idx & 63;
  float m0 = pml[2 * r], l0 = pml[2 * r + 1];
  float m1 = pml[2 * (r + 32768)], l1 = pml[2 * (r + 32768) + 1];
  float O0 = pO[(size_t)r * 64 + dh];
  float O1 = pO[((size_t)r + 32768) * 64 + dh];
  float mm = fmaxf(m0, m1);
  float w0 = __expf(m0 - mm), w1 = __expf(m1 - mm);
  float val = (O0 * w0 + O1 * w1) / (l0 * w0 + l1 * w1);
  int bh = r >> 10, n = r & 1023;
  int b = bh >> 4, h = bh & 15;
  O[(size_t)(b * 1024 + n) * 1024 + h * 64 + dh] = (__bf16)val;
}

extern "C" void kernel_launch(void* const* d_in, const int* in_sizes, int n_in,
                              void* d_out, int out_size, void* d_ws, size_t ws_size,
                              hipStream_t stream) {
  (void)in_sizes; (void)n_in; (void)out_size; (void)ws_size;
  const float* x       = (const float*)d_in[0];
  const float* cond    = (const float*)d_in[1];
  const float* ctx     = (const float*)d_in[2];
  const float* ln1_w   = (const float*)d_in[3];
  const float* ln1_b   = (const float*)d_in[4];
  const float* g1_w    = (const float*)d_in[5];
  const float* g1_b    = (const float*)d_in[6];
  const float* b1_w    = (const float*)d_in[7];
  const float* b1_b    = (const float*)d_in[8];
  const float* ln2_w   = (const float*)d_in[9];
  const float* ln2_b   = (const float*)d_in[10];
  const float* g2_w    = (const float*)d_in[11];
  const float* g2_b    = (const float*)d_in[12];
  const float* b2_w    = (const float*)d_in[13];
  const float* b2_b    = (const float*)d_in[14];
  const float* sa_wq   = (const float*)d_in[15];
  const float* sa_wkv  = (const float*)d_in[16];
  const float* sa_wo   = (const float*)d_in[17];
  const float* sa_bo   = (const float*)d_in[18];
  const float* ca_lnc_w = (const float*)d_in[19];
  const float* ca_lnc_b = (const float*)d_in[20];
  const float* ca_wq   = (const float*)d_in[21];
  const float* ca_wkv  = (const float*)d_in[22];
  const float* ca_wo   = (const float*)d_in[23];
  const float* ca_bo   = (const float*)d_in[24];
  const float* ff_w1   = (const float*)d_in[25];
  const float* ff_b1   = (const float*)d_in[26];
  const float* ff_w2   = (const float*)d_in[27];
  const float* ff_b2   = (const float*)d_in[28];
  float* out = (float*)d_out;

  char* ws = (char*)d_ws;
  size_t o = 0;
  auto alloc = [&](size_t bytes) {
    void* p = ws + o;
    o += (bytes + 255) & ~(size_t)255;
    return p;
  };

  __bf16* wqT   = (__bf16*)alloc(1024ull * 1024 * 2);  // wqT+wkvT contiguous => BT[3072][1024]
  __bf16* wkvT  = (__bf16*)alloc(2048ull * 1024 * 2);
  __bf16* woT   = (__bf16*)alloc(1024ull * 1024 * 2);
  __bf16* cwqT  = (__bf16*)alloc(1024ull * 1024 * 2);
  __bf16* cwkvT = (__bf16*)alloc(2048ull * 768 * 2);
  __bf16* cwoT  = (__bf16*)alloc(1024ull * 1024 * 2);
  __bf16* ff1T  = (__bf16*)alloc(4096ull * 1024 * 2);
  __bf16* ff2T  = (__bf16*)alloc(1024ull * 4096 * 2);
  float*  mods  = (float*)alloc(4ull * 2 * 1024 * 4);
  float2* tbl   = (float2*)alloc(1024ull * 32 * 8);
  __bf16* ain   = (__bf16*)alloc(2048ull * 1024 * 2);
  float*  Qf    = (float*)alloc(2048ull * 1024 * 4);   // Qf+KVf = contiguous 24MB QKV span
  float*  KVf   = (float*)alloc(2048ull * 2048 * 4);
  __bf16* ctxn  = (__bf16*)alloc(1024ull * 768 * 2);
  __bf16* Qr    = (__bf16*)alloc(2048ull * 1024 * 2);
  __bf16* Kr    = (__bf16*)alloc(2048ull * 1024 * 2);
  __bf16* VTb   = (__bf16*)alloc(2048ull * 1024 * 2);
  __bf16* Ob    = (__bf16*)alloc(2048ull * 1024 * 2);
  float*  x1    = (float*)alloc(2048ull * 1024 * 4);
  float*  x2    = (float*)alloc(2048ull * 1024 * 4);
  float*  QKVf  = Qf;            // [2048][3072] fp32 self-attn fused output
  __bf16* hb    = (__bf16*)KVf;  // FFN hidden (2048x4096 bf16)
  float*  pbuf  = (float*)Qr;    // ff2 split-K partials: 2 x 8MB
  float*  mpart = (float*)Qf;    // mod GEMV partials
  float*  pO    = (float*)KVf;   // attn partials (16MB)
  float*  pml   = (float*)Qf;    // attn m/l (512KB)

  // ---- weight prep: one fused launch ----
  WtDesc wd;
  const float* srcs[8] = {sa_wq, sa_wkv, sa_wo, ca_wq, ca_wkv, ca_wo, ff_w1, ff_w2};
  __bf16* dsts[8] = {wqT, wkvT, woT, cwqT, cwkvT, cwoT, ff1T, ff2T};
  int Ks[8] = {1024, 1024, 1024, 1024, 768, 1024, 1024, 4096};
  int Ns[8] = {1024, 2048, 1024, 1024, 2048, 1024, 4096, 1024};
  int cum = 0;
  for (int i = 0; i < 8; ++i) {
    wd.src[i] = srcs[i]; wd.dst[i] = dsts[i]; wd.K[i] = Ks[i]; wd.N[i] = Ns[i];
    wd.tstart[i] = cum;
    cum += (Ks[i] >> 5) * (Ns[i] >> 5);
  }
  wd.tstart[8] = cum;  // 15872
  wt_all_kernel<<<cum, 256, 0, stream>>>(wd);
  rope_tbl_kernel<<<128, 256, 0, stream>>>(tbl);
  mod_part_kernel<<<dim3(4, 2, 32), 256, 0, stream>>>(cond, g1_w, b1_w, g2_w, b2_w, mpart);
  mod_reduce_kernel<<<32, 256, 0, stream>>>(mpart, g1_b, b1_b, g2_b, b2_b, mods);

  // ---- self attention (fused QKV projection: N=3072) ----
  adaln_kernel<<<2048, 256, 0, stream>>>(x, ln1_w, ln1_b, mods, 0, 1, ain);
  gemm3<128, 64, 0><<<dim3(16, 48), 256, 0, stream>>>(ain, wqT, nullptr, nullptr, QKVf, 2048, 3072, 1024, 1);
  rope_kernel<<<4096, 256, 0, stream>>>(QKVf, 3072, 0, tbl, Qr, 1024, 0.125f);
  rope_kernel<<<4096, 256, 0, stream>>>(QKVf, 3072, 1024, tbl, Kr, 1024, 1.0f);
  vt_kernel<<<dim3(32, 32, 2), 256, 0, stream>>>(QKVf, 3072, 2048, VTb, 1024);
  attn_part_kernel<8><<<dim3(16, 32, 2), 256, 0, stream>>>(Qr, Kr, VTb, pO, pml, 1024, 1024);
  attn_combine_kernel<<<8192, 256, 0, stream>>>(pO, pml, Ob);
  gemm3<128, 64, 1><<<dim3(16, 16), 256, 0, stream>>>(Ob, woT, sa_bo, x, x1, 2048, 1024, 1024, 1);

  // ---- cross attention ----
  adaln_kernel<<<2048, 256, 0, stream>>>(x1, ln1_w, ln1_b, mods, 0, 1, ain);
  ctxln_kernel<<<1024, 256, 0, stream>>>(ctx, ca_lnc_w, ca_lnc_b, ctxn);
  gemm3<128, 64, 0><<<dim3(16, 16), 256, 0, stream>>>(ain, cwqT, nullptr, nullptr, Qf, 2048, 1024, 1024, 1);
  gemm3<64, 128, 0><<<dim3(16, 16), 256, 0, stream>>>(ctxn, cwkvT, nullptr, nullptr, KVf, 1024, 2048, 768, 1);
  rope_kernel<<<4096, 256, 0, stream>>>(Qf, 1024, 0, tbl, Qr, 1024, 0.125f);
  rope_kernel<<<2048, 256, 0, stream>>>(KVf, 2048, 0, tbl, Kr, 512, 1.0f);
  vt_kernel<<<dim3(32, 16, 2), 256, 0, stream>>>(KVf, 2048, 1024, VTb, 512);
  attn_part_kernel<4><<<dim3(16, 32, 2), 256, 0, stream>>>(Qr, Kr, VTb, pO, pml, 1024, 512);
  attn_combine_kernel<<<8192, 256, 0, stream>>>(pO, pml, Ob);
  gemm3<128, 64, 1><<<dim3(16, 16), 256, 0, stream>>>(Ob, cwoT, ca_bo, x1, x2, 2048, 1024, 1024, 1);

  // ---- FFN ----
  adaln_kernel<<<2048, 256, 0, stream>>>(x2, ln2_w, ln2_b, mods, 2, 3, ain);
  gemm3<128, 128, 2><<<dim3(16, 32), 256, 0, stream>>>(ain, ff1T, ff_b1, nullptr, hb, 2048, 4096, 1024, 1);
  gemm3<128, 64, 3><<<dim3(16, 16, 2), 256, 0, stream>>>(hb, ff2T, nullptr, nullptr, pbuf, 2048, 1024, 4096, 2);
  ff2red_kernel<<<2048, 256, 0, stream>>>(pbuf, ff_b2, x2, out, 2048 * 1024, 1024);
}

// Round 8
// 280.634 us; speedup vs baseline: 1.7998x; 1.0164x over previous
//
#include <hip/hip_runtime.h>
#include <hip/hip_bf16.h>
#include <math.h>

// B=2 N=1024 M=512 D=1024 H=16 DH=64 MID=1024 DC=768 MULT=4

typedef float f32x4 __attribute__((ext_vector_type(4)));
typedef __bf16 bf16x8 __attribute__((ext_vector_type(8)));
typedef __bf16 bf16x4 __attribute__((ext_vector_type(4)));
typedef __bf16 bf16x2 __attribute__((ext_vector_type(2)));

#define DEVI __device__ __forceinline__

DEVI void gload16(const void* g, void* l) {
  __builtin_amdgcn_global_load_lds((const __attribute__((address_space(1))) void*)g,
                                   (__attribute__((address_space(3))) void*)l, 16, 0, 0);
}

// ---------------- fused weight transpose: 8 matrices, one launch ----------------
struct WtDesc {
  const float* src[8];
  __bf16* dst[8];
  int K[8], N[8];
  int tstart[9];  // cumulative 32x32-tile offsets
};

__global__ __launch_bounds__(256) void wt_all_kernel(WtDesc d) {
  __shared__ float tile[32][33];
  int blk = blockIdx.x;
  int e = 0;
#pragma unroll
  for (int i = 0; i < 7; ++i) e += (blk >= d.tstart[i + 1]) ? 1 : 0;
  int li = blk - d.tstart[e];
  const float* W = d.src[e];
  __bf16* WT = d.dst[e];
  int K = d.K[e], N = d.N[e];
  int ntx = N >> 5;
  int n0 = (li % ntx) * 32, k0 = (li / ntx) * 32;
  int tx = threadIdx.x & 31, ty = threadIdx.x >> 5;
#pragma unroll
  for (int i = 0; i < 4; ++i) {
    int k = ty + i * 8;
    tile[k][tx] = W[(size_t)(k0 + k) * N + n0 + tx];
  }
  __syncthreads();
#pragma unroll
  for (int i = 0; i < 4; ++i) {
    int n = ty + i * 8;
    WT[(size_t)(n0 + n) * K + k0 + tx] = (__bf16)tile[tx][n];
  }
}

// ---------------- modulation GEMV, k-split partials ----------------
__global__ __launch_bounds__(256) void mod_part_kernel(
    const float* __restrict__ cond,
    const float* __restrict__ g1w, const float* __restrict__ b1w,
    const float* __restrict__ g2w, const float* __restrict__ b2w,
    float* __restrict__ part) {
  __shared__ float sc[128];
  int dchunk = blockIdx.x, b = blockIdx.y;
  int mat = blockIdx.z >> 3, ks = blockIdx.z & 7;
  const float* W = (mat == 0) ? g1w : (mat == 1) ? b1w : (mat == 2) ? g2w : b2w;
  if (threadIdx.x < 128) sc[threadIdx.x] = cond[b * 1024 + ks * 128 + threadIdx.x];
  __syncthreads();
  int d = dchunk * 256 + threadIdx.x;
  const float* Wp = W + (size_t)(ks * 128) * 1024 + d;
  float acc = 0.f;
#pragma unroll 8
  for (int k = 0; k < 128; ++k) acc += sc[k] * Wp[(size_t)k * 1024];
  part[(size_t)(blockIdx.z * 2 + b) * 1024 + d] = acc;
}

__global__ __launch_bounds__(256) void mod_reduce_kernel(
    const float* __restrict__ part,
    const float* __restrict__ g1b, const float* __restrict__ b1b,
    const float* __restrict__ g2b, const float* __restrict__ b2b,
    float* __restrict__ mods) {
  int idx = blockIdx.x * 256 + threadIdx.x;  // 0..8191
  int mat = idx >> 11, b = (idx >> 10) & 1, d = idx & 1023;
  float s = 0.f;
#pragma unroll
  for (int ks = 0; ks < 8; ++ks) s += part[(size_t)((mat * 8 + ks) * 2 + b) * 1024 + d];
  const float* Bv = (mat == 0) ? g1b : (mat == 1) ? b1b : (mat == 2) ? g2b : b2b;
  mods[(size_t)(mat * 2 + b) * 1024 + d] = s + Bv[d];
}

// ---------------- adaLN: out_bf16 = LN(x)*(1+g)+bt ----------------
__global__ __launch_bounds__(256) void adaln_kernel(const float* __restrict__ X,
                                                    const float* __restrict__ lnw,
                                                    const float* __restrict__ lnb,
                                                    const float* __restrict__ mods,
                                                    int gi, int bi,
                                                    __bf16* __restrict__ out) {
  __shared__ float red[2][4];
  int row = blockIdx.x;  // 0..2047
  int b = row >> 10;
  int t = threadIdx.x;
  const float4 xv = ((const float4*)(X + (size_t)row * 1024))[t];
  float s  = xv.x + xv.y + xv.z + xv.w;
  float s2 = xv.x * xv.x + xv.y * xv.y + xv.z * xv.z + xv.w * xv.w;
  int lane = t & 63, w = t >> 6;
#pragma unroll
  for (int off = 32; off > 0; off >>= 1) {
    s += __shfl_down(s, off);
    s2 += __shfl_down(s2, off);
  }
  if (lane == 0) { red[0][w] = s; red[1][w] = s2; }
  __syncthreads();
  s  = red[0][0] + red[0][1] + red[0][2] + red[0][3];
  s2 = red[1][0] + red[1][1] + red[1][2] + red[1][3];
  float mu = s * (1.0f / 1024.0f);
  float var = s2 * (1.0f / 1024.0f) - mu * mu;
  float rstd = rsqrtf(var + 1e-5f);
  const float4 wv = ((const float4*)lnw)[t];
  const float4 bv = ((const float4*)lnb)[t];
  const float4 gv = ((const float4*)(mods + (size_t)(gi * 2 + b) * 1024))[t];
  const float4 tv = ((const float4*)(mods + (size_t)(bi * 2 + b) * 1024))[t];
  bf16x4 ov;
  ov[0] = (__bf16)(((xv.x - mu) * rstd * wv.x + bv.x) * (1.0f + gv.x) + tv.x);
  ov[1] = (__bf16)(((xv.y - mu) * rstd * wv.y + bv.y) * (1.0f + gv.y) + tv.y);
  ov[2] = (__bf16)(((xv.z - mu) * rstd * wv.z + bv.z) * (1.0f + gv.z) + tv.z);
  ov[3] = (__bf16)(((xv.w - mu) * rstd * wv.w + bv.w) * (1.0f + gv.w) + tv.w);
  *(bf16x4*)(out + (size_t)row * 1024 + t * 4) = ov;
}

// ---------------- context LN (D=768) ----------------
__global__ __launch_bounds__(256) void ctxln_kernel(const float* __restrict__ X,
                                                    const float* __restrict__ w,
                                                    const float* __restrict__ bias,
                                                    __bf16* __restrict__ out) {
  __shared__ float red[2][4];
  int row = blockIdx.x;  // 0..1023
  int t = threadIdx.x;
  const float* xp = X + (size_t)row * 768;
  float v[3];
  float s = 0.f, s2 = 0.f;
#pragma unroll
  for (int i = 0; i < 3; ++i) {
    v[i] = xp[t + i * 256];
    s += v[i];
    s2 += v[i] * v[i];
  }
  int lane = t & 63, wv_ = t >> 6;
#pragma unroll
  for (int off = 32; off > 0; off >>= 1) {
    s += __shfl_down(s, off);
    s2 += __shfl_down(s2, off);
  }
  if (lane == 0) { red[0][wv_] = s; red[1][wv_] = s2; }
  __syncthreads();
  s  = red[0][0] + red[0][1] + red[0][2] + red[0][3];
  s2 = red[1][0] + red[1][1] + red[1][2] + red[1][3];
  float mu = s * (1.0f / 768.0f);
  float var = s2 * (1.0f / 768.0f) - mu * mu;
  float rstd = rsqrtf(var + 1e-5f);
#pragma unroll
  for (int i = 0; i < 3; ++i) {
    int c = t + i * 256;
    out[(size_t)row * 768 + c] = (__bf16)((v[i] - mu) * rstd * w[c] + bias[c]);
  }
}

// ---------------- rope table ----------------
__global__ __launch_bounds__(256) void rope_tbl_kernel(float2* __restrict__ tbl) {
  int idx = blockIdx.x * 256 + threadIdx.x;  // 1024*32
  int n = idx >> 5, i = idx & 31;
  float inv = expf(-(float)(2 * i) * (1.0f / 64.0f) * 9.210340371976184f);  // ln(10000)
  float ang = (float)n * inv;
  tbl[idx] = make_float2(sinf(ang), cosf(ang));
}

// ---------------- rope + head-layout (+ optional scale) ----------------
__global__ __launch_bounds__(256) void rope_kernel(const float* __restrict__ X, int ldx, int col0,
                                                   const float2* __restrict__ tbl,
                                                   __bf16* __restrict__ out, int Ntok, float scale) {
  int idx = blockIdx.x * 256 + threadIdx.x;  // B*Ntok*16*32
  int i = idx & 31;
  int h = (idx >> 5) & 15;
  int nn = idx >> 9;
  int n = nn % Ntok;
  int b = nn / Ntok;
  const float* xp = X + (size_t)(b * Ntok + n) * ldx + col0 + h * 64 + 2 * i;
  float xe = xp[0], xo = xp[1];
  float2 sc2 = tbl[n * 32 + i];
  float re = (xe * sc2.y - xo * sc2.x) * scale;
  float ro = (xe * sc2.x + xo * sc2.y) * scale;
  __bf16* op = out + ((size_t)(b * 16 + h) * Ntok + n) * 64 + 2 * i;
  op[0] = (__bf16)re;
  op[1] = (__bf16)ro;
}

// ---------------- V transpose ----------------
__global__ __launch_bounds__(256) void vt_kernel(const float* __restrict__ KV, int ld, int col0,
                                                 __bf16* __restrict__ VT, int Ntok) {
  __shared__ float tile[32][33];
  int bh = blockIdx.x;
  int n0 = blockIdx.y * 32, d0 = blockIdx.z * 32;
  int b = bh >> 4, h = bh & 15;
  int tx = threadIdx.x & 31, ty = threadIdx.x >> 5;
#pragma unroll
  for (int i = 0; i < 4; ++i) {
    int n = ty + i * 8;
    tile[n][tx] = KV[(size_t)(b * Ntok + n0 + n) * ld + col0 + h * 64 + d0 + tx];
  }
  __syncthreads();
#pragma unroll
  for (int i = 0; i < 4; ++i) {
    int d = ty + i * 8;
    VT[((size_t)bh * 64 + d0 + d) * Ntok + n0 + tx] = (__bf16)tile[tx][d];
  }
}

// ---------------- pipelined bf16 GEMM, depth-DEPTH counted-vmcnt pipeline ----------------
// LDS swizzle: LDS[r][c] holds source chunk c ^ ((r>>1)&3); frag reads XOR back (2-way, free).
// K-loop: NBUF=DEPTH+1 buffers; per step: s_waitcnt vmcnt((DEPTH-1)*LPT) waits only for
// this step's buffer; raw s_barrier (no drain); stage it+DEPTH issued after barrier (WAR-safe:
// its buffer's readers all passed the barrier). Tail drains once with vmcnt(0).
// EPI: 0 fp32 out; 1 fp32 out+bias+res; 2 bf16 gelu(acc+bias); 3 fp32 partial at slice z
template <int BM, int BN, int EPI, int DEPTH>
__global__ __launch_bounds__(256) void gemm3(const __bf16* __restrict__ A,
                                             const __bf16* __restrict__ BT,
                                             const float* __restrict__ bias,
                                             const float* __restrict__ res,
                                             void* __restrict__ outv,
                                             int M, int N, int K, int kslices) {
  constexpr int MI = BM / 32, NI = BN / 32;
  constexpr int NBUF = DEPTH + 1;
  constexpr int LPT = BM / 64 + BN / 64;  // gloads per thread per stage
  __shared__ __bf16 sA[NBUF][BM * 32];
  __shared__ __bf16 sB[NBUF][BN * 32];
  const int t = threadIdx.x;
  const int w = t >> 6, lane = t & 63;
  const int lr = lane & 15, lg = lane >> 4;
  const int fxor = (lr >> 1) & 3;
  // XCD-aware bijective block swizzle (all grids are multiples of 8)
  int nwg = gridDim.x * gridDim.y * gridDim.z;
  int flat = blockIdx.x + gridDim.x * (blockIdx.y + gridDim.y * blockIdx.z);
  flat = (flat & 7) * (nwg >> 3) + (flat >> 3);
  const int bm = flat % gridDim.x;
  int rest = flat / gridDim.x;
  const int bn = rest % gridDim.y;
  const int bz = rest / gridDim.y;
  const int wm = (w >> 1) * (BM / 2), wn = (w & 1) * (BN / 2);
  const int kper = K / kslices;
  const int k0 = bz * kper;
  const int nsteps = kper / 32;
  f32x4 acc[MI][NI] = {};

  auto stage = [&](int buf, int kt) {
#pragma unroll
    for (int i = 0; i < BM / 64; ++i) {
      int e8 = i * 256 + t;
      int row = e8 >> 2, c = e8 & 3;
      int scol = (c ^ ((row >> 1) & 3)) << 3;
      gload16(A + (size_t)(bm * BM + row) * K + kt + scol, &sA[buf][e8 * 8]);
    }
#pragma unroll
    for (int i = 0; i < BN / 64; ++i) {
      int e8 = i * 256 + t;
      int row = e8 >> 2, c = e8 & 3;
      int scol = (c ^ ((row >> 1) & 3)) << 3;
      gload16(BT + (size_t)(bn * BN + row) * K + kt + scol, &sB[buf][e8 * 8]);
    }
  };

  auto compute = [&](int buf) {
    bf16x8 af[MI], bfr[NI];
#pragma unroll
    for (int mi = 0; mi < MI; ++mi)
      af[mi] = *(const bf16x8*)(&sA[buf][(wm + mi * 16 + lr) * 32 + ((lg ^ fxor) << 3)]);
#pragma unroll
    for (int ni = 0; ni < NI; ++ni)
      bfr[ni] = *(const bf16x8*)(&sB[buf][(wn + ni * 16 + lr) * 32 + ((lg ^ fxor) << 3)]);
#pragma unroll
    for (int mi = 0; mi < MI; ++mi)
#pragma unroll
      for (int ni = 0; ni < NI; ++ni)
        acc[mi][ni] = __builtin_amdgcn_mfma_f32_16x16x32_bf16(af[mi], bfr[ni], acc[mi][ni], 0, 0, 0);
  };

#pragma unroll
  for (int i = 0; i < DEPTH; ++i) stage(i, k0 + i * 32);  // K >= DEPTH*32 always here

  int it = 0;
  for (; it < nsteps - (DEPTH - 1); ++it) {
    asm volatile("s_waitcnt vmcnt(%0)" :: "n"((DEPTH - 1) * LPT) : "memory");
    __builtin_amdgcn_s_barrier();
    __builtin_amdgcn_sched_barrier(0);
    if (it + DEPTH < nsteps) stage((it + DEPTH) % NBUF, k0 + (it + DEPTH) * 32);
    compute(it % NBUF);
  }
  asm volatile("s_waitcnt vmcnt(0)" ::: "memory");
  __builtin_amdgcn_s_barrier();
  __builtin_amdgcn_sched_barrier(0);
  for (; it < nsteps; ++it) compute(it % NBUF);

#pragma unroll
  for (int mi = 0; mi < MI; ++mi) {
    int row = bm * BM + wm + mi * 16 + lg * 4;
#pragma unroll
    for (int ni = 0; ni < NI; ++ni) {
      int col = bn * BN + wn + ni * 16 + lr;
#pragma unroll
      for (int r = 0; r < 4; ++r) {
        float v = acc[mi][ni][r];
        size_t off = (size_t)(row + r) * N + col;
        if (EPI == 0) {
          ((float*)outv)[off] = v;
        } else if (EPI == 1) {
          ((float*)outv)[off] = v + bias[col] + res[off];
        } else if (EPI == 2) {
          float xg = v + bias[col];
          ((__bf16*)outv)[off] = (__bf16)(0.5f * xg * (1.0f + erff(xg * 0.7071067811865475f)));
        } else {
          ((float*)outv)[(size_t)bz * M * N + off] = v;
        }
      }
    }
  }
}

// ---------------- split-K reduce for ff2 ----------------
__global__ __launch_bounds__(256) void ff2red_kernel(const float* __restrict__ part,
                                                     const float* __restrict__ bias,
                                                     const float* __restrict__ res,
                                                     float* __restrict__ out, int MN, int N) {
  int idx = blockIdx.x * 256 + threadIdx.x;
  float4 p0 = ((const float4*)part)[idx];
  float4 p1 = ((const float4*)(part + MN))[idx];
  float4 rr = ((const float4*)res)[idx];
  int colb = (idx * 4) & (N - 1);
  float4 bb = *(const float4*)(bias + colb);
  float4 o;
  o.x = p0.x + p1.x + bb.x + rr.x;
  o.y = p0.y + p1.y + bb.y + rr.y;
  o.z = p0.z + p1.z + bb.z + rr.z;
  o.w = p0.w + p1.w + bb.w + rr.w;
  ((float4*)out)[idx] = o;
}

// ---------------- attention, split-K flash partials, LDS-staged K/V ----------------
template <int KITERS>
__global__ __launch_bounds__(256) void attn_part_kernel(const __bf16* __restrict__ Qr,
                                                        const __bf16* __restrict__ Kr,
                                                        const __bf16* __restrict__ VT,
                                                        float* __restrict__ pO,
                                                        float* __restrict__ pml,
                                                        int Nq, int Nk) {
  __shared__ __bf16 sK[2][64 * 64];
  __shared__ __bf16 sV[2][64 * 64];
  __shared__ __bf16 Pl[4][16 * 64];
  const int t = threadIdx.x, w = t >> 6, lane = t & 63;
  const int lr = lane & 15, lg = lane >> 4;
  const int lsrc = lane & 48;
  const int swz = (lr & 7) << 3;
  int flat = blockIdx.x + (blockIdx.y << 4) + (blockIdx.z << 9);  // grid 16x32x2
  flat = (flat & 7) * 128 + (flat >> 3);
  const int bh = (flat >> 4) & 31, z = flat >> 9;
  const int q0 = (flat & 15) * 64 + w * 16;
  const int k0 = z * (KITERS * 64);

  auto stage = [&](int buf, int kt) {
#pragma unroll
    for (int i = 0; i < 2; ++i) {
      int e8 = i * 256 + t;                  // 16B-unit index in [0,512)
      int row = e8 >> 3, col8 = e8 & 7;
      int scol = (col8 ^ (row & 7)) << 3;    // pre-swizzled source column
      gload16(Kr + ((size_t)bh * Nk + kt + row) * 64 + scol, &sK[buf][e8 * 8]);
      gload16(VT + ((size_t)bh * 64 + row) * Nk + kt + scol, &sV[buf][e8 * 8]);
    }
  };

  bf16x8 qf[2];
#pragma unroll
  for (int kh = 0; kh < 2; ++kh)
    qf[kh] = *(const bf16x8*)(Qr + ((size_t)bh * Nq + q0 + lr) * 64 + kh * 32 + lg * 8);
  f32x4 accO[4] = {};
  float m = -INFINITY, l = 0.f;

  stage(0, k0);
  __syncthreads();
  int cur = 0;
#pragma unroll
  for (int it = 0; it < KITERS; ++it) {
    if (it + 1 < KITERS) stage(cur ^ 1, k0 + (it + 1) * 64);  // async prefetch
    f32x4 s[4] = {};
#pragma unroll
    for (int nf = 0; nf < 4; ++nf) {
      int r = nf * 16 + lr;
#pragma unroll
      for (int kh = 0; kh < 2; ++kh) {
        bf16x8 kf = *(const bf16x8*)(&sK[cur][r * 64 + (((kh * 4 + lg) ^ (lr & 7)) << 3)]);
        s[nf] = __builtin_amdgcn_mfma_f32_16x16x32_bf16(kf, qf[kh], s[nf], 0, 0, 0);
      }
    }
    float p[16];
#pragma unroll
    for (int j = 0; j < 16; ++j) p[j] = s[j >> 2][j & 3];
    float pm = p[0];
#pragma unroll
    for (int j = 1; j < 16; ++j) pm = fmaxf(pm, p[j]);
    pm = fmaxf(pm, __shfl_xor(pm, 16));
    pm = fmaxf(pm, __shfl_xor(pm, 32));
    if (!__all(pm <= m + 8.f)) {  // defer-max
      float mnew = fmaxf(m, pm);
      float resc = __expf(m - mnew);
      float rq[4];
#pragma unroll
      for (int r = 0; r < 4; ++r) rq[r] = __shfl(resc, lsrc | (lg * 4 + r));
#pragma unroll
      for (int df = 0; df < 4; ++df)
#pragma unroll
        for (int r = 0; r < 4; ++r) accO[df][r] *= rq[r];
      l *= resc;
      m = mnew;
    }
    float rs = 0.f;
#pragma unroll
    for (int j = 0; j < 16; ++j) { p[j] = __expf(p[j] - m); rs += p[j]; }
    rs += __shfl_xor(rs, 16);
    rs += __shfl_xor(rs, 32);
    l += rs;
#pragma unroll
    for (int nf = 0; nf < 4; ++nf)
#pragma unroll
      for (int jj = 0; jj < 2; ++jj) {
        int k = nf * 16 + lg * 4 + 2 * jj;
        bf16x2 pk;
        pk[0] = (__bf16)p[nf * 4 + 2 * jj];
        pk[1] = (__bf16)p[nf * 4 + 2 * jj + 1];
        *(bf16x2*)(&Pl[w][lr * 64 + (k ^ swz)]) = pk;
      }
    bf16x8 pa0 = *(const bf16x8*)(&Pl[w][lr * 64 + ((lg * 8) ^ swz)]);
    bf16x8 pa1 = *(const bf16x8*)(&Pl[w][lr * 64 + ((32 + lg * 8) ^ swz)]);
#pragma unroll
    for (int df = 0; df < 4; ++df) {
      int d = df * 16 + lr;
      bf16x8 vf0 = *(const bf16x8*)(&sV[cur][d * 64 + ((lg ^ (lr & 7)) << 3)]);
      bf16x8 vf1 = *(const bf16x8*)(&sV[cur][d * 64 + (((4 + lg) ^ (lr & 7)) << 3)]);
      accO[df] = __builtin_amdgcn_mfma_f32_16x16x32_bf16(pa0, vf0, accO[df], 0, 0, 0);
      accO[df] = __builtin_amdgcn_mfma_f32_16x16x32_bf16(pa1, vf1, accO[df], 0, 0, 0);
    }
    __syncthreads();
    cur ^= 1;
  }
  const size_t rbase = (size_t)(z * 32 + bh) * Nq + q0;
  if (lg == 0) {
    pml[(rbase + lr) * 2] = m;
    pml[(rbase + lr) * 2 + 1] = l;
  }
#pragma unroll
  for (int r = 0; r < 4; ++r)
#pragma unroll
    for (int df = 0; df < 4; ++df)
      pO[(rbase + lg * 4 + r) * 64 + df * 16 + lr] = accO[df][r];
}

// ---------------- combine 2 flash slices -> O token-major bf16 ----------------
__global__ __launch_bounds__(256) void attn_combine_kernel(const float* __restrict__ pO,
                                                           const float* __restrict__ pml,
                                                           __bf16* __restrict__ O) {
  int idx = blockIdx.x * 256 + threadIdx.x;  // 32768*64 threads
  int r = idx >> 6, dh = idx & 63;
  float m0 = pml[2 * r], l0 = pml[2 * r + 1];
  float m1 = pml[2 * (r + 32768)], l1 = pml[2 * (r + 32768) + 1];
  float O0 = pO[(size_t)r * 64 + dh];
  float O1 = pO[((size_t)r + 32768) * 64 + dh];
  float mm = fmaxf(m0, m1);
  float w0 = __expf(m0 - mm), w1 = __expf(m1 - mm);
  float val = (O0 * w0 + O1 * w1) / (l0 * w0 + l1 * w1);
  int bh = r >> 10, n = r & 1023;
  int b = bh >> 4, h = bh & 15;
  O[(size_t)(b * 1024 + n) * 1024 + h * 64 + dh] = (__bf16)val;
}

extern "C" void kernel_launch(void* const* d_in, const int* in_sizes, int n_in,
                              void* d_out, int out_size, void* d_ws, size_t ws_size,
                              hipStream_t stream) {
  (void)in_sizes; (void)n_in; (void)out_size; (void)ws_size;
  const float* x       = (const float*)d_in[0];
  const float* cond    = (const float*)d_in[1];
  const float* ctx     = (const float*)d_in[2];
  const float* ln1_w   = (const float*)d_in[3];
  const float* ln1_b   = (const float*)d_in[4];
  const float* g1_w    = (const float*)d_in[5];
  const float* g1_b    = (const float*)d_in[6];
  const float* b1_w    = (const float*)d_in[7];
  const float* b1_b    = (const float*)d_in[8];
  const float* ln2_w   = (const float*)d_in[9];
  const float* ln2_b   = (const float*)d_in[10];
  const float* g2_w    = (const float*)d_in[11];
  const float* g2_b    = (const float*)d_in[12];
  const float* b2_w    = (const float*)d_in[13];
  const float* b2_b    = (const float*)d_in[14];
  const float* sa_wq   = (const float*)d_in[15];
  const float* sa_wkv  = (const float*)d_in[16];
  const float* sa_wo   = (const float*)d_in[17];
  const float* sa_bo   = (const float*)d_in[18];
  const float* ca_lnc_w = (const float*)d_in[19];
  const float* ca_lnc_b = (const float*)d_in[20];
  const float* ca_wq   = (const float*)d_in[21];
  const float* ca_wkv  = (const float*)d_in[22];
  const float* ca_wo   = (const float*)d_in[23];
  const float* ca_bo   = (const float*)d_in[24];
  const float* ff_w1   = (const float*)d_in[25];
  const float* ff_b1   = (const float*)d_in[26];
  const float* ff_w2   = (const float*)d_in[27];
  const float* ff_b2   = (const float*)d_in[28];
  float* out = (float*)d_out;

  char* ws = (char*)d_ws;
  size_t o = 0;
  auto alloc = [&](size_t bytes) {
    void* p = ws + o;
    o += (bytes + 255) & ~(size_t)255;
    return p;
  };

  __bf16* wqT   = (__bf16*)alloc(1024ull * 1024 * 2);  // wqT+wkvT contiguous => BT[3072][1024]
  __bf16* wkvT  = (__bf16*)alloc(2048ull * 1024 * 2);
  __bf16* woT   = (__bf16*)alloc(1024ull * 1024 * 2);
  __bf16* cwqT  = (__bf16*)alloc(1024ull * 1024 * 2);
  __bf16* cwkvT = (__bf16*)alloc(2048ull * 768 * 2);
  __bf16* cwoT  = (__bf16*)alloc(1024ull * 1024 * 2);
  __bf16* ff1T  = (__bf16*)alloc(4096ull * 1024 * 2);
  __bf16* ff2T  = (__bf16*)alloc(1024ull * 4096 * 2);
  float*  mods  = (float*)alloc(4ull * 2 * 1024 * 4);
  float2* tbl   = (float2*)alloc(1024ull * 32 * 8);
  __bf16* ain   = (__bf16*)alloc(2048ull * 1024 * 2);
  float*  Qf    = (float*)alloc(2048ull * 1024 * 4);   // Qf+KVf = contiguous 24MB QKV span
  float*  KVf   = (float*)alloc(2048ull * 2048 * 4);
  __bf16* ctxn  = (__bf16*)alloc(1024ull * 768 * 2);
  __bf16* Qr    = (__bf16*)alloc(2048ull * 1024 * 2);
  __bf16* Kr    = (__bf16*)alloc(2048ull * 1024 * 2);
  __bf16* VTb   = (__bf16*)alloc(2048ull * 1024 * 2);
  __bf16* Ob    = (__bf16*)alloc(2048ull * 1024 * 2);
  float*  x1    = (float*)alloc(2048ull * 1024 * 4);
  float*  x2    = (float*)alloc(2048ull * 1024 * 4);
  float*  QKVf  = Qf;            // [2048][3072] fp32 self-attn fused output
  __bf16* hb    = (__bf16*)KVf;  // FFN hidden (2048x4096 bf16)
  float*  pbuf  = (float*)Qr;    // ff2 split-K partials: 2 x 8MB
  float*  mpart = (float*)Qf;    // mod GEMV partials
  float*  pO    = (float*)KVf;   // attn partials (16MB)
  float*  pml   = (float*)Qf;    // attn m/l (512KB)

  // ---- weight prep: one fused launch ----
  WtDesc wd;
  const float* srcs[8] = {sa_wq, sa_wkv, sa_wo, ca_wq, ca_wkv, ca_wo, ff_w1, ff_w2};
  __bf16* dsts[8] = {wqT, wkvT, woT, cwqT, cwkvT, cwoT, ff1T, ff2T};
  int Ks[8] = {1024, 1024, 1024, 1024, 768, 1024, 1024, 4096};
  int Ns[8] = {1024, 2048, 1024, 1024, 2048, 1024, 4096, 1024};
  int cum = 0;
  for (int i = 0; i < 8; ++i) {
    wd.src[i] = srcs[i]; wd.dst[i] = dsts[i]; wd.K[i] = Ks[i]; wd.N[i] = Ns[i];
    wd.tstart[i] = cum;
    cum += (Ks[i] >> 5) * (Ns[i] >> 5);
  }
  wd.tstart[8] = cum;  // 15872
  wt_all_kernel<<<cum, 256, 0, stream>>>(wd);
  rope_tbl_kernel<<<128, 256, 0, stream>>>(tbl);
  mod_part_kernel<<<dim3(4, 2, 32), 256, 0, stream>>>(cond, g1_w, b1_w, g2_w, b2_w, mpart);
  mod_reduce_kernel<<<32, 256, 0, stream>>>(mpart, g1_b, b1_b, g2_b, b2_b, mods);

  // ---- self attention (fused QKV projection: N=3072) ----
  adaln_kernel<<<2048, 256, 0, stream>>>(x, ln1_w, ln1_b, mods, 0, 1, ain);
  gemm3<128, 64, 0, 3><<<dim3(16, 48), 256, 0, stream>>>(ain, wqT, nullptr, nullptr, QKVf, 2048, 3072, 1024, 1);
  rope_kernel<<<4096, 256, 0, stream>>>(QKVf, 3072, 0, tbl, Qr, 1024, 0.125f);
  rope_kernel<<<4096, 256, 0, stream>>>(QKVf, 3072, 1024, tbl, Kr, 1024, 1.0f);
  vt_kernel<<<dim3(32, 32, 2), 256, 0, stream>>>(QKVf, 3072, 2048, VTb, 1024);
  attn_part_kernel<8><<<dim3(16, 32, 2), 256, 0, stream>>>(Qr, Kr, VTb, pO, pml, 1024, 1024);
  attn_combine_kernel<<<8192, 256, 0, stream>>>(pO, pml, Ob);
  gemm3<128, 64, 1, 3><<<dim3(16, 16), 256, 0, stream>>>(Ob, woT, sa_bo, x, x1, 2048, 1024, 1024, 1);

  // ---- cross attention ----
  adaln_kernel<<<2048, 256, 0, stream>>>(x1, ln1_w, ln1_b, mods, 0, 1, ain);
  ctxln_kernel<<<1024, 256, 0, stream>>>(ctx, ca_lnc_w, ca_lnc_b, ctxn);
  gemm3<128, 64, 0, 3><<<dim3(16, 16), 256, 0, stream>>>(ain, cwqT, nullptr, nullptr, Qf, 2048, 1024, 1024, 1);
  gemm3<128, 64, 0, 3><<<dim3(8, 32), 256, 0, stream>>>(ctxn, cwkvT, nullptr, nullptr, KVf, 1024, 2048, 768, 1);
  rope_kernel<<<4096, 256, 0, stream>>>(Qf, 1024, 0, tbl, Qr, 1024, 0.125f);
  rope_kernel<<<2048, 256, 0, stream>>>(KVf, 2048, 0, tbl, Kr, 512, 1.0f);
  vt_kernel<<<dim3(32, 16, 2), 256, 0, stream>>>(KVf, 2048, 1024, VTb, 512);
  attn_part_kernel<4><<<dim3(16, 32, 2), 256, 0, stream>>>(Qr, Kr, VTb, pO, pml, 1024, 512);
  attn_combine_kernel<<<8192, 256, 0, stream>>>(pO, pml, Ob);
  gemm3<128, 64, 1, 3><<<dim3(16, 16), 256, 0, stream>>>(Ob, cwoT, ca_bo, x1, x2, 2048, 1024, 1024, 1);

  // ---- FFN ----
  adaln_kernel<<<2048, 256, 0, stream>>>(x2, ln2_w, ln2_b, mods, 2, 3, ain);
  gemm3<128, 128, 2, 2><<<dim3(16, 32), 256, 0, stream>>>(ain, ff1T, ff_b1, nullptr, hb, 2048, 4096, 1024, 1);
  gemm3<128, 64, 3, 3><<<dim3(16, 16, 2), 256, 0, stream>>>(hb, ff2T, nullptr, nullptr, pbuf, 2048, 1024, 4096, 2);
  ff2red_kernel<<<2048, 256, 0, stream>>>(pbuf, ff_b2, x2, out, 2048 * 1024, 1024);
}